// Round 1
// baseline (898.890 us; speedup 1.0000x reference)
//
#include <hip/hip_runtime.h>
#include <hip/hip_bf16.h>
#include <math.h>

#define FIN 128
#define HID 128
#define NCLS 40

// ---------------------------------------------------------------------------
// Edge-index dtype detection: reference dtype is int64, harness doc claims
// int32. If buffer is int64 (little-endian), every odd 32-bit word (high word)
// of the first pairs is 0 (values in [0,1e5)). Random int32 edge data would
// have nonzero odd words with overwhelming probability.
// flag==1  -> data is int32;  flag==0 -> data is int64.
// ---------------------------------------------------------------------------
__global__ void detect_kernel(const unsigned int* __restrict__ ei32, int npairs,
                              int* __restrict__ flag) {
    int i = blockIdx.x * blockDim.x + threadIdx.x;
    if (i < npairs) {
        if (ei32[2 * i + 1] != 0u) atomicOr(flag, 1);
    }
}

__device__ __forceinline__ void load_edge(const void* ei, int E, int e, int is32,
                                          int& src, int& dst) {
    if (is32) {
        const int* p = (const int*)ei;
        src = p[e];
        dst = p[E + e];
    } else {
        const long long* p = (const long long*)ei;
        src = (int)p[e];
        dst = (int)p[E + e];
    }
}

__global__ void deg_kernel(const void* __restrict__ ei, int E,
                           const int* __restrict__ flag, int* __restrict__ deg) {
    int e = blockIdx.x * blockDim.x + threadIdx.x;
    if (e >= E) return;
    int is32 = *flag;
    int dst;
    if (is32) dst = ((const int*)ei)[E + e];
    else      dst = (int)((const long long*)ei)[E + e];
    atomicAdd(&deg[dst], 1);
}

__global__ void dinv_kernel(const int* __restrict__ deg, float* __restrict__ dinv, int n) {
    int i = blockIdx.x * blockDim.x + threadIdx.x;
    if (i < n) dinv[i] = rsqrtf((float)deg[i] + 1.0f);  // +1 = self loop
}

// ---------------------------------------------------------------------------
// GEMM1: Y[n x 128] = X[n x 128] @ W[128 x 128]   (fp32 vector FMA)
// block = 256 threads, tile 32 rows x 128 cols, 4x4 register tile per thread
// ---------------------------------------------------------------------------
__global__ __launch_bounds__(256) void gemm1_kernel(const float* __restrict__ X,
                                                    const float* __restrict__ W,
                                                    float* __restrict__ Y, int n) {
    __shared__ float Ws[32][128];  // k-tile x cols, 16 KB
    __shared__ float Xs[32][36];   // rows x k-tile (pad 36 for alignment + banks)
    const int t = threadIdx.x;
    const int row0 = blockIdx.x * 32;
    const int tr = t >> 5;   // 0..7  -> rows tr*4..tr*4+3
    const int tc = t & 31;   // 0..31 -> cols tc*4..tc*4+3
    float acc[4][4] = {};

    for (int kt = 0; kt < 4; ++kt) {
        // stage W tile: 32x128 floats, 4 float4 per thread
#pragma unroll
        for (int j = 0; j < 4; ++j) {
            int f4 = t + j * 256;
            int r = f4 >> 5;
            int c = (f4 & 31) << 2;
            *(float4*)&Ws[r][c] = *(const float4*)&W[(kt * 32 + r) * HID + c];
        }
        // stage X tile: 32 rows x 32 k, 1 float4 per thread
        {
            int r = t >> 3;
            int c = (t & 7) << 2;
            int row = row0 + r;
            float4 v = make_float4(0.f, 0.f, 0.f, 0.f);
            if (row < n) v = *(const float4*)&X[row * FIN + kt * 32 + c];
            *(float4*)&Xs[r][c] = v;
        }
        __syncthreads();
#pragma unroll
        for (int kk = 0; kk < 32; ++kk) {
            float4 wv = *(const float4*)&Ws[kk][tc << 2];
#pragma unroll
            for (int i = 0; i < 4; ++i) {
                float xv = Xs[tr * 4 + i][kk];
                acc[i][0] += xv * wv.x;
                acc[i][1] += xv * wv.y;
                acc[i][2] += xv * wv.z;
                acc[i][3] += xv * wv.w;
            }
        }
        __syncthreads();
    }
#pragma unroll
    for (int i = 0; i < 4; ++i) {
        int row = row0 + tr * 4 + i;
        if (row < n) {
            float4 o = make_float4(acc[i][0], acc[i][1], acc[i][2], acc[i][3]);
            *(float4*)&Y[row * HID + (tc << 2)] = o;
        }
    }
}

// ---------------------------------------------------------------------------
// GEMM2: Y[n x 40] = relu(Xin + b1)[n x 128] @ W2[128 x 40]
// cols padded to 64 in LDS; tile 64 rows x 64 cols, 4x4 per thread
// ---------------------------------------------------------------------------
__global__ __launch_bounds__(256) void gemm2_kernel(const float* __restrict__ Xin,
                                                    const float* __restrict__ W,
                                                    const float* __restrict__ b1,
                                                    float* __restrict__ Y, int n) {
    __shared__ float Ws[HID][64];  // 32 KB, cols 40..63 zero
    __shared__ float Xs[64][36];
    const int t = threadIdx.x;
    const int row0 = blockIdx.x * 64;
    const int tr = t >> 4;  // 0..15 -> rows tr*4..
    const int tc = t & 15;  // 0..15 -> cols tc*4..

    for (int f = t; f < HID * 64; f += 256) {
        int r = f >> 6;
        int c = f & 63;
        Ws[r][c] = (c < NCLS) ? W[r * NCLS + c] : 0.0f;
    }
    float acc[4][4] = {};
    __syncthreads();

    for (int kt = 0; kt < 4; ++kt) {
#pragma unroll
        for (int j = 0; j < 2; ++j) {
            int f4 = t + j * 256;       // 0..511
            int r = f4 >> 3;            // 0..63
            int c = (f4 & 7) << 2;      // 0..28
            int row = row0 + r;
            float4 v = make_float4(0.f, 0.f, 0.f, 0.f);
            if (row < n) {
                v = *(const float4*)&Xin[row * HID + kt * 32 + c];
                float4 bb = *(const float4*)&b1[kt * 32 + c];
                v.x = fmaxf(v.x + bb.x, 0.f);
                v.y = fmaxf(v.y + bb.y, 0.f);
                v.z = fmaxf(v.z + bb.z, 0.f);
                v.w = fmaxf(v.w + bb.w, 0.f);
            }
            *(float4*)&Xs[r][c] = v;
        }
        __syncthreads();
#pragma unroll
        for (int kk = 0; kk < 32; ++kk) {
            float4 wv = *(const float4*)&Ws[kt * 32 + kk][tc << 2];
#pragma unroll
            for (int i = 0; i < 4; ++i) {
                float xv = Xs[tr * 4 + i][kk];
                acc[i][0] += xv * wv.x;
                acc[i][1] += xv * wv.y;
                acc[i][2] += xv * wv.z;
                acc[i][3] += xv * wv.w;
            }
        }
        __syncthreads();
    }
    int c0 = tc << 2;
    if (c0 < NCLS) {
#pragma unroll
        for (int i = 0; i < 4; ++i) {
            int row = row0 + tr * 4 + i;
            if (row < n) {
                *(float4*)&Y[row * NCLS + c0] =
                    make_float4(acc[i][0], acc[i][1], acc[i][2], acc[i][3]);
            }
        }
    }
}

// out1[i][:] = xw1[i][:] * dinv[i]^2   (self-loop init, full overwrite)
__global__ void selfinit1_kernel(const float* __restrict__ xw,
                                 const float* __restrict__ dinv,
                                 float* __restrict__ out, int n) {
    int i4 = blockIdx.x * blockDim.x + threadIdx.x;
    if (i4 >= n * (HID / 4)) return;
    int row = i4 >> 5;
    float d = dinv[row];
    float s = d * d;
    float4 v = *(const float4*)&xw[(size_t)i4 * 4];
    v.x *= s; v.y *= s; v.z *= s; v.w *= s;
    *(float4*)&out[(size_t)i4 * 4] = v;
}

__global__ void selfinit2_kernel(const float* __restrict__ xw,
                                 const float* __restrict__ dinv,
                                 float* __restrict__ out, int n) {
    int i4 = blockIdx.x * blockDim.x + threadIdx.x;
    if (i4 >= n * (NCLS / 4)) return;
    int row = i4 / (NCLS / 4);
    float d = dinv[row];
    float s = d * d;
    float4 v = *(const float4*)&xw[(size_t)i4 * 4];
    v.x *= s; v.y *= s; v.z *= s; v.w *= s;
    *(float4*)&out[(size_t)i4 * 4] = v;
}

// one wave per edge, 128 feats (float2 per lane)
__global__ __launch_bounds__(256) void scatter1_kernel(const void* __restrict__ ei,
                                                       const int* __restrict__ flag,
                                                       const float* __restrict__ xw,
                                                       const float* __restrict__ dinv,
                                                       float* __restrict__ out, int E) {
    int gw = (int)((blockIdx.x * 256u + threadIdx.x) >> 6);
    if (gw >= E) return;
    int lane = threadIdx.x & 63;
    int src, dst;
    load_edge(ei, E, gw, *flag, src, dst);
    float w = dinv[src] * dinv[dst];
    float2 v = *(const float2*)&xw[(size_t)src * HID + lane * 2];
    float* o = &out[(size_t)dst * HID + lane * 2];
    atomicAdd(o, v.x * w);
    atomicAdd(o + 1, v.y * w);
}

// one wave per edge, 40 feats (lanes 0..39)
__global__ __launch_bounds__(256) void scatter2_kernel(const void* __restrict__ ei,
                                                       const int* __restrict__ flag,
                                                       const float* __restrict__ xw,
                                                       const float* __restrict__ dinv,
                                                       float* __restrict__ out, int E) {
    int gw = (int)((blockIdx.x * 256u + threadIdx.x) >> 6);
    if (gw >= E) return;
    int lane = threadIdx.x & 63;
    int src, dst;
    load_edge(ei, E, gw, *flag, src, dst);
    if (lane < NCLS) {
        float w = dinv[src] * dinv[dst];
        float v = xw[(size_t)src * NCLS + lane] * w;
        atomicAdd(&out[(size_t)dst * NCLS + lane], v);
    }
}

// in-place row-wise log_softmax(out + b2); one wave per row
__global__ __launch_bounds__(256) void logsoftmax_kernel(float* __restrict__ out,
                                                         const float* __restrict__ b2,
                                                         int n) {
    int gw = (int)((blockIdx.x * 256u + threadIdx.x) >> 6);
    if (gw >= n) return;
    int lane = threadIdx.x & 63;
    float v = -INFINITY;
    if (lane < NCLS) v = out[(size_t)gw * NCLS + lane] + b2[lane];
    float m = v;
#pragma unroll
    for (int off = 32; off >= 1; off >>= 1) m = fmaxf(m, __shfl_xor(m, off, 64));
    float e = (lane < NCLS) ? expf(v - m) : 0.0f;
    float s = e;
#pragma unroll
    for (int off = 32; off >= 1; off >>= 1) s += __shfl_xor(s, off, 64);
    float r = v - m - logf(s);
    if (lane < NCLS) out[(size_t)gw * NCLS + lane] = r;
}

extern "C" void kernel_launch(void* const* d_in, const int* in_sizes, int n_in,
                              void* d_out, int out_size, void* d_ws, size_t ws_size,
                              hipStream_t stream) {
    const float* x  = (const float*)d_in[0];
    const void*  ei = d_in[1];
    const float* W1 = (const float*)d_in[2];
    const float* b1 = (const float*)d_in[3];
    const float* W2 = (const float*)d_in[4];
    const float* b2 = (const float*)d_in[5];
    float* out = (float*)d_out;

    const int n = in_sizes[0] / FIN;  // 100000
    const int E = in_sizes[1] / 2;    // 640000

    // workspace layout (256B-aligned regions)
    char* ws = (char*)d_ws;
    size_t off = 0;
    auto alloc = [&](size_t bytes) {
        size_t p = off;
        off += (bytes + 255) & ~(size_t)255;
        return p;
    };
    int*   deg  = (int*)(ws + alloc((size_t)n * 4));
    int*   flag = (int*)(ws + alloc(256));
    float* dinv = (float*)(ws + alloc((size_t)n * 4));
    float* xw1  = (float*)(ws + alloc((size_t)n * HID * 4));
    float* out1 = (float*)(ws + alloc((size_t)n * HID * 4));
    float* xw2  = xw1;  // region A reusable once scatter1 finished (stream order)

    hipMemsetAsync(deg, 0, (size_t)n * 4, stream);
    hipMemsetAsync(flag, 0, 4, stream);

    int npairs = (E < 2048) ? E : 2048;
    detect_kernel<<<(npairs + 255) / 256, 256, 0, stream>>>((const unsigned int*)ei, npairs, flag);
    deg_kernel<<<(E + 255) / 256, 256, 0, stream>>>(ei, E, flag, deg);
    dinv_kernel<<<(n + 255) / 256, 256, 0, stream>>>(deg, dinv, n);

    gemm1_kernel<<<(n + 31) / 32, 256, 0, stream>>>(x, W1, xw1, n);
    selfinit1_kernel<<<(n * (HID / 4) + 255) / 256, 256, 0, stream>>>(xw1, dinv, out1, n);
    scatter1_kernel<<<((size_t)E * 64 + 255) / 256, 256, 0, stream>>>(ei, flag, xw1, dinv, out1, E);

    gemm2_kernel<<<(n + 63) / 64, 256, 0, stream>>>(out1, W2, b1, xw2, n);
    selfinit2_kernel<<<(n * (NCLS / 4) + 255) / 256, 256, 0, stream>>>(xw2, dinv, out, n);
    scatter2_kernel<<<((size_t)E * 64 + 255) / 256, 256, 0, stream>>>(ei, flag, xw2, dinv, out, E);

    logsoftmax_kernel<<<((size_t)n * 64 + 255) / 256, 256, 0, stream>>>(out, b2, n);
}

// Round 2
// 423.141 us; speedup vs baseline: 2.1243x; 2.1243x over previous
//
#include <hip/hip_runtime.h>
#include <hip/hip_bf16.h>
#include <math.h>

#define FIN 128
#define HID 128
#define NCLS 40

// ---------------------------------------------------------------------------
// Edge-index dtype detection (int64 reference vs int32 harness doc): if the
// buffer is little-endian int64 with values < 2^31, every odd 32-bit word is 0.
// flag==1 -> int32, flag==0 -> int64.
// ---------------------------------------------------------------------------
__global__ void detect_kernel(const unsigned int* __restrict__ ei32, int npairs,
                              int* __restrict__ flag) {
    int i = blockIdx.x * blockDim.x + threadIdx.x;
    if (i < npairs) {
        if (ei32[2 * i + 1] != 0u) atomicOr(flag, 1);
    }
}

__device__ __forceinline__ void load_edge(const void* ei, int E, int e, int is32,
                                          int& src, int& dst) {
    if (is32) {
        const int* p = (const int*)ei;
        src = p[e];
        dst = p[E + e];
    } else {
        const long long* p = (const long long*)ei;
        src = (int)p[e];
        dst = (int)p[E + e];
    }
}

__global__ void deg_kernel(const void* __restrict__ ei, int E,
                           const int* __restrict__ flag, int* __restrict__ deg) {
    int e = blockIdx.x * blockDim.x + threadIdx.x;
    if (e >= E) return;
    int dst;
    if (*flag) dst = ((const int*)ei)[E + e];
    else       dst = (int)((const long long*)ei)[E + e];
    atomicAdd(&deg[dst], 1);
}

__global__ void dinv_kernel(const int* __restrict__ deg, float* __restrict__ dinv, int n) {
    int i = blockIdx.x * blockDim.x + threadIdx.x;
    if (i < n) dinv[i] = rsqrtf((float)deg[i] + 1.0f);  // +1 = self loop
}

// ---------------- 3-kernel exclusive scan of deg -> rowoff[0..n] ------------
__global__ __launch_bounds__(256) void scan1_kernel(const int* __restrict__ deg,
                                                    int* __restrict__ locscan,
                                                    int* __restrict__ blocksum, int n) {
    __shared__ int s[256];
    int t = threadIdx.x;
    int i = blockIdx.x * 256 + t;
    s[t] = (i < n) ? deg[i] : 0;
    __syncthreads();
#pragma unroll
    for (int off = 1; off < 256; off <<= 1) {
        int u = (t >= off) ? s[t - off] : 0;
        __syncthreads();
        s[t] += u;
        __syncthreads();
    }
    if (i < n) locscan[i] = s[t];  // inclusive within block
    if (t == 255) blocksum[blockIdx.x] = s[255];
}

__global__ __launch_bounds__(512) void scan2_kernel(int* __restrict__ blocksum, int nb) {
    __shared__ int s[512];
    int t = threadIdx.x;
    s[t] = (t < nb) ? blocksum[t] : 0;
    __syncthreads();
#pragma unroll
    for (int off = 1; off < 512; off <<= 1) {
        int u = (t >= off) ? s[t - off] : 0;
        __syncthreads();
        s[t] += u;
        __syncthreads();
    }
    if (t < nb) blocksum[t] = s[t];  // inclusive scan of block sums
}

__global__ __launch_bounds__(256) void scan3_kernel(const int* __restrict__ locscan,
                                                    const int* __restrict__ blocksum,
                                                    int* __restrict__ rowoff, int n) {
    int i = blockIdx.x * 256 + threadIdx.x;
    if (i >= n) return;
    int base = (blockIdx.x == 0) ? 0 : blocksum[blockIdx.x - 1];
    rowoff[i + 1] = base + locscan[i];
    if (i == 0) rowoff[0] = 0;
}

__global__ void cursor_init_kernel(const int* __restrict__ rowoff,
                                   int* __restrict__ cursor, int n) {
    int i = blockIdx.x * blockDim.x + threadIdx.x;
    if (i < n) cursor[i] = rowoff[i];
}

// bucket sort edges by dst: sortedSrc[rowoff[dst] ...] = src
__global__ void sort_kernel(const void* __restrict__ ei, const int* __restrict__ flag,
                            int* __restrict__ cursor, int* __restrict__ sortedSrc, int E) {
    int e = blockIdx.x * blockDim.x + threadIdx.x;
    if (e >= E) return;
    int src, dst;
    load_edge(ei, E, e, *flag, src, dst);
    int pos = atomicAdd(&cursor[dst], 1);
    sortedSrc[pos] = src;
}

// ---------------------------------------------------------------------------
// GEMM1: Y[n x 128] = X[n x 128] @ W[128 x 128]   (fp32 vector FMA)
// ---------------------------------------------------------------------------
__global__ __launch_bounds__(256) void gemm1_kernel(const float* __restrict__ X,
                                                    const float* __restrict__ W,
                                                    float* __restrict__ Y, int n) {
    __shared__ float Ws[32][128];
    __shared__ float Xs[32][36];
    const int t = threadIdx.x;
    const int row0 = blockIdx.x * 32;
    const int tr = t >> 5;
    const int tc = t & 31;
    float acc[4][4] = {};

    for (int kt = 0; kt < 4; ++kt) {
#pragma unroll
        for (int j = 0; j < 4; ++j) {
            int f4 = t + j * 256;
            int r = f4 >> 5;
            int c = (f4 & 31) << 2;
            *(float4*)&Ws[r][c] = *(const float4*)&W[(kt * 32 + r) * HID + c];
        }
        {
            int r = t >> 3;
            int c = (t & 7) << 2;
            int row = row0 + r;
            float4 v = make_float4(0.f, 0.f, 0.f, 0.f);
            if (row < n) v = *(const float4*)&X[row * FIN + kt * 32 + c];
            *(float4*)&Xs[r][c] = v;
        }
        __syncthreads();
#pragma unroll
        for (int kk = 0; kk < 32; ++kk) {
            float4 wv = *(const float4*)&Ws[kk][tc << 2];
#pragma unroll
            for (int i = 0; i < 4; ++i) {
                float xv = Xs[tr * 4 + i][kk];
                acc[i][0] += xv * wv.x;
                acc[i][1] += xv * wv.y;
                acc[i][2] += xv * wv.z;
                acc[i][3] += xv * wv.w;
            }
        }
        __syncthreads();
    }
#pragma unroll
    for (int i = 0; i < 4; ++i) {
        int row = row0 + tr * 4 + i;
        if (row < n) {
            *(float4*)&Y[row * HID + (tc << 2)] =
                make_float4(acc[i][0], acc[i][1], acc[i][2], acc[i][3]);
        }
    }
}

// ---------------------------------------------------------------------------
// GEMM2: Y[n x 40] = relu(Xin + b1)[n x 128] @ W2[128 x 40]
// ---------------------------------------------------------------------------
__global__ __launch_bounds__(256) void gemm2_kernel(const float* __restrict__ Xin,
                                                    const float* __restrict__ W,
                                                    const float* __restrict__ b1,
                                                    float* __restrict__ Y, int n) {
    __shared__ float Ws[HID][64];
    __shared__ float Xs[64][36];
    const int t = threadIdx.x;
    const int row0 = blockIdx.x * 64;
    const int tr = t >> 4;
    const int tc = t & 15;

    for (int f = t; f < HID * 64; f += 256) {
        int r = f >> 6;
        int c = f & 63;
        Ws[r][c] = (c < NCLS) ? W[r * NCLS + c] : 0.0f;
    }
    float acc[4][4] = {};
    __syncthreads();

    for (int kt = 0; kt < 4; ++kt) {
#pragma unroll
        for (int j = 0; j < 2; ++j) {
            int f4 = t + j * 256;
            int r = f4 >> 3;
            int c = (f4 & 7) << 2;
            int row = row0 + r;
            float4 v = make_float4(0.f, 0.f, 0.f, 0.f);
            if (row < n) {
                v = *(const float4*)&Xin[row * HID + kt * 32 + c];
                float4 bb = *(const float4*)&b1[kt * 32 + c];
                v.x = fmaxf(v.x + bb.x, 0.f);
                v.y = fmaxf(v.y + bb.y, 0.f);
                v.z = fmaxf(v.z + bb.z, 0.f);
                v.w = fmaxf(v.w + bb.w, 0.f);
            }
            *(float4*)&Xs[r][c] = v;
        }
        __syncthreads();
#pragma unroll
        for (int kk = 0; kk < 32; ++kk) {
            float4 wv = *(const float4*)&Ws[kt * 32 + kk][tc << 2];
#pragma unroll
            for (int i = 0; i < 4; ++i) {
                float xv = Xs[tr * 4 + i][kk];
                acc[i][0] += xv * wv.x;
                acc[i][1] += xv * wv.y;
                acc[i][2] += xv * wv.z;
                acc[i][3] += xv * wv.w;
            }
        }
        __syncthreads();
    }
    int c0 = tc << 2;
    if (c0 < NCLS) {
#pragma unroll
        for (int i = 0; i < 4; ++i) {
            int row = row0 + tr * 4 + i;
            if (row < n) {
                *(float4*)&Y[row * NCLS + c0] =
                    make_float4(acc[i][0], acc[i][1], acc[i][2], acc[i][3]);
            }
        }
    }
}

// ---------------------------------------------------------------------------
// gather1: out1[i] = dinv[i]^2 * xw1[i] + sum_{e in CSR row i} dinv[s]*dinv[i] * xw1[s]
// one wave per node, float2 per lane (128 feats)
// ---------------------------------------------------------------------------
__global__ __launch_bounds__(256) void gather1_kernel(const float* __restrict__ xw,
                                                      const float* __restrict__ dinv,
                                                      const int* __restrict__ rowoff,
                                                      const int* __restrict__ ssrc,
                                                      float* __restrict__ out, int n) {
    int gw = (int)((blockIdx.x * 256u + threadIdx.x) >> 6);
    if (gw >= n) return;
    int lane = threadIdx.x & 63;
    float di = dinv[gw];
    int rs = rowoff[gw], re = rowoff[gw + 1];
    float2 acc = *(const float2*)&xw[(size_t)gw * HID + lane * 2];
    float s2 = di * di;
    acc.x *= s2;
    acc.y *= s2;
    for (int e = rs; e < re; ++e) {
        int s = ssrc[e];
        float w = dinv[s] * di;
        float2 v = *(const float2*)&xw[(size_t)s * HID + lane * 2];
        acc.x += v.x * w;
        acc.y += v.y * w;
    }
    *(float2*)&out[(size_t)gw * HID + lane * 2] = acc;
}

// ---------------------------------------------------------------------------
// gather2 + bias + log_softmax fused: one wave per node, lanes 0..39 = classes
// ---------------------------------------------------------------------------
__global__ __launch_bounds__(256) void gather2_kernel(const float* __restrict__ xw,
                                                      const float* __restrict__ dinv,
                                                      const int* __restrict__ rowoff,
                                                      const int* __restrict__ ssrc,
                                                      const float* __restrict__ b2,
                                                      float* __restrict__ out, int n) {
    int gw = (int)((blockIdx.x * 256u + threadIdx.x) >> 6);
    if (gw >= n) return;
    int lane = threadIdx.x & 63;
    float di = dinv[gw];
    int rs = rowoff[gw], re = rowoff[gw + 1];
    float acc = 0.0f;
    if (lane < NCLS) acc = xw[(size_t)gw * NCLS + lane] * di * di;
    for (int e = rs; e < re; ++e) {
        int s = ssrc[e];
        float w = dinv[s] * di;
        if (lane < NCLS) acc += xw[(size_t)s * NCLS + lane] * w;
    }
    float v = (lane < NCLS) ? acc + b2[lane] : -INFINITY;
    float m = v;
#pragma unroll
    for (int off = 32; off >= 1; off >>= 1) m = fmaxf(m, __shfl_xor(m, off, 64));
    float e_ = (lane < NCLS) ? expf(v - m) : 0.0f;
    float ssum = e_;
#pragma unroll
    for (int off = 32; off >= 1; off >>= 1) ssum += __shfl_xor(ssum, off, 64);
    if (lane < NCLS) out[(size_t)gw * NCLS + lane] = v - m - logf(ssum);
}

extern "C" void kernel_launch(void* const* d_in, const int* in_sizes, int n_in,
                              void* d_out, int out_size, void* d_ws, size_t ws_size,
                              hipStream_t stream) {
    const float* x  = (const float*)d_in[0];
    const void*  ei = d_in[1];
    const float* W1 = (const float*)d_in[2];
    const float* b1 = (const float*)d_in[3];
    const float* W2 = (const float*)d_in[4];
    const float* b2 = (const float*)d_in[5];
    float* out = (float*)d_out;

    const int n = in_sizes[0] / FIN;  // 100000
    const int E = in_sizes[1] / 2;    // 640000

    char* ws = (char*)d_ws;
    size_t off = 0;
    auto alloc = [&](size_t bytes) {
        size_t p = off;
        off += (bytes + 255) & ~(size_t)255;
        return p;
    };
    int*   deg    = (int*)(ws + alloc((size_t)n * 4));
    int*   flag   = (int*)(ws + alloc(256));
    float* dinv   = (float*)(ws + alloc((size_t)n * 4));
    int*   rowoff = (int*)(ws + alloc((size_t)(n + 1) * 4));
    int*   cursor = (int*)(ws + alloc((size_t)n * 4));  // doubles as locscan
    int*   bsum   = (int*)(ws + alloc(512 * 4));
    int*   ssrc   = (int*)(ws + alloc((size_t)E * 4));
    float* xw1    = (float*)(ws + alloc((size_t)n * HID * 4));
    float* out1   = (float*)(ws + alloc((size_t)n * HID * 4));
    float* xw2    = xw1;  // reuse after gather1 consumed xw1 (stream order)

    hipMemsetAsync(deg, 0, (size_t)n * 4, stream);
    hipMemsetAsync(flag, 0, 4, stream);

    const int npairs = (E < 2048) ? E : 2048;
    const int nb = (n + 255) / 256;  // scan blocks (391 <= 512)

    detect_kernel<<<(npairs + 255) / 256, 256, 0, stream>>>((const unsigned int*)ei, npairs, flag);
    deg_kernel<<<(E + 255) / 256, 256, 0, stream>>>(ei, E, flag, deg);
    dinv_kernel<<<nb, 256, 0, stream>>>(deg, dinv, n);

    scan1_kernel<<<nb, 256, 0, stream>>>(deg, cursor, bsum, n);
    scan2_kernel<<<1, 512, 0, stream>>>(bsum, nb);
    scan3_kernel<<<nb, 256, 0, stream>>>(cursor, bsum, rowoff, n);
    cursor_init_kernel<<<nb, 256, 0, stream>>>(rowoff, cursor, n);
    sort_kernel<<<(E + 255) / 256, 256, 0, stream>>>(ei, flag, cursor, ssrc, E);

    gemm1_kernel<<<(n + 31) / 32, 256, 0, stream>>>(x, W1, xw1, n);
    gather1_kernel<<<(int)(((size_t)n * 64 + 255) / 256), 256, 0, stream>>>(
        xw1, dinv, rowoff, ssrc, out1, n);

    gemm2_kernel<<<(n + 63) / 64, 256, 0, stream>>>(out1, W2, b1, xw2, n);
    gather2_kernel<<<(int)(((size_t)n * 64 + 255) / 256), 256, 0, stream>>>(
        xw2, dinv, rowoff, ssrc, b2, out, n);
}

// Round 3
// 307.443 us; speedup vs baseline: 2.9238x; 1.3763x over previous
//
#include <hip/hip_runtime.h>
#include <hip/hip_bf16.h>
#include <math.h>

#define FIN 128
#define HID 128
#define NCLS 40
#define XW2S 64  // padded row stride of xw2

typedef __attribute__((ext_vector_type(8))) short short8v;  // 8 bf16
typedef __attribute__((ext_vector_type(4))) float f32x4;

__device__ __forceinline__ unsigned short f2bf(float f) {
    unsigned int u = __float_as_uint(f);
    u += 0x7fffu + ((u >> 16) & 1u);  // RNE
    return (unsigned short)(u >> 16);
}

// ---------------------------------------------------------------------------
// edge dtype detect: int64 (reference) vs int32 (harness doc)
// ---------------------------------------------------------------------------
__global__ void detect_kernel(const unsigned int* __restrict__ ei32, int npairs,
                              int* __restrict__ flag) {
    int i = blockIdx.x * blockDim.x + threadIdx.x;
    if (i < npairs) {
        if (ei32[2 * i + 1] != 0u) atomicOr(flag, 1);
    }
}

__device__ __forceinline__ void load_edge(const void* ei, int E, int e, int is32,
                                          int& src, int& dst) {
    if (is32) {
        const int* p = (const int*)ei;
        src = p[e];
        dst = p[E + e];
    } else {
        const long long* p = (const long long*)ei;
        src = (int)p[e];
        dst = (int)p[E + e];
    }
}

__global__ void deg_kernel(const void* __restrict__ ei, int E,
                           const int* __restrict__ flag, int* __restrict__ deg) {
    int e = blockIdx.x * blockDim.x + threadIdx.x;
    if (e >= E) return;
    int dst;
    if (*flag) dst = ((const int*)ei)[E + e];
    else       dst = (int)((const long long*)ei)[E + e];
    atomicAdd(&deg[dst], 1);
}

__global__ void dinv_kernel(const int* __restrict__ deg, float* __restrict__ dinv, int n) {
    int i = blockIdx.x * blockDim.x + threadIdx.x;
    if (i < n) dinv[i] = rsqrtf((float)deg[i] + 1.0f);  // +1 = self loop
}

// ---------------- scan deg -> rowoff --------------------------------------
__global__ __launch_bounds__(256) void scan1_kernel(const int* __restrict__ deg,
                                                    int* __restrict__ locscan,
                                                    int* __restrict__ blocksum, int n) {
    __shared__ int s[256];
    int t = threadIdx.x;
    int i = blockIdx.x * 256 + t;
    s[t] = (i < n) ? deg[i] : 0;
    __syncthreads();
#pragma unroll
    for (int off = 1; off < 256; off <<= 1) {
        int u = (t >= off) ? s[t - off] : 0;
        __syncthreads();
        s[t] += u;
        __syncthreads();
    }
    if (i < n) locscan[i] = s[t];
    if (t == 255) blocksum[blockIdx.x] = s[255];
}

__global__ __launch_bounds__(512) void scan2_kernel(int* __restrict__ blocksum, int nb) {
    __shared__ int s[512];
    int t = threadIdx.x;
    s[t] = (t < nb) ? blocksum[t] : 0;
    __syncthreads();
#pragma unroll
    for (int off = 1; off < 512; off <<= 1) {
        int u = (t >= off) ? s[t - off] : 0;
        __syncthreads();
        s[t] += u;
        __syncthreads();
    }
    if (t < nb) blocksum[t] = s[t];
}

__global__ __launch_bounds__(256) void scan3_kernel(const int* __restrict__ locscan,
                                                    const int* __restrict__ blocksum,
                                                    int* __restrict__ rowoff, int n) {
    int i = blockIdx.x * 256 + threadIdx.x;
    if (i >= n) return;
    int base = (blockIdx.x == 0) ? 0 : blocksum[blockIdx.x - 1];
    rowoff[i + 1] = base + locscan[i];
    if (i == 0) rowoff[0] = 0;
}

__global__ void cursor_init_kernel(const int* __restrict__ rowoff,
                                   int* __restrict__ cursor, int n) {
    int i = blockIdx.x * blockDim.x + threadIdx.x;
    if (i < n) cursor[i] = rowoff[i];
}

// bucket sort: epay[rowoff[dst]...] = {src, dinv[src]*dinv[dst]}
__global__ void sort_kernel(const void* __restrict__ ei, const int* __restrict__ flag,
                            const float* __restrict__ dinv, int* __restrict__ cursor,
                            int2* __restrict__ epay, int E) {
    int e = blockIdx.x * blockDim.x + threadIdx.x;
    if (e >= E) return;
    int src, dst;
    load_edge(ei, E, e, *flag, src, dst);
    float w = dinv[src] * dinv[dst];
    int pos = atomicAdd(&cursor[dst], 1);
    epay[pos] = make_int2(src, __float_as_int(w));
}

// ---------------------------------------------------------------------------
// W transpose+cast: Wt1[nidx][k] = bf16(W1[k][nidx]), 128x128
// ---------------------------------------------------------------------------
__global__ void prepw1_kernel(const float* __restrict__ W, unsigned short* __restrict__ Wt) {
    int i = blockIdx.x * 256 + threadIdx.x;
    if (i < 128 * 128) {
        int nidx = i >> 7, k = i & 127;
        Wt[i] = f2bf(W[k * HID + nidx]);
    }
}

// Wt2[nidx][k] = bf16(W2[k][nidx]) for nidx<40, rows 40..47 zero
__global__ void prepw2_kernel(const float* __restrict__ W, unsigned short* __restrict__ Wt) {
    int i = blockIdx.x * 256 + threadIdx.x;
    if (i < 48 * 128) {
        int nidx = i >> 7, k = i & 127;
        Wt[i] = (nidx < NCLS) ? f2bf(W[k * NCLS + nidx]) : 0;
    }
}

// ---------------------------------------------------------------------------
// MFMA GEMM1: xw1[n x 128] = bf16(X) @ bf16(W1)
// block = 256 (4 waves), 64 rows/block, wave = 16 rows x 128 cols
// A frag: row = lane&15, k = (lane>>4)*8 + i (8 contiguous, cast from fp32)
// B frag: col = lane&15, k contiguous (from transposed Wt in LDS, pad 136)
// D: col = lane&15, row = (lane>>4)*4 + reg   [verified m89/m91]
// ---------------------------------------------------------------------------
__global__ __launch_bounds__(256) void gemm1_kernel(const float* __restrict__ X,
                                                    const unsigned short* __restrict__ Wt,
                                                    float* __restrict__ Y, int n) {
    __shared__ unsigned short Bs[128][136];  // +8 pad: breaks 256B-stride bank conflict
    const int t = threadIdx.x;
    for (int i = t; i < 128 * 16; i += 256) {  // 2048 x 16B chunks
        int c = i >> 4, kc = (i & 15) << 3;
        *(int4*)&Bs[c][kc] = ((const int4*)Wt)[i];
    }
    __syncthreads();

    const int wv = t >> 6, lane = t & 63;
    const int lr = lane & 15, kg = lane >> 4;
    const int row0 = blockIdx.x * 64 + wv * 16;
    int arow = row0 + lr;
    if (arow >= n) arow = n - 1;
    const float* aptr = X + (size_t)arow * FIN + kg * 8;

    f32x4 acc[8];
#pragma unroll
    for (int nf = 0; nf < 8; ++nf) acc[nf] = (f32x4){0.f, 0.f, 0.f, 0.f};

#pragma unroll
    for (int kt = 0; kt < 4; ++kt) {
        float4 a0 = *(const float4*)(aptr + kt * 32);
        float4 a1 = *(const float4*)(aptr + kt * 32 + 4);
        short8v af;
        af[0] = (short)f2bf(a0.x); af[1] = (short)f2bf(a0.y);
        af[2] = (short)f2bf(a0.z); af[3] = (short)f2bf(a0.w);
        af[4] = (short)f2bf(a1.x); af[5] = (short)f2bf(a1.y);
        af[6] = (short)f2bf(a1.z); af[7] = (short)f2bf(a1.w);
#pragma unroll
        for (int nf = 0; nf < 8; ++nf) {
            short8v bf_ = *(const short8v*)&Bs[nf * 16 + lr][kt * 32 + kg * 8];
            acc[nf] = __builtin_amdgcn_mfma_f32_16x16x32_bf16(af, bf_, acc[nf], 0, 0, 0);
        }
    }
#pragma unroll
    for (int nf = 0; nf < 8; ++nf) {
        int col = nf * 16 + lr;
#pragma unroll
        for (int r = 0; r < 4; ++r) {
            int row = row0 + kg * 4 + r;
            if (row < n) Y[(size_t)row * HID + col] = acc[nf][r];
        }
    }
}

// ---------------------------------------------------------------------------
// MFMA GEMM2: xw2[n x 40 (stride 64)] = bf16(relu(out1 + b1)) @ bf16(W2)
// ---------------------------------------------------------------------------
__global__ __launch_bounds__(256) void gemm2_kernel(const float* __restrict__ Xin,
                                                    const unsigned short* __restrict__ Wt,
                                                    const float* __restrict__ b1,
                                                    float* __restrict__ Y, int n) {
    __shared__ unsigned short Bs[48][136];
    const int t = threadIdx.x;
    for (int i = t; i < 48 * 16; i += 256) {
        int c = i >> 4, kc = (i & 15) << 3;
        *(int4*)&Bs[c][kc] = ((const int4*)Wt)[i];
    }
    __syncthreads();

    const int wv = t >> 6, lane = t & 63;
    const int lr = lane & 15, kg = lane >> 4;
    const int row0 = blockIdx.x * 64 + wv * 16;
    int arow = row0 + lr;
    if (arow >= n) arow = n - 1;
    const float* aptr = Xin + (size_t)arow * HID + kg * 8;
    const float* bptr = b1 + kg * 8;

    f32x4 acc[3];
#pragma unroll
    for (int nf = 0; nf < 3; ++nf) acc[nf] = (f32x4){0.f, 0.f, 0.f, 0.f};

#pragma unroll
    for (int kt = 0; kt < 4; ++kt) {
        float4 a0 = *(const float4*)(aptr + kt * 32);
        float4 a1 = *(const float4*)(aptr + kt * 32 + 4);
        float4 c0 = *(const float4*)(bptr + kt * 32);
        float4 c1 = *(const float4*)(bptr + kt * 32 + 4);
        short8v af;
        af[0] = (short)f2bf(fmaxf(a0.x + c0.x, 0.f));
        af[1] = (short)f2bf(fmaxf(a0.y + c0.y, 0.f));
        af[2] = (short)f2bf(fmaxf(a0.z + c0.z, 0.f));
        af[3] = (short)f2bf(fmaxf(a0.w + c0.w, 0.f));
        af[4] = (short)f2bf(fmaxf(a1.x + c1.x, 0.f));
        af[5] = (short)f2bf(fmaxf(a1.y + c1.y, 0.f));
        af[6] = (short)f2bf(fmaxf(a1.z + c1.z, 0.f));
        af[7] = (short)f2bf(fmaxf(a1.w + c1.w, 0.f));
#pragma unroll
        for (int nf = 0; nf < 3; ++nf) {
            short8v bf_ = *(const short8v*)&Bs[nf * 16 + lr][kt * 32 + kg * 8];
            acc[nf] = __builtin_amdgcn_mfma_f32_16x16x32_bf16(af, bf_, acc[nf], 0, 0, 0);
        }
    }
#pragma unroll
    for (int nf = 0; nf < 3; ++nf) {
        int col = nf * 16 + lr;
        if (col < NCLS) {
#pragma unroll
            for (int r = 0; r < 4; ++r) {
                int row = row0 + kg * 4 + r;
                if (row < n) Y[(size_t)row * XW2S + col] = acc[nf][r];
            }
        }
    }
}

// ---------------------------------------------------------------------------
// gather1: out1[i] = di^2*xw[i] + sum_edges w_e * xw[src_e]; wave/node,
// cooperative payload load + shfl broadcast + 4-way edge unroll (MLP)
// ---------------------------------------------------------------------------
__global__ __launch_bounds__(256) void gather1_kernel(const float* __restrict__ xw,
                                                      const float* __restrict__ dinv,
                                                      const int* __restrict__ rowoff,
                                                      const int2* __restrict__ epay,
                                                      float* __restrict__ out, int n) {
    int gw = (int)((blockIdx.x * 256u + threadIdx.x) >> 6);
    if (gw >= n) return;
    int lane = threadIdx.x & 63;
    float di = dinv[gw];
    int rs = rowoff[gw], re = rowoff[gw + 1];
    float2 acc = *(const float2*)&xw[(size_t)gw * HID + lane * 2];
    float s2 = di * di;
    acc.x *= s2;
    acc.y *= s2;

    for (int base = rs; base < re; base += 64) {
        int avail = re - base;
        int2 p = make_int2(0, 0);
        if (lane < avail) p = epay[base + lane];
        int cnt = (avail < 64) ? avail : 64;
        int j = 0;
        for (; j + 4 <= cnt; j += 4) {
            int s0 = __shfl(p.x, j, 64);
            int s1 = __shfl(p.x, j + 1, 64);
            int s2i = __shfl(p.x, j + 2, 64);
            int s3 = __shfl(p.x, j + 3, 64);
            float w0 = __int_as_float(__shfl(p.y, j, 64));
            float w1 = __int_as_float(__shfl(p.y, j + 1, 64));
            float w2 = __int_as_float(__shfl(p.y, j + 2, 64));
            float w3 = __int_as_float(__shfl(p.y, j + 3, 64));
            float2 v0 = *(const float2*)&xw[(size_t)s0 * HID + lane * 2];
            float2 v1 = *(const float2*)&xw[(size_t)s1 * HID + lane * 2];
            float2 v2 = *(const float2*)&xw[(size_t)s2i * HID + lane * 2];
            float2 v3 = *(const float2*)&xw[(size_t)s3 * HID + lane * 2];
            acc.x = fmaf(v0.x, w0, acc.x); acc.y = fmaf(v0.y, w0, acc.y);
            acc.x = fmaf(v1.x, w1, acc.x); acc.y = fmaf(v1.y, w1, acc.y);
            acc.x = fmaf(v2.x, w2, acc.x); acc.y = fmaf(v2.y, w2, acc.y);
            acc.x = fmaf(v3.x, w3, acc.x); acc.y = fmaf(v3.y, w3, acc.y);
        }
        if (j + 2 <= cnt) {
            int s0 = __shfl(p.x, j, 64);
            int s1 = __shfl(p.x, j + 1, 64);
            float w0 = __int_as_float(__shfl(p.y, j, 64));
            float w1 = __int_as_float(__shfl(p.y, j + 1, 64));
            float2 v0 = *(const float2*)&xw[(size_t)s0 * HID + lane * 2];
            float2 v1 = *(const float2*)&xw[(size_t)s1 * HID + lane * 2];
            acc.x = fmaf(v0.x, w0, acc.x); acc.y = fmaf(v0.y, w0, acc.y);
            acc.x = fmaf(v1.x, w1, acc.x); acc.y = fmaf(v1.y, w1, acc.y);
            j += 2;
        }
        if (j < cnt) {
            int s0 = __shfl(p.x, j, 64);
            float w0 = __int_as_float(__shfl(p.y, j, 64));
            float2 v0 = *(const float2*)&xw[(size_t)s0 * HID + lane * 2];
            acc.x = fmaf(v0.x, w0, acc.x); acc.y = fmaf(v0.y, w0, acc.y);
        }
    }
    *(float2*)&out[(size_t)gw * HID + lane * 2] = acc;
}

// ---------------------------------------------------------------------------
// gather2 + b2 + log_softmax: wave/node, lanes 0..39 = classes, xw stride 64
// ---------------------------------------------------------------------------
__global__ __launch_bounds__(256) void gather2_kernel(const float* __restrict__ xw,
                                                      const float* __restrict__ dinv,
                                                      const int* __restrict__ rowoff,
                                                      const int2* __restrict__ epay,
                                                      const float* __restrict__ b2,
                                                      float* __restrict__ out, int n) {
    int gw = (int)((blockIdx.x * 256u + threadIdx.x) >> 6);
    if (gw >= n) return;
    int lane = threadIdx.x & 63;
    float di = dinv[gw];
    int rs = rowoff[gw], re = rowoff[gw + 1];
    bool act = lane < NCLS;
    float acc = 0.0f;
    if (act) acc = xw[(size_t)gw * XW2S + lane] * di * di;

    for (int base = rs; base < re; base += 64) {
        int avail = re - base;
        int2 p = make_int2(0, 0);
        if (lane < avail) p = epay[base + lane];
        int cnt = (avail < 64) ? avail : 64;
        int j = 0;
        for (; j + 4 <= cnt; j += 4) {
            int s0 = __shfl(p.x, j, 64);
            int s1 = __shfl(p.x, j + 1, 64);
            int s2i = __shfl(p.x, j + 2, 64);
            int s3 = __shfl(p.x, j + 3, 64);
            float w0 = __int_as_float(__shfl(p.y, j, 64));
            float w1 = __int_as_float(__shfl(p.y, j + 1, 64));
            float w2 = __int_as_float(__shfl(p.y, j + 2, 64));
            float w3 = __int_as_float(__shfl(p.y, j + 3, 64));
            float v0 = 0.f, v1 = 0.f, v2 = 0.f, v3 = 0.f;
            if (act) {
                v0 = xw[(size_t)s0 * XW2S + lane];
                v1 = xw[(size_t)s1 * XW2S + lane];
                v2 = xw[(size_t)s2i * XW2S + lane];
                v3 = xw[(size_t)s3 * XW2S + lane];
            }
            acc = fmaf(v0, w0, acc);
            acc = fmaf(v1, w1, acc);
            acc = fmaf(v2, w2, acc);
            acc = fmaf(v3, w3, acc);
        }
        for (; j < cnt; ++j) {
            int s0 = __shfl(p.x, j, 64);
            float w0 = __int_as_float(__shfl(p.y, j, 64));
            float v0 = act ? xw[(size_t)s0 * XW2S + lane] : 0.f;
            acc = fmaf(v0, w0, acc);
        }
    }
    float v = act ? acc + b2[lane] : -INFINITY;
    float m = v;
#pragma unroll
    for (int off = 32; off >= 1; off >>= 1) m = fmaxf(m, __shfl_xor(m, off, 64));
    float e_ = act ? expf(v - m) : 0.0f;
    float ssum = e_;
#pragma unroll
    for (int off = 32; off >= 1; off >>= 1) ssum += __shfl_xor(ssum, off, 64);
    if (act) out[(size_t)gw * NCLS + lane] = v - m - logf(ssum);
}

extern "C" void kernel_launch(void* const* d_in, const int* in_sizes, int n_in,
                              void* d_out, int out_size, void* d_ws, size_t ws_size,
                              hipStream_t stream) {
    const float* x  = (const float*)d_in[0];
    const void*  ei = d_in[1];
    const float* W1 = (const float*)d_in[2];
    const float* b1 = (const float*)d_in[3];
    const float* W2 = (const float*)d_in[4];
    const float* b2 = (const float*)d_in[5];
    float* out = (float*)d_out;

    const int n = in_sizes[0] / FIN;  // 100000
    const int E = in_sizes[1] / 2;    // 640000

    char* ws = (char*)d_ws;
    size_t off = 0;
    auto alloc = [&](size_t bytes) {
        size_t p = off;
        off += (bytes + 255) & ~(size_t)255;
        return p;
    };
    int*   deg    = (int*)(ws + alloc((size_t)n * 4));
    int*   flag   = (int*)(ws + alloc(256));
    float* dinv   = (float*)(ws + alloc((size_t)n * 4));
    int*   rowoff = (int*)(ws + alloc((size_t)(n + 1) * 4));
    int*   cursor = (int*)(ws + alloc((size_t)n * 4));  // doubles as locscan
    int*   bsum   = (int*)(ws + alloc(512 * 4));
    unsigned short* wt1 = (unsigned short*)(ws + alloc(128 * 128 * 2));
    unsigned short* wt2 = (unsigned short*)(ws + alloc(48 * 128 * 2));
    int2*  epay   = (int2*)(ws + alloc((size_t)E * 8));
    float* xw1    = (float*)(ws + alloc((size_t)n * HID * 4));
    float* out1   = (float*)(ws + alloc((size_t)n * HID * 4));
    float* xw2    = xw1;  // n*64 fp32 fits in region A, reused after gather1

    hipMemsetAsync(deg, 0, (size_t)n * 4, stream);
    hipMemsetAsync(flag, 0, 4, stream);

    const int npairs = (E < 2048) ? E : 2048;
    const int nb = (n + 255) / 256;  // 391 <= 512

    detect_kernel<<<(npairs + 255) / 256, 256, 0, stream>>>((const unsigned int*)ei, npairs, flag);
    deg_kernel<<<(E + 255) / 256, 256, 0, stream>>>(ei, E, flag, deg);
    dinv_kernel<<<nb, 256, 0, stream>>>(deg, dinv, n);
    prepw1_kernel<<<64, 256, 0, stream>>>(W1, wt1);
    prepw2_kernel<<<24, 256, 0, stream>>>(W2, wt2);

    scan1_kernel<<<nb, 256, 0, stream>>>(deg, cursor, bsum, n);
    scan2_kernel<<<1, 512, 0, stream>>>(bsum, nb);
    scan3_kernel<<<nb, 256, 0, stream>>>(cursor, bsum, rowoff, n);
    cursor_init_kernel<<<nb, 256, 0, stream>>>(rowoff, cursor, n);
    sort_kernel<<<(E + 255) / 256, 256, 0, stream>>>(ei, flag, dinv, cursor, epay, E);

    gemm1_kernel<<<(n + 63) / 64, 256, 0, stream>>>(x, wt1, xw1, n);
    gather1_kernel<<<(int)(((size_t)n * 64 + 255) / 256), 256, 0, stream>>>(
        xw1, dinv, rowoff, epay, out1, n);

    gemm2_kernel<<<(n + 63) / 64, 256, 0, stream>>>(out1, wt2, b1, xw2, n);
    gather2_kernel<<<(int)(((size_t)n * 64 + 255) / 256), 256, 0, stream>>>(
        xw2, dinv, rowoff, epay, b2, out, n);
}

// Round 4
// 278.204 us; speedup vs baseline: 3.2311x; 1.1051x over previous
//
#include <hip/hip_runtime.h>
#include <hip/hip_bf16.h>
#include <math.h>

#define FIN 128
#define HID 128
#define NCLS 40
#define XW2S 64  // padded row stride (in bf16 elems) of xw2

typedef __attribute__((ext_vector_type(8))) short short8v;  // 8 bf16
typedef __attribute__((ext_vector_type(4))) float f32x4;
typedef unsigned short ushortT;

__device__ __forceinline__ unsigned short f2bf(float f) {
    unsigned int u = __float_as_uint(f);
    u += 0x7fffu + ((u >> 16) & 1u);  // RNE
    return (unsigned short)(u >> 16);
}
__device__ __forceinline__ float bf2f(unsigned int u16) {
    return __uint_as_float(u16 << 16);
}

// ---------------------------------------------------------------------------
// edge dtype detect: int64 (reference) vs int32
// ---------------------------------------------------------------------------
__global__ void detect_kernel(const unsigned int* __restrict__ ei32, int npairs,
                              int* __restrict__ flag) {
    int i = blockIdx.x * blockDim.x + threadIdx.x;
    if (i < npairs) {
        if (ei32[2 * i + 1] != 0u) atomicOr(flag, 1);
    }
}

__device__ __forceinline__ void load_edge(const void* ei, int E, int e, int is32,
                                          int& src, int& dst) {
    if (is32) {
        const int* p = (const int*)ei;
        src = p[e];
        dst = p[E + e];
    } else {
        const long long* p = (const long long*)ei;
        src = (int)p[e];
        dst = (int)p[E + e];
    }
}

__global__ void deg_kernel(const void* __restrict__ ei, int E,
                           const int* __restrict__ flag, int* __restrict__ deg) {
    int e = blockIdx.x * blockDim.x + threadIdx.x;
    if (e >= E) return;
    int dst;
    if (*flag) dst = ((const int*)ei)[E + e];
    else       dst = (int)((const long long*)ei)[E + e];
    atomicAdd(&deg[dst], 1);
}

// ---------------- scan deg -> rowoff (+ dinv, + cursor) --------------------
__global__ __launch_bounds__(256) void scan1_kernel(const int* __restrict__ deg,
                                                    int* __restrict__ locscan,
                                                    int* __restrict__ blocksum,
                                                    float* __restrict__ dinv, int n) {
    __shared__ int s[256];
    int t = threadIdx.x;
    int i = blockIdx.x * 256 + t;
    int d = (i < n) ? deg[i] : 0;
    if (i < n) dinv[i] = rsqrtf((float)d + 1.0f);  // +1 self loop
    s[t] = d;
    __syncthreads();
#pragma unroll
    for (int off = 1; off < 256; off <<= 1) {
        int u = (t >= off) ? s[t - off] : 0;
        __syncthreads();
        s[t] += u;
        __syncthreads();
    }
    if (i < n) locscan[i] = s[t];
    if (t == 255) blocksum[blockIdx.x] = s[255];
}

__global__ __launch_bounds__(512) void scan2_kernel(int* __restrict__ blocksum, int nb) {
    __shared__ int s[512];
    int t = threadIdx.x;
    s[t] = (t < nb) ? blocksum[t] : 0;
    __syncthreads();
#pragma unroll
    for (int off = 1; off < 512; off <<= 1) {
        int u = (t >= off) ? s[t - off] : 0;
        __syncthreads();
        s[t] += u;
        __syncthreads();
    }
    if (t < nb) blocksum[t] = s[t];
}

__global__ __launch_bounds__(256) void scan3_kernel(const int* __restrict__ locscan,
                                                    const int* __restrict__ blocksum,
                                                    const int* __restrict__ deg,
                                                    int* __restrict__ rowoff,
                                                    int* __restrict__ cursor, int n) {
    int i = blockIdx.x * 256 + threadIdx.x;
    if (i >= n) return;
    int base = (blockIdx.x == 0) ? 0 : blocksum[blockIdx.x - 1];
    int incl = base + locscan[i];
    rowoff[i + 1] = incl;
    cursor[i] = incl - deg[i];  // exclusive prefix = rowoff[i]
    if (i == 0) rowoff[0] = 0;
}

// bucket sort: epay[rowoff[dst]...] = {src, dinv[src]*dinv[dst]}
__global__ void sort_kernel(const void* __restrict__ ei, const int* __restrict__ flag,
                            const float* __restrict__ dinv, int* __restrict__ cursor,
                            int2* __restrict__ epay, int E) {
    int e = blockIdx.x * blockDim.x + threadIdx.x;
    if (e >= E) return;
    int src, dst;
    load_edge(ei, E, e, *flag, src, dst);
    float w = dinv[src] * dinv[dst];
    int pos = atomicAdd(&cursor[dst], 1);
    epay[pos] = make_int2(src, __float_as_int(w));
}

// W transpose+cast, both weights in one launch
__global__ void prepw_kernel(const float* __restrict__ W1, unsigned short* __restrict__ Wt1,
                             const float* __restrict__ W2, unsigned short* __restrict__ Wt2) {
    int i = blockIdx.x * 256 + threadIdx.x;
    if (i < 128 * 128) {
        int nidx = i >> 7, k = i & 127;
        Wt1[i] = f2bf(W1[k * HID + nidx]);
    } else if (i < 128 * 128 + 48 * 128) {
        int j = i - 128 * 128;
        int nidx = j >> 7, k = j & 127;
        Wt2[j] = (nidx < NCLS) ? f2bf(W2[k * NCLS + nidx]) : 0;
    }
}

// ---------------------------------------------------------------------------
// MFMA GEMM1: xw1[n x 128] (bf16) = bf16(X) @ bf16(W1)
// ---------------------------------------------------------------------------
__global__ __launch_bounds__(256) void gemm1_kernel(const float* __restrict__ X,
                                                    const unsigned short* __restrict__ Wt,
                                                    unsigned short* __restrict__ Y, int n) {
    __shared__ unsigned short Bs[128][136];
    const int t = threadIdx.x;
    for (int i = t; i < 128 * 16; i += 256) {
        int c = i >> 4, kc = (i & 15) << 3;
        *(int4*)&Bs[c][kc] = ((const int4*)Wt)[i];
    }
    __syncthreads();

    const int wv = t >> 6, lane = t & 63;
    const int lr = lane & 15, kg = lane >> 4;
    const int row0 = blockIdx.x * 64 + wv * 16;
    int arow = row0 + lr;
    if (arow >= n) arow = n - 1;
    const float* aptr = X + (size_t)arow * FIN + kg * 8;

    f32x4 acc[8];
#pragma unroll
    for (int nf = 0; nf < 8; ++nf) acc[nf] = (f32x4){0.f, 0.f, 0.f, 0.f};

#pragma unroll
    for (int kt = 0; kt < 4; ++kt) {
        float4 a0 = *(const float4*)(aptr + kt * 32);
        float4 a1 = *(const float4*)(aptr + kt * 32 + 4);
        short8v af;
        af[0] = (short)f2bf(a0.x); af[1] = (short)f2bf(a0.y);
        af[2] = (short)f2bf(a0.z); af[3] = (short)f2bf(a0.w);
        af[4] = (short)f2bf(a1.x); af[5] = (short)f2bf(a1.y);
        af[6] = (short)f2bf(a1.z); af[7] = (short)f2bf(a1.w);
#pragma unroll
        for (int nf = 0; nf < 8; ++nf) {
            short8v bf_ = *(const short8v*)&Bs[nf * 16 + lr][kt * 32 + kg * 8];
            acc[nf] = __builtin_amdgcn_mfma_f32_16x16x32_bf16(af, bf_, acc[nf], 0, 0, 0);
        }
    }
#pragma unroll
    for (int nf = 0; nf < 8; ++nf) {
        int col = nf * 16 + lr;
#pragma unroll
        for (int r = 0; r < 4; ++r) {
            int row = row0 + kg * 4 + r;
            if (row < n) Y[(size_t)row * HID + col] = f2bf(acc[nf][r]);
        }
    }
}

// ---------------------------------------------------------------------------
// MFMA GEMM2: xw2[n x 40 (bf16, stride 64)] = bf16(relu(out1_bf16 + b1)) @ bf16(W2)
// ---------------------------------------------------------------------------
__global__ __launch_bounds__(256) void gemm2_kernel(const unsigned short* __restrict__ Xin,
                                                    const unsigned short* __restrict__ Wt,
                                                    const float* __restrict__ b1,
                                                    unsigned short* __restrict__ Y, int n) {
    __shared__ unsigned short Bs[48][136];
    const int t = threadIdx.x;
    for (int i = t; i < 48 * 16; i += 256) {
        int c = i >> 4, kc = (i & 15) << 3;
        *(int4*)&Bs[c][kc] = ((const int4*)Wt)[i];
    }
    __syncthreads();

    const int wv = t >> 6, lane = t & 63;
    const int lr = lane & 15, kg = lane >> 4;
    const int row0 = blockIdx.x * 64 + wv * 16;
    int arow = row0 + lr;
    if (arow >= n) arow = n - 1;
    const unsigned short* aptr = Xin + (size_t)arow * HID + kg * 8;
    const float* bptr = b1 + kg * 8;

    f32x4 acc[3];
#pragma unroll
    for (int nf = 0; nf < 3; ++nf) acc[nf] = (f32x4){0.f, 0.f, 0.f, 0.f};

#pragma unroll
    for (int kt = 0; kt < 4; ++kt) {
        uint4 a = *(const uint4*)(aptr + kt * 32);  // 8 bf16
        float4 c0 = *(const float4*)(bptr + kt * 32);
        float4 c1 = *(const float4*)(bptr + kt * 32 + 4);
        short8v af;
        af[0] = (short)f2bf(fmaxf(bf2f(a.x & 0xffffu) + c0.x, 0.f));
        af[1] = (short)f2bf(fmaxf(bf2f(a.x >> 16)     + c0.y, 0.f));
        af[2] = (short)f2bf(fmaxf(bf2f(a.y & 0xffffu) + c0.z, 0.f));
        af[3] = (short)f2bf(fmaxf(bf2f(a.y >> 16)     + c0.w, 0.f));
        af[4] = (short)f2bf(fmaxf(bf2f(a.z & 0xffffu) + c1.x, 0.f));
        af[5] = (short)f2bf(fmaxf(bf2f(a.z >> 16)     + c1.y, 0.f));
        af[6] = (short)f2bf(fmaxf(bf2f(a.w & 0xffffu) + c1.z, 0.f));
        af[7] = (short)f2bf(fmaxf(bf2f(a.w >> 16)     + c1.w, 0.f));
#pragma unroll
        for (int nf = 0; nf < 3; ++nf) {
            short8v bf_ = *(const short8v*)&Bs[nf * 16 + lr][kt * 32 + kg * 8];
            acc[nf] = __builtin_amdgcn_mfma_f32_16x16x32_bf16(af, bf_, acc[nf], 0, 0, 0);
        }
    }
#pragma unroll
    for (int nf = 0; nf < 3; ++nf) {
        int col = nf * 16 + lr;
        if (col < NCLS) {
#pragma unroll
            for (int r = 0; r < 4; ++r) {
                int row = row0 + kg * 4 + r;
                if (row < n) Y[(size_t)row * XW2S + col] = f2bf(acc[nf][r]);
            }
        }
    }
}

// ---------------------------------------------------------------------------
// gather1: out1[i] = di^2*xw[i] + sum_e w_e*xw[src_e]; bf16 payload (dword/lane)
// ---------------------------------------------------------------------------
__global__ __launch_bounds__(256) void gather1_kernel(const unsigned int* __restrict__ xw,
                                                      const float* __restrict__ dinv,
                                                      const int* __restrict__ rowoff,
                                                      const int2* __restrict__ epay,
                                                      unsigned int* __restrict__ out, int n) {
    int gw = (int)((blockIdx.x * 256u + threadIdx.x) >> 6);
    if (gw >= n) return;
    int lane = threadIdx.x & 63;
    float di = dinv[gw];
    int rs = rowoff[gw], re = rowoff[gw + 1];
    unsigned int own = xw[(size_t)gw * 64 + lane];
    float s2 = di * di;
    float accx = bf2f(own & 0xffffu) * s2;
    float accy = bf2f(own >> 16) * s2;

    for (int base = rs; base < re; base += 64) {
        int avail = re - base;
        int2 p = make_int2(0, 0);
        if (lane < avail) p = epay[base + lane];
        int cnt = (avail < 64) ? avail : 64;
        int j = 0;
        for (; j + 4 <= cnt; j += 4) {
            int s0 = __shfl(p.x, j, 64);
            int s1 = __shfl(p.x, j + 1, 64);
            int s2i = __shfl(p.x, j + 2, 64);
            int s3 = __shfl(p.x, j + 3, 64);
            float w0 = __int_as_float(__shfl(p.y, j, 64));
            float w1 = __int_as_float(__shfl(p.y, j + 1, 64));
            float w2 = __int_as_float(__shfl(p.y, j + 2, 64));
            float w3 = __int_as_float(__shfl(p.y, j + 3, 64));
            unsigned int v0 = xw[(size_t)s0 * 64 + lane];
            unsigned int v1 = xw[(size_t)s1 * 64 + lane];
            unsigned int v2 = xw[(size_t)s2i * 64 + lane];
            unsigned int v3 = xw[(size_t)s3 * 64 + lane];
            accx = fmaf(bf2f(v0 & 0xffffu), w0, accx);
            accy = fmaf(bf2f(v0 >> 16), w0, accy);
            accx = fmaf(bf2f(v1 & 0xffffu), w1, accx);
            accy = fmaf(bf2f(v1 >> 16), w1, accy);
            accx = fmaf(bf2f(v2 & 0xffffu), w2, accx);
            accy = fmaf(bf2f(v2 >> 16), w2, accy);
            accx = fmaf(bf2f(v3 & 0xffffu), w3, accx);
            accy = fmaf(bf2f(v3 >> 16), w3, accy);
        }
        if (j + 2 <= cnt) {
            int s0 = __shfl(p.x, j, 64);
            int s1 = __shfl(p.x, j + 1, 64);
            float w0 = __int_as_float(__shfl(p.y, j, 64));
            float w1 = __int_as_float(__shfl(p.y, j + 1, 64));
            unsigned int v0 = xw[(size_t)s0 * 64 + lane];
            unsigned int v1 = xw[(size_t)s1 * 64 + lane];
            accx = fmaf(bf2f(v0 & 0xffffu), w0, accx);
            accy = fmaf(bf2f(v0 >> 16), w0, accy);
            accx = fmaf(bf2f(v1 & 0xffffu), w1, accx);
            accy = fmaf(bf2f(v1 >> 16), w1, accy);
            j += 2;
        }
        if (j < cnt) {
            int s0 = __shfl(p.x, j, 64);
            float w0 = __int_as_float(__shfl(p.y, j, 64));
            unsigned int v0 = xw[(size_t)s0 * 64 + lane];
            accx = fmaf(bf2f(v0 & 0xffffu), w0, accx);
            accy = fmaf(bf2f(v0 >> 16), w0, accy);
        }
    }
    out[(size_t)gw * 64 + lane] = (unsigned int)f2bf(accx) | ((unsigned int)f2bf(accy) << 16);
}

// ---------------------------------------------------------------------------
// gather2 + b2 + log_softmax: bf16 payload, lanes 0..39 = classes
// ---------------------------------------------------------------------------
__global__ __launch_bounds__(256) void gather2_kernel(const unsigned short* __restrict__ xw,
                                                      const float* __restrict__ dinv,
                                                      const int* __restrict__ rowoff,
                                                      const int2* __restrict__ epay,
                                                      const float* __restrict__ b2,
                                                      float* __restrict__ out, int n) {
    int gw = (int)((blockIdx.x * 256u + threadIdx.x) >> 6);
    if (gw >= n) return;
    int lane = threadIdx.x & 63;
    float di = dinv[gw];
    int rs = rowoff[gw], re = rowoff[gw + 1];
    bool act = lane < NCLS;
    float acc = 0.0f;
    if (act) acc = bf2f(xw[(size_t)gw * XW2S + lane]) * di * di;

    for (int base = rs; base < re; base += 64) {
        int avail = re - base;
        int2 p = make_int2(0, 0);
        if (lane < avail) p = epay[base + lane];
        int cnt = (avail < 64) ? avail : 64;
        int j = 0;
        for (; j + 4 <= cnt; j += 4) {
            int s0 = __shfl(p.x, j, 64);
            int s1 = __shfl(p.x, j + 1, 64);
            int s2i = __shfl(p.x, j + 2, 64);
            int s3 = __shfl(p.x, j + 3, 64);
            float w0 = __int_as_float(__shfl(p.y, j, 64));
            float w1 = __int_as_float(__shfl(p.y, j + 1, 64));
            float w2 = __int_as_float(__shfl(p.y, j + 2, 64));
            float w3 = __int_as_float(__shfl(p.y, j + 3, 64));
            float v0 = 0.f, v1 = 0.f, v2 = 0.f, v3 = 0.f;
            if (act) {
                v0 = bf2f(xw[(size_t)s0 * XW2S + lane]);
                v1 = bf2f(xw[(size_t)s1 * XW2S + lane]);
                v2 = bf2f(xw[(size_t)s2i * XW2S + lane]);
                v3 = bf2f(xw[(size_t)s3 * XW2S + lane]);
            }
            acc = fmaf(v0, w0, acc);
            acc = fmaf(v1, w1, acc);
            acc = fmaf(v2, w2, acc);
            acc = fmaf(v3, w3, acc);
        }
        for (; j < cnt; ++j) {
            int s0 = __shfl(p.x, j, 64);
            float w0 = __int_as_float(__shfl(p.y, j, 64));
            float v0 = act ? bf2f(xw[(size_t)s0 * XW2S + lane]) : 0.f;
            acc = fmaf(v0, w0, acc);
        }
    }
    float v = act ? acc + b2[lane] : -INFINITY;
    float m = v;
#pragma unroll
    for (int off = 32; off >= 1; off >>= 1) m = fmaxf(m, __shfl_xor(m, off, 64));
    float e_ = act ? expf(v - m) : 0.0f;
    float ssum = e_;
#pragma unroll
    for (int off = 32; off >= 1; off >>= 1) ssum += __shfl_xor(ssum, off, 64);
    if (act) out[(size_t)gw * NCLS + lane] = v - m - logf(ssum);
}

extern "C" void kernel_launch(void* const* d_in, const int* in_sizes, int n_in,
                              void* d_out, int out_size, void* d_ws, size_t ws_size,
                              hipStream_t stream) {
    const float* x  = (const float*)d_in[0];
    const void*  ei = d_in[1];
    const float* W1 = (const float*)d_in[2];
    const float* b1 = (const float*)d_in[3];
    const float* W2 = (const float*)d_in[4];
    const float* b2 = (const float*)d_in[5];
    float* out = (float*)d_out;

    const int n = in_sizes[0] / FIN;  // 100000
    const int E = in_sizes[1] / 2;    // 640000

    char* ws = (char*)d_ws;
    size_t off = 0;
    auto alloc = [&](size_t bytes) {
        size_t p = off;
        off += (bytes + 255) & ~(size_t)255;
        return p;
    };
    int*   deg    = (int*)(ws + alloc((size_t)n * 4));
    int*   flag   = (int*)(ws + alloc(256));
    float* dinv   = (float*)(ws + alloc((size_t)n * 4));
    int*   rowoff = (int*)(ws + alloc((size_t)(n + 1) * 4));
    int*   locscan= (int*)(ws + alloc((size_t)n * 4));
    int*   cursor = (int*)(ws + alloc((size_t)n * 4));
    int*   bsum   = (int*)(ws + alloc(512 * 4));
    unsigned short* wt1 = (unsigned short*)(ws + alloc(128 * 128 * 2));
    unsigned short* wt2 = (unsigned short*)(ws + alloc(48 * 128 * 2));
    int2*  epay   = (int2*)(ws + alloc((size_t)E * 8));
    unsigned short* xw1  = (unsigned short*)(ws + alloc((size_t)n * HID * 2));
    unsigned short* out1 = (unsigned short*)(ws + alloc((size_t)n * HID * 2));
    unsigned short* xw2  = xw1;  // n*64 bf16 fits in xw1 region, reused after gather1

    hipMemsetAsync(deg, 0, (size_t)n * 4, stream);
    hipMemsetAsync(flag, 0, 4, stream);

    const int npairs = (E < 2048) ? E : 2048;
    const int nb = (n + 255) / 256;  // 391 <= 512

    detect_kernel<<<(npairs + 255) / 256, 256, 0, stream>>>((const unsigned int*)ei, npairs, flag);
    deg_kernel<<<(E + 255) / 256, 256, 0, stream>>>(ei, E, flag, deg);
    prepw_kernel<<<(128 * 128 + 48 * 128 + 255) / 256, 256, 0, stream>>>(W1, wt1, W2, wt2);

    scan1_kernel<<<nb, 256, 0, stream>>>(deg, locscan, bsum, dinv, n);
    scan2_kernel<<<1, 512, 0, stream>>>(bsum, nb);
    scan3_kernel<<<nb, 256, 0, stream>>>(locscan, bsum, deg, rowoff, cursor, n);
    sort_kernel<<<(E + 255) / 256, 256, 0, stream>>>(ei, flag, dinv, cursor, epay, E);

    gemm1_kernel<<<(n + 63) / 64, 256, 0, stream>>>(x, wt1, xw1, n);
    gather1_kernel<<<(int)(((size_t)n * 64 + 255) / 256), 256, 0, stream>>>(
        (const unsigned int*)xw1, dinv, rowoff, epay, (unsigned int*)out1, n);

    gemm2_kernel<<<(n + 63) / 64, 256, 0, stream>>>(out1, wt2, b1, xw2, n);
    gather2_kernel<<<(int)(((size_t)n * 64 + 255) / 256), 256, 0, stream>>>(
        xw2, dinv, rowoff, epay, b2, out, n);
}

// Round 5
// 268.983 us; speedup vs baseline: 3.3418x; 1.0343x over previous
//
#include <hip/hip_runtime.h>
#include <hip/hip_bf16.h>
#include <math.h>

#define FIN 128
#define HID 128
#define NCLS 40

typedef __attribute__((ext_vector_type(8))) short short8v;  // 8 bf16
typedef __attribute__((ext_vector_type(4))) float f32x4;

__device__ __forceinline__ unsigned short f2bf(float f) {
    unsigned int u = __float_as_uint(f);
    u += 0x7fffu + ((u >> 16) & 1u);  // RNE
    return (unsigned short)(u >> 16);
}
__device__ __forceinline__ float bf2f(unsigned int u16) {
    return __uint_as_float(u16 << 16);
}

// ---------------------------------------------------------------------------
// edge dtype detect: int64 (reference) vs int32
// ---------------------------------------------------------------------------
__global__ void detect_kernel(const unsigned int* __restrict__ ei32, int npairs,
                              int* __restrict__ flag) {
    int i = blockIdx.x * blockDim.x + threadIdx.x;
    if (i < npairs) {
        if (ei32[2 * i + 1] != 0u) atomicOr(flag, 1);
    }
}

__device__ __forceinline__ void load_edge(const void* ei, int E, int e, int is32,
                                          int& src, int& dst) {
    if (is32) {
        const int* p = (const int*)ei;
        src = p[e];
        dst = p[E + e];
    } else {
        const long long* p = (const long long*)ei;
        src = (int)p[e];
        dst = (int)p[E + e];
    }
}

__global__ void deg_kernel(const void* __restrict__ ei, int E,
                           const int* __restrict__ flag, int* __restrict__ deg) {
    int e = blockIdx.x * blockDim.x + threadIdx.x;
    if (e >= E) return;
    int dst;
    if (*flag) dst = ((const int*)ei)[E + e];
    else       dst = (int)((const long long*)ei)[E + e];
    atomicAdd(&deg[dst], 1);
}

// ---------------- scan deg -> rowoff (+ dinv, + cursor) --------------------
__global__ __launch_bounds__(256) void scan1_kernel(const int* __restrict__ deg,
                                                    int* __restrict__ locscan,
                                                    int* __restrict__ blocksum,
                                                    float* __restrict__ dinv, int n) {
    __shared__ int s[256];
    int t = threadIdx.x;
    int i = blockIdx.x * 256 + t;
    int d = (i < n) ? deg[i] : 0;
    if (i < n) dinv[i] = rsqrtf((float)d + 1.0f);  // +1 self loop
    s[t] = d;
    __syncthreads();
#pragma unroll
    for (int off = 1; off < 256; off <<= 1) {
        int u = (t >= off) ? s[t - off] : 0;
        __syncthreads();
        s[t] += u;
        __syncthreads();
    }
    if (i < n) locscan[i] = s[t];
    if (t == 255) blocksum[blockIdx.x] = s[255];
}

__global__ __launch_bounds__(512) void scan2_kernel(int* __restrict__ blocksum, int nb) {
    __shared__ int s[512];
    int t = threadIdx.x;
    s[t] = (t < nb) ? blocksum[t] : 0;
    __syncthreads();
#pragma unroll
    for (int off = 1; off < 512; off <<= 1) {
        int u = (t >= off) ? s[t - off] : 0;
        __syncthreads();
        s[t] += u;
        __syncthreads();
    }
    if (t < nb) blocksum[t] = s[t];
}

__global__ __launch_bounds__(256) void scan3_kernel(const int* __restrict__ locscan,
                                                    const int* __restrict__ blocksum,
                                                    const int* __restrict__ deg,
                                                    int* __restrict__ rowoff,
                                                    int* __restrict__ cursor, int n) {
    int i = blockIdx.x * 256 + threadIdx.x;
    if (i >= n) return;
    int base = (blockIdx.x == 0) ? 0 : blocksum[blockIdx.x - 1];
    int incl = base + locscan[i];
    rowoff[i + 1] = incl;
    cursor[i] = incl - deg[i];
    if (i == 0) rowoff[0] = 0;
}

// bucket sort: epay[rowoff[dst]...] = {src, dinv[src]*dinv[dst]}
__global__ void sort_kernel(const void* __restrict__ ei, const int* __restrict__ flag,
                            const float* __restrict__ dinv, int* __restrict__ cursor,
                            int2* __restrict__ epay, int E) {
    int e = blockIdx.x * blockDim.x + threadIdx.x;
    if (e >= E) return;
    int src, dst;
    load_edge(ei, E, e, *flag, src, dst);
    float w = dinv[src] * dinv[dst];
    int pos = atomicAdd(&cursor[dst], 1);
    epay[pos] = make_int2(src, __float_as_int(w));
}

// W transpose+cast, both weights in one launch
__global__ void prepw_kernel(const float* __restrict__ W1, unsigned short* __restrict__ Wt1,
                             const float* __restrict__ W2, unsigned short* __restrict__ Wt2) {
    int i = blockIdx.x * 256 + threadIdx.x;
    if (i < 128 * 128) {
        int nidx = i >> 7, k = i & 127;
        Wt1[i] = f2bf(W1[k * HID + nidx]);
    } else if (i < 128 * 128 + 48 * 128) {
        int j = i - 128 * 128;
        int nidx = j >> 7, k = j & 127;
        Wt2[j] = (nidx < NCLS) ? f2bf(W2[k * NCLS + nidx]) : 0;
    }
}

// ---------------------------------------------------------------------------
// MFMA GEMM1: xw1[n x 128] (bf16) = bf16(X) @ bf16(W1)
// ---------------------------------------------------------------------------
__global__ __launch_bounds__(256) void gemm1_kernel(const float* __restrict__ X,
                                                    const unsigned short* __restrict__ Wt,
                                                    unsigned short* __restrict__ Y, int n) {
    __shared__ unsigned short Bs[128][136];
    const int t = threadIdx.x;
    for (int i = t; i < 128 * 16; i += 256) {
        int c = i >> 4, kc = (i & 15) << 3;
        *(int4*)&Bs[c][kc] = ((const int4*)Wt)[i];
    }
    __syncthreads();

    const int wv = t >> 6, lane = t & 63;
    const int lr = lane & 15, kg = lane >> 4;
    const int row0 = blockIdx.x * 64 + wv * 16;
    int arow = row0 + lr;
    if (arow >= n) arow = n - 1;
    const float* aptr = X + (size_t)arow * FIN + kg * 8;

    f32x4 acc[8];
#pragma unroll
    for (int nf = 0; nf < 8; ++nf) acc[nf] = (f32x4){0.f, 0.f, 0.f, 0.f};

#pragma unroll
    for (int kt = 0; kt < 4; ++kt) {
        float4 a0 = *(const float4*)(aptr + kt * 32);
        float4 a1 = *(const float4*)(aptr + kt * 32 + 4);
        short8v af;
        af[0] = (short)f2bf(a0.x); af[1] = (short)f2bf(a0.y);
        af[2] = (short)f2bf(a0.z); af[3] = (short)f2bf(a0.w);
        af[4] = (short)f2bf(a1.x); af[5] = (short)f2bf(a1.y);
        af[6] = (short)f2bf(a1.z); af[7] = (short)f2bf(a1.w);
#pragma unroll
        for (int nf = 0; nf < 8; ++nf) {
            short8v bf_ = *(const short8v*)&Bs[nf * 16 + lr][kt * 32 + kg * 8];
            acc[nf] = __builtin_amdgcn_mfma_f32_16x16x32_bf16(af, bf_, acc[nf], 0, 0, 0);
        }
    }
#pragma unroll
    for (int nf = 0; nf < 8; ++nf) {
        int col = nf * 16 + lr;
#pragma unroll
        for (int r = 0; r < 4; ++r) {
            int row = row0 + kg * 4 + r;
            if (row < n) Y[(size_t)row * HID + col] = f2bf(acc[nf][r]);
        }
    }
}

// ---------------------------------------------------------------------------
// MFMA GEMM2: xw2[n x 40 (bf16, stride 40)] = bf16(relu(out1_bf16 + b1)) @ bf16(W2)
// ---------------------------------------------------------------------------
__global__ __launch_bounds__(256) void gemm2_kernel(const unsigned short* __restrict__ Xin,
                                                    const unsigned short* __restrict__ Wt,
                                                    const float* __restrict__ b1,
                                                    unsigned short* __restrict__ Y, int n) {
    __shared__ unsigned short Bs[48][136];
    const int t = threadIdx.x;
    for (int i = t; i < 48 * 16; i += 256) {
        int c = i >> 4, kc = (i & 15) << 3;
        *(int4*)&Bs[c][kc] = ((const int4*)Wt)[i];
    }
    __syncthreads();

    const int wv = t >> 6, lane = t & 63;
    const int lr = lane & 15, kg = lane >> 4;
    const int row0 = blockIdx.x * 64 + wv * 16;
    int arow = row0 + lr;
    if (arow >= n) arow = n - 1;
    const unsigned short* aptr = Xin + (size_t)arow * HID + kg * 8;
    const float* bptr = b1 + kg * 8;

    f32x4 acc[3];
#pragma unroll
    for (int nf = 0; nf < 3; ++nf) acc[nf] = (f32x4){0.f, 0.f, 0.f, 0.f};

#pragma unroll
    for (int kt = 0; kt < 4; ++kt) {
        uint4 a = *(const uint4*)(aptr + kt * 32);  // 8 bf16
        float4 c0 = *(const float4*)(bptr + kt * 32);
        float4 c1 = *(const float4*)(bptr + kt * 32 + 4);
        short8v af;
        af[0] = (short)f2bf(fmaxf(bf2f(a.x & 0xffffu) + c0.x, 0.f));
        af[1] = (short)f2bf(fmaxf(bf2f(a.x >> 16)     + c0.y, 0.f));
        af[2] = (short)f2bf(fmaxf(bf2f(a.y & 0xffffu) + c0.z, 0.f));
        af[3] = (short)f2bf(fmaxf(bf2f(a.y >> 16)     + c0.w, 0.f));
        af[4] = (short)f2bf(fmaxf(bf2f(a.z & 0xffffu) + c1.x, 0.f));
        af[5] = (short)f2bf(fmaxf(bf2f(a.z >> 16)     + c1.y, 0.f));
        af[6] = (short)f2bf(fmaxf(bf2f(a.w & 0xffffu) + c1.z, 0.f));
        af[7] = (short)f2bf(fmaxf(bf2f(a.w >> 16)     + c1.w, 0.f));
#pragma unroll
        for (int nf = 0; nf < 3; ++nf) {
            short8v bf_ = *(const short8v*)&Bs[nf * 16 + lr][kt * 32 + kg * 8];
            acc[nf] = __builtin_amdgcn_mfma_f32_16x16x32_bf16(af, bf_, acc[nf], 0, 0, 0);
        }
    }
#pragma unroll
    for (int nf = 0; nf < 3; ++nf) {
        int col = nf * 16 + lr;
        if (col < NCLS) {
#pragma unroll
            for (int r = 0; r < 4; ++r) {
                int row = row0 + kg * 4 + r;
                if (row < n) Y[(size_t)row * NCLS + col] = f2bf(acc[nf][r]);
            }
        }
    }
}

// ---------------------------------------------------------------------------
// gather1: dual-edge — lanes 0-31 handle edge j, lanes 32-63 edge j+1.
// Each lane: uint2 (4 bf16) of its edge's 256B row. Merge halves at end.
// ---------------------------------------------------------------------------
__global__ __launch_bounds__(256) void gather1_kernel(const unsigned int* __restrict__ xw,
                                                      const float* __restrict__ dinv,
                                                      const int* __restrict__ rowoff,
                                                      const int2* __restrict__ epay,
                                                      unsigned int* __restrict__ out, int n) {
    int gw = (int)((blockIdx.x * 256u + threadIdx.x) >> 6);
    if (gw >= n) return;
    const int lane = threadIdx.x & 63;
    const int half = lane >> 5;
    const int q = lane & 31;  // dword-pair idx: classes 4q..4q+3
    float di = dinv[gw];
    int rs = rowoff[gw], re = rowoff[gw + 1];

    float a0 = 0.f, a1 = 0.f, a2 = 0.f, a3 = 0.f;
    if (half == 0) {  // self term counted once
        uint2 own = *(const uint2*)(xw + (size_t)gw * 64 + q * 2);
        float s2 = di * di;
        a0 = bf2f(own.x & 0xffffu) * s2;
        a1 = bf2f(own.x >> 16) * s2;
        a2 = bf2f(own.y & 0xffffu) * s2;
        a3 = bf2f(own.y >> 16) * s2;
    }

    for (int base = rs; base < re; base += 64) {
        int avail = re - base;
        int2 p = make_int2(0, 0);
        if (lane < avail) p = epay[base + lane];
        int cnt = (avail < 64) ? avail : 64;
        for (int j = 0; j < cnt; j += 4) {
            int slA = j + half;
            int slB = j + 2 + half;
            int sA = __shfl(p.x, slA & 63, 64);
            float wA = __int_as_float(__shfl(p.y, slA & 63, 64));
            int sB = __shfl(p.x, slB & 63, 64);
            float wB = __int_as_float(__shfl(p.y, slB & 63, 64));
            if (slA >= cnt) wA = 0.f;  // wraps map to valid rows; w=0 kills them
            if (slB >= cnt) wB = 0.f;
            uint2 vA = *(const uint2*)(xw + (size_t)sA * 64 + q * 2);
            uint2 vB = *(const uint2*)(xw + (size_t)sB * 64 + q * 2);
            a0 = fmaf(bf2f(vA.x & 0xffffu), wA, a0);
            a1 = fmaf(bf2f(vA.x >> 16),     wA, a1);
            a2 = fmaf(bf2f(vA.y & 0xffffu), wA, a2);
            a3 = fmaf(bf2f(vA.y >> 16),     wA, a3);
            a0 = fmaf(bf2f(vB.x & 0xffffu), wB, a0);
            a1 = fmaf(bf2f(vB.x >> 16),     wB, a1);
            a2 = fmaf(bf2f(vB.y & 0xffffu), wB, a2);
            a3 = fmaf(bf2f(vB.y >> 16),     wB, a3);
        }
    }
    a0 += __shfl(a0, lane ^ 32, 64);
    a1 += __shfl(a1, lane ^ 32, 64);
    a2 += __shfl(a2, lane ^ 32, 64);
    a3 += __shfl(a3, lane ^ 32, 64);
    if (half == 0) {
        uint2 o;
        o.x = (unsigned)f2bf(a0) | ((unsigned)f2bf(a1) << 16);
        o.y = (unsigned)f2bf(a2) | ((unsigned)f2bf(a3) << 16);
        *(uint2*)(out + (size_t)gw * 64 + q * 2) = o;
    }
}

// ---------------------------------------------------------------------------
// gather2: triple-edge — lane groups {0-19, 20-39, 40-59} each handle one
// edge (dword = 2 classes per lane, stride-40 bf16 rows). Cross-group
// reduce, then fused +b2 and log_softmax (20 lanes x 2 classes).
// ---------------------------------------------------------------------------
__global__ __launch_bounds__(256) void gather2_kernel(const unsigned int* __restrict__ xw,
                                                      const float* __restrict__ dinv,
                                                      const int* __restrict__ rowoff,
                                                      const int2* __restrict__ epay,
                                                      const float* __restrict__ b2,
                                                      float* __restrict__ out, int n) {
    int gw = (int)((blockIdx.x * 256u + threadIdx.x) >> 6);
    if (gw >= n) return;
    const int lane = threadIdx.x & 63;
    int g = lane / 20;                    // 0..3 (3 = idle)
    bool active = g < 3;
    int q = active ? (lane - g * 20) : 0; // class pair idx 0..19
    float di = dinv[gw];
    int rs = rowoff[gw], re = rowoff[gw + 1];

    float accx = 0.f, accy = 0.f;
    if (g == 0) {  // self term
        unsigned int v = xw[(size_t)gw * 20 + q];
        float s2 = di * di;
        accx = bf2f(v & 0xffffu) * s2;
        accy = bf2f(v >> 16) * s2;
    }

    for (int base = rs; base < re; base += 64) {
        int avail = re - base;
        int2 p = make_int2(0, 0);
        if (lane < avail) p = epay[base + lane];
        int cnt = (avail < 64) ? avail : 64;
        for (int j = 0; j < cnt; j += 6) {  // 6 edges per iter (2 rounds of 3)
            int slA = j + g;
            int slB = j + 3 + g;
            int sA = __shfl(p.x, slA & 63, 64);
            float wA = __int_as_float(__shfl(p.y, slA & 63, 64));
            int sB = __shfl(p.x, slB & 63, 64);
            float wB = __int_as_float(__shfl(p.y, slB & 63, 64));
            if (slA >= cnt || !active) wA = 0.f;
            if (slB >= cnt || !active) wB = 0.f;
            unsigned int vA = xw[(size_t)sA * 20 + q];
            unsigned int vB = xw[(size_t)sB * 20 + q];
            accx = fmaf(bf2f(vA & 0xffffu), wA, accx);
            accy = fmaf(bf2f(vA >> 16),     wA, accy);
            accx = fmaf(bf2f(vB & 0xffffu), wB, accx);
            accy = fmaf(bf2f(vB >> 16),     wB, accy);
        }
    }
    // sum the 3 groups into lanes 0..19 (shfl reads happen before writes)
    float t1 = __shfl(accx, (lane + 20) & 63, 64);
    float t2 = __shfl(accx, (lane + 40) & 63, 64);
    float u1 = __shfl(accy, (lane + 20) & 63, 64);
    float u2 = __shfl(accy, (lane + 40) & 63, 64);
    accx += t1 + t2;
    accy += u1 + u2;

    bool fin = lane < 20;
    float vx = -INFINITY, vy = -INFINITY;
    if (fin) {
        float2 bb = *(const float2*)&b2[q * 2];
        vx = accx + bb.x;
        vy = accy + bb.y;
    }
    float m = fmaxf(vx, vy);
#pragma unroll
    for (int off = 32; off >= 1; off >>= 1) m = fmaxf(m, __shfl_xor(m, off, 64));
    float es = fin ? (expf(vx - m) + expf(vy - m)) : 0.f;
#pragma unroll
    for (int off = 32; off >= 1; off >>= 1) es += __shfl_xor(es, off, 64);
    if (fin) {
        float ls = logf(es);
        *(float2*)&out[(size_t)gw * NCLS + q * 2] = make_float2(vx - m - ls, vy - m - ls);
    }
}

extern "C" void kernel_launch(void* const* d_in, const int* in_sizes, int n_in,
                              void* d_out, int out_size, void* d_ws, size_t ws_size,
                              hipStream_t stream) {
    const float* x  = (const float*)d_in[0];
    const void*  ei = d_in[1];
    const float* W1 = (const float*)d_in[2];
    const float* b1 = (const float*)d_in[3];
    const float* W2 = (const float*)d_in[4];
    const float* b2 = (const float*)d_in[5];
    float* out = (float*)d_out;

    const int n = in_sizes[0] / FIN;  // 100000
    const int E = in_sizes[1] / 2;    // 640000

    char* ws = (char*)d_ws;
    size_t off = 0;
    auto alloc = [&](size_t bytes) {
        size_t p = off;
        off += (bytes + 255) & ~(size_t)255;
        return p;
    };
    int*   deg    = (int*)(ws + alloc((size_t)n * 4));
    int*   flag   = (int*)(ws + alloc(256));
    float* dinv   = (float*)(ws + alloc((size_t)n * 4));
    int*   rowoff = (int*)(ws + alloc((size_t)(n + 1) * 4));
    int*   locscan= (int*)(ws + alloc((size_t)n * 4));
    int*   cursor = (int*)(ws + alloc((size_t)n * 4));
    int*   bsum   = (int*)(ws + alloc(512 * 4));
    unsigned short* wt1 = (unsigned short*)(ws + alloc(128 * 128 * 2));
    unsigned short* wt2 = (unsigned short*)(ws + alloc(48 * 128 * 2));
    int2*  epay   = (int2*)(ws + alloc((size_t)E * 8));
    unsigned short* xw1  = (unsigned short*)(ws + alloc((size_t)n * HID * 2));
    unsigned short* out1 = (unsigned short*)(ws + alloc((size_t)n * HID * 2));
    unsigned short* xw2  = xw1;  // n*40 bf16 fits in xw1 region, reused after gather1

    hipMemsetAsync(deg, 0, (size_t)n * 4, stream);
    hipMemsetAsync(flag, 0, 4, stream);

    const int npairs = (E < 2048) ? E : 2048;
    const int nb = (n + 255) / 256;  // 391 <= 512

    detect_kernel<<<(npairs + 255) / 256, 256, 0, stream>>>((const unsigned int*)ei, npairs, flag);
    deg_kernel<<<(E + 255) / 256, 256, 0, stream>>>(ei, E, flag, deg);
    prepw_kernel<<<(128 * 128 + 48 * 128 + 255) / 256, 256, 0, stream>>>(W1, wt1, W2, wt2);

    scan1_kernel<<<nb, 256, 0, stream>>>(deg, locscan, bsum, dinv, n);
    scan2_kernel<<<1, 512, 0, stream>>>(bsum, nb);
    scan3_kernel<<<nb, 256, 0, stream>>>(locscan, bsum, deg, rowoff, cursor, n);
    sort_kernel<<<(E + 255) / 256, 256, 0, stream>>>(ei, flag, dinv, cursor, epay, E);

    gemm1_kernel<<<(n + 63) / 64, 256, 0, stream>>>(x, wt1, xw1, n);
    gather1_kernel<<<(int)(((size_t)n * 64 + 255) / 256), 256, 0, stream>>>(
        (const unsigned int*)xw1, dinv, rowoff, epay, (unsigned int*)out1, n);

    gemm2_kernel<<<(n + 63) / 64, 256, 0, stream>>>(out1, wt2, b1, xw2, n);
    gather2_kernel<<<(int)(((size_t)n * 64 + 255) / 256), 256, 0, stream>>>(
        (const unsigned int*)xw2, dinv, rowoff, epay, b2, out, n);
}

// Round 6
// 267.838 us; speedup vs baseline: 3.3561x; 1.0043x over previous
//
#include <hip/hip_runtime.h>
#include <hip/hip_bf16.h>
#include <math.h>

#define FIN 128
#define HID 128
#define NCLS 40

typedef __attribute__((ext_vector_type(8))) short short8v;  // 8 bf16
typedef __attribute__((ext_vector_type(4))) float f32x4;

__device__ __forceinline__ unsigned short f2bf(float f) {
    unsigned int u = __float_as_uint(f);
    u += 0x7fffu + ((u >> 16) & 1u);  // RNE
    return (unsigned short)(u >> 16);
}
__device__ __forceinline__ float bflo(unsigned int v) {
    return __uint_as_float(v << 16);
}
__device__ __forceinline__ float bfhi(unsigned int v) {
    return __uint_as_float(v & 0xffff0000u);
}

__device__ __forceinline__ void load_edge(const void* ei, int E, int e, int is32,
                                          int& src, int& dst) {
    if (is32) {
        const int* p = (const int*)ei;
        src = p[e];
        dst = p[E + e];
    } else {
        const long long* p = (const long long*)ei;
        src = (int)p[e];
        dst = (int)p[E + e];
    }
}

// ---------------------------------------------------------------------------
// prep: block 0 = edge-dtype detect (int64 vs int32);
//       blocks 1..88 = weight transpose+bf16 cast;
//       blocks 89..479 = zero deg;  block 480 = zero rows xw1[n], xw2[n]
// ---------------------------------------------------------------------------
__global__ __launch_bounds__(256) void prep_kernel(const unsigned int* __restrict__ ei32,
                                                   int npairs, int* __restrict__ flag,
                                                   const float* __restrict__ W1,
                                                   unsigned short* __restrict__ Wt1,
                                                   const float* __restrict__ W2,
                                                   unsigned short* __restrict__ Wt2,
                                                   int* __restrict__ deg,
                                                   unsigned int* __restrict__ z1,
                                                   unsigned int* __restrict__ z2, int n) {
    const int b = blockIdx.x, t = threadIdx.x;
    if (b == 0) {
        unsigned int any = 0;
        for (int k = t; k < npairs; k += 256) any |= ei32[2 * k + 1];
        __shared__ int sf[4];
        unsigned long long ball = __ballot(any != 0);
        if ((t & 63) == 0) sf[t >> 6] = (ball != 0ull) ? 1 : 0;
        __syncthreads();
        if (t == 0) flag[0] = sf[0] | sf[1] | sf[2] | sf[3];
    } else if (b <= 88) {
        int i = (b - 1) * 256 + t;
        if (i < 128 * 128) {
            int nidx = i >> 7, k = i & 127;
            Wt1[i] = f2bf(W1[k * HID + nidx]);
        } else if (i < 128 * 128 + 48 * 128) {
            int j = i - 128 * 128;
            int nidx = j >> 7, k = j & 127;
            Wt2[j] = (nidx < NCLS) ? f2bf(W2[k * NCLS + nidx]) : 0;
        }
    } else if (b <= 479) {
        int i = (b - 89) * 256 + t;
        if (i < n) deg[i] = 0;
    } else {
        if (t < 64) z1[t] = 0;          // xw1 zero row (64 dwords)
        else if (t < 84) z2[t - 64] = 0;  // xw2 zero row (20 dwords)
    }
}

__global__ void deg_kernel(const void* __restrict__ ei, int E,
                           const int* __restrict__ flag, int* __restrict__ deg) {
    int e = blockIdx.x * blockDim.x + threadIdx.x;
    if (e >= E) return;
    int dst;
    if (*flag) dst = ((const int*)ei)[E + e];
    else       dst = (int)((const long long*)ei)[E + e];
    atomicAdd(&deg[dst], 1);
}

// ---------------- scan deg -> rowoff (+ dinv, + cursor) --------------------
__global__ __launch_bounds__(256) void scan1_kernel(const int* __restrict__ deg,
                                                    int* __restrict__ locscan,
                                                    int* __restrict__ blocksum,
                                                    float* __restrict__ dinv, int n) {
    __shared__ int s[256];
    int t = threadIdx.x;
    int i = blockIdx.x * 256 + t;
    int d = (i < n) ? deg[i] : 0;
    if (i < n) dinv[i] = rsqrtf((float)d + 1.0f);  // +1 self loop
    s[t] = d;
    __syncthreads();
#pragma unroll
    for (int off = 1; off < 256; off <<= 1) {
        int u = (t >= off) ? s[t - off] : 0;
        __syncthreads();
        s[t] += u;
        __syncthreads();
    }
    if (i < n) locscan[i] = s[t];
    if (t == 255) blocksum[blockIdx.x] = s[255];
}

__global__ __launch_bounds__(512) void scan2_kernel(int* __restrict__ blocksum, int nb) {
    __shared__ int s[512];
    int t = threadIdx.x;
    s[t] = (t < nb) ? blocksum[t] : 0;
    __syncthreads();
#pragma unroll
    for (int off = 1; off < 512; off <<= 1) {
        int u = (t >= off) ? s[t - off] : 0;
        __syncthreads();
        s[t] += u;
        __syncthreads();
    }
    if (t < nb) blocksum[t] = s[t];
}

__global__ __launch_bounds__(256) void scan3_kernel(const int* __restrict__ locscan,
                                                    const int* __restrict__ blocksum,
                                                    const int* __restrict__ deg,
                                                    int* __restrict__ rowoff,
                                                    int* __restrict__ cursor, int n) {
    int i = blockIdx.x * 256 + threadIdx.x;
    if (i >= n) return;
    int base = (blockIdx.x == 0) ? 0 : blocksum[blockIdx.x - 1];
    int incl = base + locscan[i];
    rowoff[i + 1] = incl;
    cursor[i] = incl - deg[i];
    if (i == 0) rowoff[0] = 0;
}

// bucket sort by dst: epay[rowoff[dst]...] = src  (no weight — folded into rows)
__global__ void sort_kernel(const void* __restrict__ ei, const int* __restrict__ flag,
                            int* __restrict__ cursor, int* __restrict__ epay, int E) {
    int e = blockIdx.x * blockDim.x + threadIdx.x;
    if (e >= E) return;
    int src, dst;
    load_edge(ei, E, e, *flag, src, dst);
    int pos = atomicAdd(&cursor[dst], 1);
    epay[pos] = src;
}

// ---------------------------------------------------------------------------
// MFMA GEMM1: xw1'[n x 128] (bf16) = dinv[row] * (bf16(X) @ bf16(W1))
// ---------------------------------------------------------------------------
__global__ __launch_bounds__(256) void gemm1_kernel(const float* __restrict__ X,
                                                    const unsigned short* __restrict__ Wt,
                                                    const float* __restrict__ dinv,
                                                    unsigned short* __restrict__ Y, int n) {
    __shared__ unsigned short Bs[128][136];
    const int t = threadIdx.x;
    for (int i = t; i < 128 * 16; i += 256) {
        int c = i >> 4, kc = (i & 15) << 3;
        *(int4*)&Bs[c][kc] = ((const int4*)Wt)[i];
    }
    __syncthreads();

    const int wv = t >> 6, lane = t & 63;
    const int lr = lane & 15, kg = lane >> 4;
    const int row0 = blockIdx.x * 64 + wv * 16;
    int arow = row0 + lr;
    if (arow >= n) arow = n - 1;
    const float* aptr = X + (size_t)arow * FIN + kg * 8;

    f32x4 acc[8];
#pragma unroll
    for (int nf = 0; nf < 8; ++nf) acc[nf] = (f32x4){0.f, 0.f, 0.f, 0.f};

#pragma unroll
    for (int kt = 0; kt < 4; ++kt) {
        float4 a0 = *(const float4*)(aptr + kt * 32);
        float4 a1 = *(const float4*)(aptr + kt * 32 + 4);
        short8v af;
        af[0] = (short)f2bf(a0.x); af[1] = (short)f2bf(a0.y);
        af[2] = (short)f2bf(a0.z); af[3] = (short)f2bf(a0.w);
        af[4] = (short)f2bf(a1.x); af[5] = (short)f2bf(a1.y);
        af[6] = (short)f2bf(a1.z); af[7] = (short)f2bf(a1.w);
#pragma unroll
        for (int nf = 0; nf < 8; ++nf) {
            short8v bf_ = *(const short8v*)&Bs[nf * 16 + lr][kt * 32 + kg * 8];
            acc[nf] = __builtin_amdgcn_mfma_f32_16x16x32_bf16(af, bf_, acc[nf], 0, 0, 0);
        }
    }
    float4 d4 = *(const float4*)&dinv[row0 + kg * 4];  // rows row0+kg*4..+3
    float dv[4] = {d4.x, d4.y, d4.z, d4.w};
#pragma unroll
    for (int nf = 0; nf < 8; ++nf) {
        int col = nf * 16 + lr;
#pragma unroll
        for (int r = 0; r < 4; ++r) {
            int row = row0 + kg * 4 + r;
            if (row < n) Y[(size_t)row * HID + col] = f2bf(acc[nf][r] * dv[r]);
        }
    }
}

// ---------------------------------------------------------------------------
// MFMA GEMM2: xw2'[n x 40] (bf16, stride 40) = dinv[row]*(out1 @ bf16(W2))
// out1 is pre-activated bf16 (relu+bias fused in gather1) -> raw A loads
// ---------------------------------------------------------------------------
__global__ __launch_bounds__(256) void gemm2_kernel(const unsigned short* __restrict__ Xin,
                                                    const unsigned short* __restrict__ Wt,
                                                    const float* __restrict__ dinv,
                                                    unsigned short* __restrict__ Y, int n) {
    __shared__ unsigned short Bs[48][136];
    const int t = threadIdx.x;
    for (int i = t; i < 48 * 16; i += 256) {
        int c = i >> 4, kc = (i & 15) << 3;
        *(int4*)&Bs[c][kc] = ((const int4*)Wt)[i];
    }
    __syncthreads();

    const int wv = t >> 6, lane = t & 63;
    const int lr = lane & 15, kg = lane >> 4;
    const int row0 = blockIdx.x * 64 + wv * 16;
    int arow = row0 + lr;
    if (arow >= n) arow = n - 1;
    const unsigned short* aptr = Xin + (size_t)arow * HID + kg * 8;

    f32x4 acc[3];
#pragma unroll
    for (int nf = 0; nf < 3; ++nf) acc[nf] = (f32x4){0.f, 0.f, 0.f, 0.f};

#pragma unroll
    for (int kt = 0; kt < 4; ++kt) {
        short8v af = *(const short8v*)(aptr + kt * 32);
#pragma unroll
        for (int nf = 0; nf < 3; ++nf) {
            short8v bf_ = *(const short8v*)&Bs[nf * 16 + lr][kt * 32 + kg * 8];
            acc[nf] = __builtin_amdgcn_mfma_f32_16x16x32_bf16(af, bf_, acc[nf], 0, 0, 0);
        }
    }
    float4 d4 = *(const float4*)&dinv[row0 + kg * 4];
    float dv[4] = {d4.x, d4.y, d4.z, d4.w};
#pragma unroll
    for (int nf = 0; nf < 3; ++nf) {
        int col = nf * 16 + lr;
        if (col < NCLS) {
#pragma unroll
            for (int r = 0; r < 4; ++r) {
                int row = row0 + kg * 4 + r;
                if (row < n) Y[(size_t)row * NCLS + col] = f2bf(acc[nf][r] * dv[r]);
            }
        }
    }
}

// ---------------------------------------------------------------------------
// gather1: acc = xw1'[i] + sum_e xw1'[src_e];  out1 = bf16(relu(dinv_i*acc + b1))
// dual-edge halves (lanes 0-31 / 32-63), uint2 = 4 feats per lane, no weights
// ---------------------------------------------------------------------------
__global__ __launch_bounds__(256) void gather1_kernel(const unsigned int* __restrict__ xw,
                                                      const float* __restrict__ dinv,
                                                      const int* __restrict__ rowoff,
                                                      const int* __restrict__ epay,
                                                      const float* __restrict__ b1,
                                                      unsigned int* __restrict__ out, int n) {
    int gw = (int)((blockIdx.x * 256u + threadIdx.x) >> 6);
    if (gw >= n) return;
    const int lane = threadIdx.x & 63;
    const int half = lane >> 5;
    const int q = lane & 31;  // feats 4q..4q+3
    float di = dinv[gw];
    int rs = rowoff[gw], re = rowoff[gw + 1];

    float a0 = 0.f, a1 = 0.f, a2 = 0.f, a3 = 0.f;
    if (half == 0) {  // self row joins the sum unscaled
        uint2 own = *(const uint2*)(xw + (size_t)gw * 64 + q * 2);
        a0 = bflo(own.x); a1 = bfhi(own.x);
        a2 = bflo(own.y); a3 = bfhi(own.y);
    }

    for (int base = rs; base < re; base += 64) {
        int avail = re - base;
        int cnt = (avail < 64) ? avail : 64;
        int px = (lane < cnt) ? epay[base + lane] : n;  // OOB slots -> zero row
        for (int j = 0; j < cnt; j += 4) {
            int sA = __shfl(px, j + half, 64);
            int sB = __shfl(px, j + 2 + half, 64);
            uint2 vA = *(const uint2*)(xw + (size_t)sA * 64 + q * 2);
            uint2 vB = *(const uint2*)(xw + (size_t)sB * 64 + q * 2);
            a0 += bflo(vA.x); a1 += bfhi(vA.x);
            a2 += bflo(vA.y); a3 += bfhi(vA.y);
            a0 += bflo(vB.x); a1 += bfhi(vB.x);
            a2 += bflo(vB.y); a3 += bfhi(vB.y);
        }
    }
    a0 += __shfl(a0, lane ^ 32, 64);
    a1 += __shfl(a1, lane ^ 32, 64);
    a2 += __shfl(a2, lane ^ 32, 64);
    a3 += __shfl(a3, lane ^ 32, 64);
    if (half == 0) {
        float4 bb = *(const float4*)&b1[q * 4];
        float r0 = fmaxf(fmaf(a0, di, bb.x), 0.f);
        float r1 = fmaxf(fmaf(a1, di, bb.y), 0.f);
        float r2 = fmaxf(fmaf(a2, di, bb.z), 0.f);
        float r3 = fmaxf(fmaf(a3, di, bb.w), 0.f);
        uint2 o;
        o.x = (unsigned)f2bf(r0) | ((unsigned)f2bf(r1) << 16);
        o.y = (unsigned)f2bf(r2) | ((unsigned)f2bf(r3) << 16);
        *(uint2*)(out + (size_t)gw * 64 + q * 2) = o;
    }
}

// ---------------------------------------------------------------------------
// gather2: logits = dinv_i*(xw2'[i] + sum_e xw2'[src_e]) + b2; log_softmax.
// 3 groups x 20 lanes, blocks of 60 edge slots, no weights, no masks.
// ---------------------------------------------------------------------------
__global__ __launch_bounds__(256) void gather2_kernel(const unsigned int* __restrict__ xw,
                                                      const float* __restrict__ dinv,
                                                      const int* __restrict__ rowoff,
                                                      const int* __restrict__ epay,
                                                      const float* __restrict__ b2,
                                                      float* __restrict__ out, int n) {
    int gw = (int)((blockIdx.x * 256u + threadIdx.x) >> 6);
    if (gw >= n) return;
    const int lane = threadIdx.x & 63;
    const int g = lane / 20;                     // 0..3 (3 mostly idle)
    const int q = lane - g * 20;                 // class pair 0..19 (g=3: 0..3)
    float di = dinv[gw];
    int rs = rowoff[gw], re = rowoff[gw + 1];

    float accx = 0.f, accy = 0.f;
    if (g == 0) {  // self row
        unsigned int v = xw[(size_t)gw * 20 + q];
        accx = bflo(v); accy = bfhi(v);
    }

    for (int base = rs; base < re; base += 60) {
        int avail = re - base;
        int cnt = (avail < 60) ? avail : 60;
        int px = (lane < cnt) ? epay[base + lane] : n;  // slots 0..59 only
        for (int j = 0; j < cnt; j += 6) {
            int sA = __shfl(px, j + g, 64);       // max slot 54+3+2=59
            int sB = __shfl(px, j + 3 + g, 64);   // g=3 may hit 60..63 -> px=n
            unsigned int vA = xw[(size_t)sA * 20 + q];
            unsigned int vB = xw[(size_t)sB * 20 + q];
            accx += bflo(vA); accy += bfhi(vA);
            accx += bflo(vB); accy += bfhi(vB);
        }
    }
    // reduce 3 groups into lanes 0..19
    float t1 = __shfl(accx, (lane + 20) & 63, 64);
    float t2 = __shfl(accx, (lane + 40) & 63, 64);
    float u1 = __shfl(accy, (lane + 20) & 63, 64);
    float u2 = __shfl(accy, (lane + 40) & 63, 64);
    accx += t1 + t2;
    accy += u1 + u2;

    bool fin = lane < 20;
    float vx = -INFINITY, vy = -INFINITY;
    if (fin) {
        float2 bb = *(const float2*)&b2[q * 2];
        vx = fmaf(accx, di, bb.x);
        vy = fmaf(accy, di, bb.y);
    }
    // 5-round reduce over lanes 0..31 (values live in 0..19; 20..31 neutral)
    float m = fmaxf(vx, vy);
#pragma unroll
    for (int off = 16; off >= 1; off >>= 1) m = fmaxf(m, __shfl_xor(m, off, 64));
    float es = fin ? (expf(vx - m) + expf(vy - m)) : 0.f;
#pragma unroll
    for (int off = 16; off >= 1; off >>= 1) es += __shfl_xor(es, off, 64);
    if (fin) {
        float ls = logf(es);
        *(float2*)&out[(size_t)gw * NCLS + q * 2] = make_float2(vx - m - ls, vy - m - ls);
    }
}

extern "C" void kernel_launch(void* const* d_in, const int* in_sizes, int n_in,
                              void* d_out, int out_size, void* d_ws, size_t ws_size,
                              hipStream_t stream) {
    const float* x  = (const float*)d_in[0];
    const void*  ei = d_in[1];
    const float* W1 = (const float*)d_in[2];
    const float* b1 = (const float*)d_in[3];
    const float* W2 = (const float*)d_in[4];
    const float* b2 = (const float*)d_in[5];
    float* out = (float*)d_out;

    const int n = in_sizes[0] / FIN;  // 100000
    const int E = in_sizes[1] / 2;    // 640000

    char* ws = (char*)d_ws;
    size_t off = 0;
    auto alloc = [&](size_t bytes) {
        size_t p = off;
        off += (bytes + 255) & ~(size_t)255;
        return p;
    };
    int*   deg    = (int*)(ws + alloc((size_t)n * 4));
    int*   flag   = (int*)(ws + alloc(256));
    float* dinv   = (float*)(ws + alloc((size_t)n * 4));
    int*   rowoff = (int*)(ws + alloc((size_t)(n + 1) * 4));
    int*   locscan= (int*)(ws + alloc((size_t)n * 4));
    int*   cursor = (int*)(ws + alloc((size_t)n * 4));
    int*   bsum   = (int*)(ws + alloc(512 * 4));
    unsigned short* wt1 = (unsigned short*)(ws + alloc(128 * 128 * 2));
    unsigned short* wt2 = (unsigned short*)(ws + alloc(48 * 128 * 2));
    int*   epay   = (int*)(ws + alloc((size_t)E * 4));
    unsigned short* xw1  = (unsigned short*)(ws + alloc((size_t)(n + 1) * HID * 2));
    unsigned short* out1 = (unsigned short*)(ws + alloc((size_t)n * HID * 2));
    unsigned short* xw2  = (unsigned short*)(ws + alloc((size_t)(n + 1) * NCLS * 2));

    const int npairs = (E < 2048) ? E : 2048;
    const int nb = (n + 255) / 256;  // 391 <= 512

    prep_kernel<<<89 + nb + 1, 256, 0, stream>>>(
        (const unsigned int*)ei, npairs, flag, W1, wt1, W2, wt2, deg,
        (unsigned int*)(xw1 + (size_t)n * HID), (unsigned int*)(xw2 + (size_t)n * NCLS), n);
    deg_kernel<<<(E + 255) / 256, 256, 0, stream>>>(ei, E, flag, deg);

    scan1_kernel<<<nb, 256, 0, stream>>>(deg, locscan, bsum, dinv, n);
    scan2_kernel<<<1, 512, 0, stream>>>(bsum, nb);
    scan3_kernel<<<nb, 256, 0, stream>>>(locscan, bsum, deg, rowoff, cursor, n);
    sort_kernel<<<(E + 255) / 256, 256, 0, stream>>>(ei, flag, cursor, epay, E);

    gemm1_kernel<<<(n + 63) / 64, 256, 0, stream>>>(x, wt1, dinv, xw1, n);
    gather1_kernel<<<(int)(((size_t)n * 64 + 255) / 256), 256, 0, stream>>>(
        (const unsigned int*)xw1, dinv, rowoff, epay, b1, (unsigned int*)out1, n);

    gemm2_kernel<<<(n + 63) / 64, 256, 0, stream>>>(out1, wt2, dinv, xw2, n);
    gather2_kernel<<<(int)(((size_t)n * 64 + 255) / 256), 256, 0, stream>>>(
        (const unsigned int*)xw2, dinv, rowoff, epay, b2, out, n);
}

// Round 7
// 226.745 us; speedup vs baseline: 3.9643x; 1.1812x over previous
//
#include <hip/hip_runtime.h>
#include <hip/hip_bf16.h>
#include <math.h>

#define FIN 128
#define HID 128
#define NCLS 40

typedef __attribute__((ext_vector_type(8))) short short8v;  // 8 bf16
typedef __attribute__((ext_vector_type(4))) float f32x4;

__device__ __forceinline__ unsigned short f2bf(float f) {
    unsigned int u = __float_as_uint(f);
    u += 0x7fffu + ((u >> 16) & 1u);  // RNE
    return (unsigned short)(u >> 16);
}
__device__ __forceinline__ float bflo(unsigned int v) {
    return __uint_as_float(v << 16);
}
__device__ __forceinline__ float bfhi(unsigned int v) {
    return __uint_as_float(v & 0xffff0000u);
}

__device__ __forceinline__ void load_edge(const void* ei, int E, int e, int is32,
                                          int& src, int& dst) {
    if (is32) {
        const int* p = (const int*)ei;
        src = p[e];
        dst = p[E + e];
    } else {
        const long long* p = (const long long*)ei;
        src = (int)p[e];
        dst = (int)p[E + e];
    }
}

// ---------------------------------------------------------------------------
// prep: block 0 = edge-dtype detect; blocks 1..88 = weight transpose+cast;
// block 89 = zero rows xw1[n], xw2[n]
// ---------------------------------------------------------------------------
__global__ __launch_bounds__(256) void prep_kernel(const unsigned int* __restrict__ ei32,
                                                   int npairs, int* __restrict__ flag,
                                                   const float* __restrict__ W1,
                                                   unsigned short* __restrict__ Wt1,
                                                   const float* __restrict__ W2,
                                                   unsigned short* __restrict__ Wt2,
                                                   unsigned int* __restrict__ z1,
                                                   unsigned int* __restrict__ z2) {
    const int b = blockIdx.x, t = threadIdx.x;
    if (b == 0) {
        unsigned int any = 0;
        for (int k = t; k < npairs; k += 256) any |= ei32[2 * k + 1];
        __shared__ int sf[4];
        unsigned long long ball = __ballot(any != 0);
        if ((t & 63) == 0) sf[t >> 6] = (ball != 0ull) ? 1 : 0;
        __syncthreads();
        if (t == 0) flag[0] = sf[0] | sf[1] | sf[2] | sf[3];
    } else if (b <= 88) {
        int i = (b - 1) * 256 + t;
        if (i < 128 * 128) {
            int nidx = i >> 7, k = i & 127;
            Wt1[i] = f2bf(W1[k * HID + nidx]);
        } else if (i < 128 * 128 + 48 * 128) {
            int j = i - 128 * 128;
            int nidx = j >> 7, k = j & 127;
            Wt2[j] = (nidx < NCLS) ? f2bf(W2[k * NCLS + nidx]) : 0;
        }
    } else {
        if (t < 64) z1[t] = 0;            // xw1 zero row (64 dwords)
        else if (t < 84) z2[t - 64] = 0;  // xw2 zero row (20 dwords)
    }
}

// ---------------------------------------------------------------------------
// K1: per-block LDS histogram over coarse buckets (dst>>8). 256 blocks fixed.
// blkhist[blk*nbk + i] written coalesced.
// ---------------------------------------------------------------------------
__global__ __launch_bounds__(256) void hist_kernel(const void* __restrict__ ei, int E,
                                                   const int* __restrict__ flag,
                                                   int* __restrict__ blkhist, int nbk) {
    __shared__ int lh[512];
    const int t = threadIdx.x, blk = blockIdx.x;
    for (int i = t; i < nbk; i += 256) lh[i] = 0;
    __syncthreads();
    const int is32 = *flag;
    for (int e = blk * 256 + t; e < E; e += 256 * 256) {
        int dst;
        if (is32) dst = ((const int*)ei)[E + e];
        else      dst = (int)((const long long*)ei)[E + e];
        atomicAdd(&lh[dst >> 8], 1);
    }
    __syncthreads();
    for (int i = t; i < nbk; i += 256) blkhist[blk * nbk + i] = lh[i];
}

// ---------------------------------------------------------------------------
// K2: per-bucket exclusive scan over the 256 block counts.
// reads strided, writes blkbase[b*256 + t] coalesced; btotal[b].
// ---------------------------------------------------------------------------
__global__ __launch_bounds__(256) void bscan_kernel(const int* __restrict__ blkhist,
                                                    int* __restrict__ blkbase,
                                                    int* __restrict__ btotal, int nbk) {
    __shared__ int s[256];
    const int t = threadIdx.x, b = blockIdx.x;
    int v = blkhist[t * nbk + b];
    s[t] = v;
    __syncthreads();
#pragma unroll
    for (int off = 1; off < 256; off <<= 1) {
        int u = (t >= off) ? s[t - off] : 0;
        __syncthreads();
        s[t] += u;
        __syncthreads();
    }
    blkbase[b * 256 + t] = s[t] - v;  // exclusive
    if (t == 255) btotal[b] = s[255];
}

// ---------------------------------------------------------------------------
// K3: exclusive scan of bucket totals -> bbase[0..nbk], bbase[nbk]=E
// ---------------------------------------------------------------------------
__global__ __launch_bounds__(512) void base_kernel(const int* __restrict__ btotal,
                                                   int* __restrict__ bbase, int nbk) {
    __shared__ int s[512];
    const int t = threadIdx.x;
    int v = (t < nbk) ? btotal[t] : 0;
    s[t] = v;
    __syncthreads();
#pragma unroll
    for (int off = 1; off < 512; off <<= 1) {
        int u = (t >= off) ? s[t - off] : 0;
        __syncthreads();
        s[t] += u;
        __syncthreads();
    }
    if (t < nbk) bbase[t] = s[t] - v;
    if (t == nbk - 1) bbase[nbk] = s[t];
}

// ---------------------------------------------------------------------------
// K4: scatter edges into coarse buckets. Each block owns exact private slices
// (from K1 counts) -> LDS cursors, no global atomics. pairs = src | dstLow<<17.
// ---------------------------------------------------------------------------
__global__ __launch_bounds__(256) void scatter_kernel(const void* __restrict__ ei, int E,
                                                      const int* __restrict__ flag,
                                                      const int* __restrict__ blkbase,
                                                      const int* __restrict__ bbase,
                                                      unsigned int* __restrict__ pairs,
                                                      int nbk) {
    __shared__ int lcur[512];
    const int t = threadIdx.x, blk = blockIdx.x;
    for (int i = t; i < nbk; i += 256) lcur[i] = bbase[i] + blkbase[i * 256 + blk];
    __syncthreads();
    const int is32 = *flag;
    for (int e = blk * 256 + t; e < E; e += 256 * 256) {
        int src, dst;
        load_edge(ei, E, e, is32, src, dst);
        int pos = atomicAdd(&lcur[dst >> 8], 1);
        pairs[pos] = (unsigned int)src | ((unsigned int)(dst & 255) << 17);
    }
}

// ---------------------------------------------------------------------------
// K5: finalize per bucket: fine deg (LDS), dinv, rowoff, dst-sorted epay.
// All global writes land in this block's contiguous region.
// ---------------------------------------------------------------------------
__global__ __launch_bounds__(256) void fin_kernel(const unsigned int* __restrict__ pairs,
                                                  const int* __restrict__ bbase,
                                                  float* __restrict__ dinv,
                                                  int* __restrict__ rowoff,
                                                  int* __restrict__ epay, int n) {
    __shared__ int deg[256];
    __shared__ int s[256];
    __shared__ int cur[256];
    const int t = threadIdx.x, b = blockIdx.x;
    deg[t] = 0;
    __syncthreads();
    const int start = bbase[b], end = bbase[b + 1];
    for (int k = start + t; k < end; k += 256) atomicAdd(&deg[pairs[k] >> 17], 1);
    __syncthreads();
    int d = deg[t];
    s[t] = d;
    __syncthreads();
#pragma unroll
    for (int off = 1; off < 256; off <<= 1) {
        int u = (t >= off) ? s[t - off] : 0;
        __syncthreads();
        s[t] += u;
        __syncthreads();
    }
    int gi = b * 256 + t;
    if (gi < n) {
        dinv[gi] = rsqrtf((float)d + 1.0f);  // +1 self loop
        rowoff[gi + 1] = start + s[t];
    }
    if (gi == 0) rowoff[0] = 0;
    cur[t] = s[t] - d;  // bucket-local exclusive
    __syncthreads();
    for (int k = start + t; k < end; k += 256) {
        unsigned int p = pairs[k];
        int dl = p >> 17;
        int pos = start + atomicAdd(&cur[dl], 1);
        epay[pos] = (int)(p & 0x1FFFFu);
    }
}

// ---------------------------------------------------------------------------
// MFMA GEMM1: xw1'[n x 128] (bf16) = dinv[row] * (bf16(X) @ bf16(W1))
// ---------------------------------------------------------------------------
__global__ __launch_bounds__(256) void gemm1_kernel(const float* __restrict__ X,
                                                    const unsigned short* __restrict__ Wt,
                                                    const float* __restrict__ dinv,
                                                    unsigned short* __restrict__ Y, int n) {
    __shared__ unsigned short Bs[128][136];
    const int t = threadIdx.x;
    for (int i = t; i < 128 * 16; i += 256) {
        int c = i >> 4, kc = (i & 15) << 3;
        *(int4*)&Bs[c][kc] = ((const int4*)Wt)[i];
    }
    __syncthreads();

    const int wv = t >> 6, lane = t & 63;
    const int lr = lane & 15, kg = lane >> 4;
    const int row0 = blockIdx.x * 64 + wv * 16;
    int arow = row0 + lr;
    if (arow >= n) arow = n - 1;
    const float* aptr = X + (size_t)arow * FIN + kg * 8;

    f32x4 acc[8];
#pragma unroll
    for (int nf = 0; nf < 8; ++nf) acc[nf] = (f32x4){0.f, 0.f, 0.f, 0.f};

#pragma unroll
    for (int kt = 0; kt < 4; ++kt) {
        float4 a0 = *(const float4*)(aptr + kt * 32);
        float4 a1 = *(const float4*)(aptr + kt * 32 + 4);
        short8v af;
        af[0] = (short)f2bf(a0.x); af[1] = (short)f2bf(a0.y);
        af[2] = (short)f2bf(a0.z); af[3] = (short)f2bf(a0.w);
        af[4] = (short)f2bf(a1.x); af[5] = (short)f2bf(a1.y);
        af[6] = (short)f2bf(a1.z); af[7] = (short)f2bf(a1.w);
#pragma unroll
        for (int nf = 0; nf < 8; ++nf) {
            short8v bf_ = *(const short8v*)&Bs[nf * 16 + lr][kt * 32 + kg * 8];
            acc[nf] = __builtin_amdgcn_mfma_f32_16x16x32_bf16(af, bf_, acc[nf], 0, 0, 0);
        }
    }
    float4 d4 = *(const float4*)&dinv[row0 + kg * 4];
    float dv[4] = {d4.x, d4.y, d4.z, d4.w};
#pragma unroll
    for (int nf = 0; nf < 8; ++nf) {
        int col = nf * 16 + lr;
#pragma unroll
        for (int r = 0; r < 4; ++r) {
            int row = row0 + kg * 4 + r;
            if (row < n) Y[(size_t)row * HID + col] = f2bf(acc[nf][r] * dv[r]);
        }
    }
}

// ---------------------------------------------------------------------------
// MFMA GEMM2: xw2'[n x 40] (bf16, stride 40) = dinv[row]*(out1 @ bf16(W2))
// ---------------------------------------------------------------------------
__global__ __launch_bounds__(256) void gemm2_kernel(const unsigned short* __restrict__ Xin,
                                                    const unsigned short* __restrict__ Wt,
                                                    const float* __restrict__ dinv,
                                                    unsigned short* __restrict__ Y, int n) {
    __shared__ unsigned short Bs[48][136];
    const int t = threadIdx.x;
    for (int i = t; i < 48 * 16; i += 256) {
        int c = i >> 4, kc = (i & 15) << 3;
        *(int4*)&Bs[c][kc] = ((const int4*)Wt)[i];
    }
    __syncthreads();

    const int wv = t >> 6, lane = t & 63;
    const int lr = lane & 15, kg = lane >> 4;
    const int row0 = blockIdx.x * 64 + wv * 16;
    int arow = row0 + lr;
    if (arow >= n) arow = n - 1;
    const unsigned short* aptr = Xin + (size_t)arow * HID + kg * 8;

    f32x4 acc[3];
#pragma unroll
    for (int nf = 0; nf < 3; ++nf) acc[nf] = (f32x4){0.f, 0.f, 0.f, 0.f};

#pragma unroll
    for (int kt = 0; kt < 4; ++kt) {
        short8v af = *(const short8v*)(aptr + kt * 32);
#pragma unroll
        for (int nf = 0; nf < 3; ++nf) {
            short8v bf_ = *(const short8v*)&Bs[nf * 16 + lr][kt * 32 + kg * 8];
            acc[nf] = __builtin_amdgcn_mfma_f32_16x16x32_bf16(af, bf_, acc[nf], 0, 0, 0);
        }
    }
    float4 d4 = *(const float4*)&dinv[row0 + kg * 4];
    float dv[4] = {d4.x, d4.y, d4.z, d4.w};
#pragma unroll
    for (int nf = 0; nf < 3; ++nf) {
        int col = nf * 16 + lr;
        if (col < NCLS) {
#pragma unroll
            for (int r = 0; r < 4; ++r) {
                int row = row0 + kg * 4 + r;
                if (row < n) Y[(size_t)row * NCLS + col] = f2bf(acc[nf][r] * dv[r]);
            }
        }
    }
}

// ---------------------------------------------------------------------------
// gather1: 4 groups x 16 lanes; each group one edge; uint4 = 8 feats/lane.
// out1 = bf16(relu(dinv_i*(self + sum_src) + b1))
// ---------------------------------------------------------------------------
__global__ __launch_bounds__(256) void gather1_kernel(const uint4* __restrict__ xw,
                                                      const float* __restrict__ dinv,
                                                      const int* __restrict__ rowoff,
                                                      const int* __restrict__ epay,
                                                      const float* __restrict__ b1,
                                                      uint4* __restrict__ out, int n) {
    int gw = (int)((blockIdx.x * 256u + threadIdx.x) >> 6);
    if (gw >= n) return;
    const int lane = threadIdx.x & 63;
    const int g = lane >> 4;  // group 0..3
    const int q = lane & 15;  // 16B chunk (feats q*8..q*8+7)
    int rs = rowoff[gw], re = rowoff[gw + 1];

    float a0 = 0.f, a1 = 0.f, a2 = 0.f, a3 = 0.f;
    float a4 = 0.f, a5 = 0.f, a6 = 0.f, a7 = 0.f;
    if (g == 0) {
        uint4 v = xw[(size_t)gw * 16 + q];
        a0 = bflo(v.x); a1 = bfhi(v.x); a2 = bflo(v.y); a3 = bfhi(v.y);
        a4 = bflo(v.z); a5 = bfhi(v.z); a6 = bflo(v.w); a7 = bfhi(v.w);
    }

    for (int base = rs; base < re; base += 64) {
        int avail = re - base;
        int cnt = (avail < 64) ? avail : 64;
        int px = (lane < cnt) ? epay[base + lane] : n;  // OOB -> zero row
        for (int j = 0; j < cnt; j += 8) {
            int sA = __shfl(px, j + g, 64);
            int sB = __shfl(px, j + 4 + g, 64);
            uint4 vA = xw[(size_t)sA * 16 + q];
            uint4 vB = xw[(size_t)sB * 16 + q];
            a0 += bflo(vA.x); a1 += bfhi(vA.x); a2 += bflo(vA.y); a3 += bfhi(vA.y);
            a4 += bflo(vA.z); a5 += bfhi(vA.z); a6 += bflo(vA.w); a7 += bfhi(vA.w);
            a0 += bflo(vB.x); a1 += bfhi(vB.x); a2 += bflo(vB.y); a3 += bfhi(vB.y);
            a4 += bflo(vB.z); a5 += bfhi(vB.z); a6 += bflo(vB.w); a7 += bfhi(vB.w);
        }
    }
    a0 += __shfl_xor(a0, 16, 64); a1 += __shfl_xor(a1, 16, 64);
    a2 += __shfl_xor(a2, 16, 64); a3 += __shfl_xor(a3, 16, 64);
    a4 += __shfl_xor(a4, 16, 64); a5 += __shfl_xor(a5, 16, 64);
    a6 += __shfl_xor(a6, 16, 64); a7 += __shfl_xor(a7, 16, 64);
    a0 += __shfl_xor(a0, 32, 64); a1 += __shfl_xor(a1, 32, 64);
    a2 += __shfl_xor(a2, 32, 64); a3 += __shfl_xor(a3, 32, 64);
    a4 += __shfl_xor(a4, 32, 64); a5 += __shfl_xor(a5, 32, 64);
    a6 += __shfl_xor(a6, 32, 64); a7 += __shfl_xor(a7, 32, 64);
    if (g == 0) {
        float di = dinv[gw];
        float4 ba = *(const float4*)&b1[q * 8];
        float4 bb = *(const float4*)&b1[q * 8 + 4];
        float r0 = fmaxf(fmaf(a0, di, ba.x), 0.f);
        float r1 = fmaxf(fmaf(a1, di, ba.y), 0.f);
        float r2 = fmaxf(fmaf(a2, di, ba.z), 0.f);
        float r3 = fmaxf(fmaf(a3, di, ba.w), 0.f);
        float r4 = fmaxf(fmaf(a4, di, bb.x), 0.f);
        float r5 = fmaxf(fmaf(a5, di, bb.y), 0.f);
        float r6 = fmaxf(fmaf(a6, di, bb.z), 0.f);
        float r7 = fmaxf(fmaf(a7, di, bb.w), 0.f);
        uint4 o;
        o.x = (unsigned)f2bf(r0) | ((unsigned)f2bf(r1) << 16);
        o.y = (unsigned)f2bf(r2) | ((unsigned)f2bf(r3) << 16);
        o.z = (unsigned)f2bf(r4) | ((unsigned)f2bf(r5) << 16);
        o.w = (unsigned)f2bf(r6) | ((unsigned)f2bf(r7) << 16);
        out[(size_t)gw * 16 + q] = o;
    }
}

// ---------------------------------------------------------------------------
// gather2: 6 groups x 10 lanes; each group one edge; uint2 = 4 classes/lane.
// logits = dinv_i*(self + sum) + b2; fused log_softmax; float4 store.
// ---------------------------------------------------------------------------
__global__ __launch_bounds__(256) void gather2_kernel(const uint2* __restrict__ xw,
                                                      const float* __restrict__ dinv,
                                                      const int* __restrict__ rowoff,
                                                      const int* __restrict__ epay,
                                                      const float* __restrict__ b2,
                                                      float* __restrict__ out, int n) {
    int gw = (int)((blockIdx.x * 256u + threadIdx.x) >> 6);
    if (gw >= n) return;
    const int lane = threadIdx.x & 63;
    int g = lane / 10;                 // 0..6 (g=6: lanes 60-63, harmless)
    int q = lane - g * 10;             // 0..9 (g=6: 0..3, in-bounds)
    int rs = rowoff[gw], re = rowoff[gw + 1];

    float a0 = 0.f, a1 = 0.f, a2 = 0.f, a3 = 0.f;
    if (g == 0) {
        uint2 v = xw[(size_t)gw * 10 + q];
        a0 = bflo(v.x); a1 = bfhi(v.x); a2 = bflo(v.y); a3 = bfhi(v.y);
    }

    for (int base = rs; base < re; base += 60) {
        int avail = re - base;
        int cnt = (avail < 60) ? avail : 60;
        int px = (lane < cnt) ? epay[base + lane] : n;  // OOB -> zero row
        for (int j = 0; j < cnt; j += 12) {
            int sA = __shfl(px, j + g, 64);        // active g<=5: slot <= 53
            int sB = __shfl(px, j + 6 + g, 64);    // active g<=5: slot <= 59
            uint2 vA = xw[(size_t)sA * 10 + q];
            uint2 vB = xw[(size_t)sB * 10 + q];
            a0 += bflo(vA.x); a1 += bfhi(vA.x); a2 += bflo(vA.y); a3 += bfhi(vA.y);
            a0 += bflo(vB.x); a1 += bfhi(vB.x); a2 += bflo(vB.y); a3 += bfhi(vB.y);
        }
    }
    // tree reduce of 6 groups into lanes 0..9: +30, then +10 and +20
    a0 += __shfl(a0, (lane + 30) & 63, 64);
    a1 += __shfl(a1, (lane + 30) & 63, 64);
    a2 += __shfl(a2, (lane + 30) & 63, 64);
    a3 += __shfl(a3, (lane + 30) & 63, 64);
    {
        float t0 = __shfl(a0, (lane + 10) & 63, 64), u0 = __shfl(a0, (lane + 20) & 63, 64);
        float t1 = __shfl(a1, (lane + 10) & 63, 64), u1 = __shfl(a1, (lane + 20) & 63, 64);
        float t2 = __shfl(a2, (lane + 10) & 63, 64), u2 = __shfl(a2, (lane + 20) & 63, 64);
        float t3 = __shfl(a3, (lane + 10) & 63, 64), u3 = __shfl(a3, (lane + 20) & 63, 64);
        a0 += t0 + u0; a1 += t1 + u1; a2 += t2 + u2; a3 += t3 + u3;
    }
    bool fin = lane < 10;
    float v0 = -INFINITY, v1 = -INFINITY, v2 = -INFINITY, v3 = -INFINITY;
    if (fin) {
        float di = dinv[gw];
        float4 bb = *(const float4*)&b2[q * 4];
        v0 = fmaf(a0, di, bb.x);
        v1 = fmaf(a1, di, bb.y);
        v2 = fmaf(a2, di, bb.z);
        v3 = fmaf(a3, di, bb.w);
    }
    float m = fmaxf(fmaxf(v0, v1), fmaxf(v2, v3));
#pragma unroll
    for (int off = 8; off >= 1; off >>= 1) m = fmaxf(m, __shfl_xor(m, off, 64));
    float es = fin ? (expf(v0 - m) + expf(v1 - m) + expf(v2 - m) + expf(v3 - m)) : 0.f;
#pragma unroll
    for (int off = 8; off >= 1; off >>= 1) es += __shfl_xor(es, off, 64);
    if (fin) {
        float ls = m + logf(es);
        *(float4*)&out[(size_t)gw * NCLS + q * 4] =
            make_float4(v0 - ls, v1 - ls, v2 - ls, v3 - ls);
    }
}

extern "C" void kernel_launch(void* const* d_in, const int* in_sizes, int n_in,
                              void* d_out, int out_size, void* d_ws, size_t ws_size,
                              hipStream_t stream) {
    const float* x  = (const float*)d_in[0];
    const void*  ei = d_in[1];
    const float* W1 = (const float*)d_in[2];
    const float* b1 = (const float*)d_in[3];
    const float* W2 = (const float*)d_in[4];
    const float* b2 = (const float*)d_in[5];
    float* out = (float*)d_out;

    const int n = in_sizes[0] / FIN;  // 100000
    const int E = in_sizes[1] / 2;    // 640000
    const int nbk = (n + 255) >> 8;   // 391 coarse buckets (<=512)

    char* ws = (char*)d_ws;
    size_t off = 0;
    auto alloc = [&](size_t bytes) {
        size_t p = off;
        off += (bytes + 255) & ~(size_t)255;
        return p;
    };
    int*   flag    = (int*)(ws + alloc(256));
    float* dinv    = (float*)(ws + alloc((size_t)n * 4));
    int*   rowoff  = (int*)(ws + alloc((size_t)(n + 1) * 4));
    int*   blkhist = (int*)(ws + alloc((size_t)256 * 512 * 4));
    int*   blkbase = (int*)(ws + alloc((size_t)512 * 256 * 4));
    int*   btotal  = (int*)(ws + alloc(512 * 4));
    int*   bbase   = (int*)(ws + alloc(520 * 4));
    unsigned short* wt1 = (unsigned short*)(ws + alloc(128 * 128 * 2));
    unsigned short* wt2 = (unsigned short*)(ws + alloc(48 * 128 * 2));
    unsigned int* pairs = (unsigned int*)(ws + alloc((size_t)E * 4));
    int*   epay    = (int*)(ws + alloc((size_t)E * 4));
    unsigned short* xw1  = (unsigned short*)(ws + alloc((size_t)(n + 1) * HID * 2));
    unsigned short* out1 = (unsigned short*)(ws + alloc((size_t)n * HID * 2));
    unsigned short* xw2  = (unsigned short*)(ws + alloc((size_t)(n + 1) * NCLS * 2));

    const int npairs = (E < 2048) ? E : 2048;

    prep_kernel<<<90, 256, 0, stream>>>(
        (const unsigned int*)ei, npairs, flag, W1, wt1, W2, wt2,
        (unsigned int*)(xw1 + (size_t)n * HID), (unsigned int*)(xw2 + (size_t)n * NCLS));
    hist_kernel<<<256, 256, 0, stream>>>(ei, E, flag, blkhist, nbk);
    bscan_kernel<<<nbk, 256, 0, stream>>>(blkhist, blkbase, btotal, nbk);
    base_kernel<<<1, 512, 0, stream>>>(btotal, bbase, nbk);
    scatter_kernel<<<256, 256, 0, stream>>>(ei, E, flag, blkbase, bbase, pairs, nbk);
    fin_kernel<<<nbk, 256, 0, stream>>>(pairs, bbase, dinv, rowoff, epay, n);

    gemm1_kernel<<<(n + 63) / 64, 256, 0, stream>>>(x, wt1, dinv, xw1, n);
    gather1_kernel<<<(int)(((size_t)n * 64 + 255) / 256), 256, 0, stream>>>(
        (const uint4*)xw1, dinv, rowoff, epay, b1, (uint4*)out1, n);

    gemm2_kernel<<<(n + 63) / 64, 256, 0, stream>>>(out1, wt2, dinv, xw2, n);
    gather2_kernel<<<(int)(((size_t)n * 64 + 255) / 256), 256, 0, stream>>>(
        (const uint2*)xw2, dinv, rowoff, epay, b2, out, n);
}

// Round 8
// 222.374 us; speedup vs baseline: 4.0422x; 1.0197x over previous
//
#include <hip/hip_runtime.h>
#include <hip/hip_bf16.h>
#include <math.h>

#define FIN 128
#define HID 128
#define NCLS 40

typedef _Float16 h2 __attribute__((ext_vector_type(2)));
typedef _Float16 h8 __attribute__((ext_vector_type(8)));
typedef __attribute__((ext_vector_type(4))) float f32x4;

__device__ __forceinline__ unsigned short f2h(float f) {
    union { _Float16 h; unsigned short u; } c;
    c.h = (_Float16)f;
    return c.u;
}
__device__ __forceinline__ h2 u2h2(unsigned int u) {
    union { unsigned int u; h2 h; } c;
    c.u = u;
    return c.h;
}
__device__ __forceinline__ unsigned int h22u(h2 h) {
    union { unsigned int u; h2 h; } c;
    c.h = h;
    return c.u;
}

__device__ __forceinline__ void load_edge(const void* ei, int E, int e, int is32,
                                          int& src, int& dst) {
    if (is32) {
        const int* p = (const int*)ei;
        src = p[e];
        dst = p[E + e];
    } else {
        const long long* p = (const long long*)ei;
        src = (int)p[e];
        dst = (int)p[E + e];
    }
}

// ---------------------------------------------------------------------------
// prep: block 0 = edge-dtype detect; blocks 1..88 = weight transpose + f16
// cast; block 89 = zero rows xw1[n], xw2[n]
// ---------------------------------------------------------------------------
__global__ __launch_bounds__(256) void prep_kernel(const unsigned int* __restrict__ ei32,
                                                   int npairs, int* __restrict__ flag,
                                                   const float* __restrict__ W1,
                                                   unsigned short* __restrict__ Wt1,
                                                   const float* __restrict__ W2,
                                                   unsigned short* __restrict__ Wt2,
                                                   unsigned int* __restrict__ z1,
                                                   unsigned int* __restrict__ z2) {
    const int b = blockIdx.x, t = threadIdx.x;
    if (b == 0) {
        unsigned int any = 0;
        for (int k = t; k < npairs; k += 256) any |= ei32[2 * k + 1];
        __shared__ int sf[4];
        unsigned long long ball = __ballot(any != 0);
        if ((t & 63) == 0) sf[t >> 6] = (ball != 0ull) ? 1 : 0;
        __syncthreads();
        if (t == 0) flag[0] = sf[0] | sf[1] | sf[2] | sf[3];
    } else if (b <= 88) {
        int i = (b - 1) * 256 + t;
        if (i < 128 * 128) {
            int nidx = i >> 7, k = i & 127;
            Wt1[i] = f2h(W1[k * HID + nidx]);
        } else if (i < 128 * 128 + 48 * 128) {
            int j = i - 128 * 128;
            int nidx = j >> 7, k = j & 127;
            Wt2[j] = (nidx < NCLS) ? f2h(W2[k * NCLS + nidx]) : 0;
        }
    } else {
        if (t < 64) z1[t] = 0;            // xw1 zero row (64 dwords)
        else if (t < 84) z2[t - 64] = 0;  // xw2 zero row (20 dwords)
    }
}

// --------------------------- radix CSR build -------------------------------
__global__ __launch_bounds__(256) void hist_kernel(const void* __restrict__ ei, int E,
                                                   const int* __restrict__ flag,
                                                   int* __restrict__ blkhist, int nbk) {
    __shared__ int lh[512];
    const int t = threadIdx.x, blk = blockIdx.x;
    for (int i = t; i < nbk; i += 256) lh[i] = 0;
    __syncthreads();
    const int is32 = *flag;
    for (int e = blk * 256 + t; e < E; e += 256 * 256) {
        int dst;
        if (is32) dst = ((const int*)ei)[E + e];
        else      dst = (int)((const long long*)ei)[E + e];
        atomicAdd(&lh[dst >> 8], 1);
    }
    __syncthreads();
    for (int i = t; i < nbk; i += 256) blkhist[blk * nbk + i] = lh[i];
}

__global__ __launch_bounds__(256) void bscan_kernel(const int* __restrict__ blkhist,
                                                    int* __restrict__ blkbase,
                                                    int* __restrict__ btotal, int nbk) {
    __shared__ int s[256];
    const int t = threadIdx.x, b = blockIdx.x;
    int v = blkhist[t * nbk + b];
    s[t] = v;
    __syncthreads();
#pragma unroll
    for (int off = 1; off < 256; off <<= 1) {
        int u = (t >= off) ? s[t - off] : 0;
        __syncthreads();
        s[t] += u;
        __syncthreads();
    }
    blkbase[b * 256 + t] = s[t] - v;  // exclusive
    if (t == 255) btotal[b] = s[255];
}

__global__ __launch_bounds__(512) void base_kernel(const int* __restrict__ btotal,
                                                   int* __restrict__ bbase, int nbk) {
    __shared__ int s[512];
    const int t = threadIdx.x;
    int v = (t < nbk) ? btotal[t] : 0;
    s[t] = v;
    __syncthreads();
#pragma unroll
    for (int off = 1; off < 512; off <<= 1) {
        int u = (t >= off) ? s[t - off] : 0;
        __syncthreads();
        s[t] += u;
        __syncthreads();
    }
    if (t < nbk) bbase[t] = s[t] - v;
    if (t == nbk - 1) bbase[nbk] = s[t];
}

__global__ __launch_bounds__(256) void scatter_kernel(const void* __restrict__ ei, int E,
                                                      const int* __restrict__ flag,
                                                      const int* __restrict__ blkbase,
                                                      const int* __restrict__ bbase,
                                                      unsigned int* __restrict__ pairs,
                                                      int nbk) {
    __shared__ int lcur[512];
    const int t = threadIdx.x, blk = blockIdx.x;
    for (int i = t; i < nbk; i += 256) lcur[i] = bbase[i] + blkbase[i * 256 + blk];
    __syncthreads();
    const int is32 = *flag;
    for (int e = blk * 256 + t; e < E; e += 256 * 256) {
        int src, dst;
        load_edge(ei, E, e, is32, src, dst);
        int pos = atomicAdd(&lcur[dst >> 8], 1);
        pairs[pos] = (unsigned int)src | ((unsigned int)(dst & 255) << 17);
    }
}

__global__ __launch_bounds__(256) void fin_kernel(const unsigned int* __restrict__ pairs,
                                                  const int* __restrict__ bbase,
                                                  float* __restrict__ dinv,
                                                  int* __restrict__ rowoff,
                                                  int* __restrict__ epay, int n) {
    __shared__ int deg[256];
    __shared__ int s[256];
    __shared__ int cur[256];
    const int t = threadIdx.x, b = blockIdx.x;
    deg[t] = 0;
    __syncthreads();
    const int start = bbase[b], end = bbase[b + 1];
    for (int k = start + t; k < end; k += 256) atomicAdd(&deg[pairs[k] >> 17], 1);
    __syncthreads();
    int d = deg[t];
    s[t] = d;
    __syncthreads();
#pragma unroll
    for (int off = 1; off < 256; off <<= 1) {
        int u = (t >= off) ? s[t - off] : 0;
        __syncthreads();
        s[t] += u;
        __syncthreads();
    }
    int gi = b * 256 + t;
    if (gi < n) {
        dinv[gi] = rsqrtf((float)d + 1.0f);  // +1 self loop
        rowoff[gi + 1] = start + s[t];
    }
    if (gi == 0) rowoff[0] = 0;
    cur[t] = s[t] - d;
    __syncthreads();
    for (int k = start + t; k < end; k += 256) {
        unsigned int p = pairs[k];
        int dl = p >> 17;
        int pos = start + atomicAdd(&cur[dl], 1);
        epay[pos] = (int)(p & 0x1FFFFu);
    }
}

// ---------------------------------------------------------------------------
// MFMA GEMM1: xw1'[n x 128] (fp16) = dinv[row] * (f16(X) @ f16(W1))
// ---------------------------------------------------------------------------
__global__ __launch_bounds__(256) void gemm1_kernel(const float* __restrict__ X,
                                                    const unsigned short* __restrict__ Wt,
                                                    const float* __restrict__ dinv,
                                                    unsigned short* __restrict__ Y, int n) {
    __shared__ unsigned short Bs[128][136];
    const int t = threadIdx.x;
    for (int i = t; i < 128 * 16; i += 256) {
        int c = i >> 4, kc = (i & 15) << 3;
        *(int4*)&Bs[c][kc] = ((const int4*)Wt)[i];
    }
    __syncthreads();

    const int wv = t >> 6, lane = t & 63;
    const int lr = lane & 15, kg = lane >> 4;
    const int row0 = blockIdx.x * 64 + wv * 16;
    int arow = row0 + lr;
    if (arow >= n) arow = n - 1;
    const float* aptr = X + (size_t)arow * FIN + kg * 8;

    f32x4 acc[8];
#pragma unroll
    for (int nf = 0; nf < 8; ++nf) acc[nf] = (f32x4){0.f, 0.f, 0.f, 0.f};

#pragma unroll
    for (int kt = 0; kt < 4; ++kt) {
        float4 a0 = *(const float4*)(aptr + kt * 32);
        float4 a1 = *(const float4*)(aptr + kt * 32 + 4);
        h8 af;
        af[0] = (_Float16)a0.x; af[1] = (_Float16)a0.y;
        af[2] = (_Float16)a0.z; af[3] = (_Float16)a0.w;
        af[4] = (_Float16)a1.x; af[5] = (_Float16)a1.y;
        af[6] = (_Float16)a1.z; af[7] = (_Float16)a1.w;
#pragma unroll
        for (int nf = 0; nf < 8; ++nf) {
            h8 bf_ = *(const h8*)&Bs[nf * 16 + lr][kt * 32 + kg * 8];
            acc[nf] = __builtin_amdgcn_mfma_f32_16x16x32_f16(af, bf_, acc[nf], 0, 0, 0);
        }
    }
    float4 d4 = *(const float4*)&dinv[row0 + kg * 4];
    float dv[4] = {d4.x, d4.y, d4.z, d4.w};
#pragma unroll
    for (int nf = 0; nf < 8; ++nf) {
        int col = nf * 16 + lr;
#pragma unroll
        for (int r = 0; r < 4; ++r) {
            int row = row0 + kg * 4 + r;
            if (row < n) Y[(size_t)row * HID + col] = f2h(acc[nf][r] * dv[r]);
        }
    }
}

// ---------------------------------------------------------------------------
// MFMA GEMM2: xw2'[n x 40] (fp16, stride 40) = dinv[row]*(out1 @ f16(W2))
// out1 is ready fp16 A-operand (relu+bias fused in gather1)
// ---------------------------------------------------------------------------
__global__ __launch_bounds__(256) void gemm2_kernel(const unsigned short* __restrict__ Xin,
                                                    const unsigned short* __restrict__ Wt,
                                                    const float* __restrict__ dinv,
                                                    unsigned short* __restrict__ Y, int n) {
    __shared__ unsigned short Bs[48][136];
    const int t = threadIdx.x;
    for (int i = t; i < 48 * 16; i += 256) {
        int c = i >> 4, kc = (i & 15) << 3;
        *(int4*)&Bs[c][kc] = ((const int4*)Wt)[i];
    }
    __syncthreads();

    const int wv = t >> 6, lane = t & 63;
    const int lr = lane & 15, kg = lane >> 4;
    const int row0 = blockIdx.x * 64 + wv * 16;
    int arow = row0 + lr;
    if (arow >= n) arow = n - 1;
    const unsigned short* aptr = Xin + (size_t)arow * HID + kg * 8;

    f32x4 acc[3];
#pragma unroll
    for (int nf = 0; nf < 3; ++nf) acc[nf] = (f32x4){0.f, 0.f, 0.f, 0.f};

#pragma unroll
    for (int kt = 0; kt < 4; ++kt) {
        h8 af = *(const h8*)(aptr + kt * 32);
#pragma unroll
        for (int nf = 0; nf < 3; ++nf) {
            h8 bf_ = *(const h8*)&Bs[nf * 16 + lr][kt * 32 + kg * 8];
            acc[nf] = __builtin_amdgcn_mfma_f32_16x16x32_f16(af, bf_, acc[nf], 0, 0, 0);
        }
    }
    float4 d4 = *(const float4*)&dinv[row0 + kg * 4];
    float dv[4] = {d4.x, d4.y, d4.z, d4.w};
#pragma unroll
    for (int nf = 0; nf < 3; ++nf) {
        int col = nf * 16 + lr;
        if (col < NCLS) {
#pragma unroll
            for (int r = 0; r < 4; ++r) {
                int row = row0 + kg * 4 + r;
                if (row < n) Y[(size_t)row * NCLS + col] = f2h(acc[nf][r] * dv[r]);
            }
        }
    }
}

// ---------------------------------------------------------------------------
// gather1: 4 groups x 16 lanes, uint4 = 8 fp16/lane, packed v_pk_add_f16.
// out1 = f16(relu(dinv_i*(self + sum_src) + b1))
// ---------------------------------------------------------------------------
__global__ __launch_bounds__(256) void gather1_kernel(const uint4* __restrict__ xw,
                                                      const float* __restrict__ dinv,
                                                      const int* __restrict__ rowoff,
                                                      const int* __restrict__ epay,
                                                      const float* __restrict__ b1,
                                                      uint4* __restrict__ out, int n) {
    int gw = (int)((blockIdx.x * 256u + threadIdx.x) >> 6);
    if (gw >= n) return;
    const int lane = threadIdx.x & 63;
    const int g = lane >> 4;
    const int q = lane & 15;
    int rs = rowoff[gw], re = rowoff[gw + 1];

    h2 c0 = (h2){0, 0}, c1 = (h2){0, 0}, c2 = (h2){0, 0}, c3 = (h2){0, 0};
    if (g == 0) {
        uint4 v = xw[(size_t)gw * 16 + q];
        c0 = u2h2(v.x); c1 = u2h2(v.y); c2 = u2h2(v.z); c3 = u2h2(v.w);
    }

    for (int base = rs; base < re; base += 64) {
        int avail = re - base;
        int cnt = (avail < 64) ? avail : 64;
        int px = (lane < cnt) ? epay[base + lane] : n;  // OOB -> zero row
        for (int j = 0; j < cnt; j += 8) {
            int sA = __shfl(px, j + g, 64);
            int sB = __shfl(px, j + 4 + g, 64);
            uint4 vA = xw[(size_t)sA * 16 + q];
            uint4 vB = xw[(size_t)sB * 16 + q];
            c0 += u2h2(vA.x); c1 += u2h2(vA.y); c2 += u2h2(vA.z); c3 += u2h2(vA.w);
            c0 += u2h2(vB.x); c1 += u2h2(vB.y); c2 += u2h2(vB.z); c3 += u2h2(vB.w);
        }
    }
    c0 += u2h2(__shfl_xor(h22u(c0), 16, 64));
    c1 += u2h2(__shfl_xor(h22u(c1), 16, 64));
    c2 += u2h2(__shfl_xor(h22u(c2), 16, 64));
    c3 += u2h2(__shfl_xor(h22u(c3), 16, 64));
    c0 += u2h2(__shfl_xor(h22u(c0), 32, 64));
    c1 += u2h2(__shfl_xor(h22u(c1), 32, 64));
    c2 += u2h2(__shfl_xor(h22u(c2), 32, 64));
    c3 += u2h2(__shfl_xor(h22u(c3), 32, 64));
    if (g == 0) {
        float di = dinv[gw];
        float4 ba = *(const float4*)&b1[q * 8];
        float4 bb = *(const float4*)&b1[q * 8 + 4];
        float r0 = fmaxf(fmaf((float)c0[0], di, ba.x), 0.f);
        float r1 = fmaxf(fmaf((float)c0[1], di, ba.y), 0.f);
        float r2 = fmaxf(fmaf((float)c1[0], di, ba.z), 0.f);
        float r3 = fmaxf(fmaf((float)c1[1], di, ba.w), 0.f);
        float r4 = fmaxf(fmaf((float)c2[0], di, bb.x), 0.f);
        float r5 = fmaxf(fmaf((float)c2[1], di, bb.y), 0.f);
        float r6 = fmaxf(fmaf((float)c3[0], di, bb.z), 0.f);
        float r7 = fmaxf(fmaf((float)c3[1], di, bb.w), 0.f);
        uint4 o;
        o.x = (unsigned)f2h(r0) | ((unsigned)f2h(r1) << 16);
        o.y = (unsigned)f2h(r2) | ((unsigned)f2h(r3) << 16);
        o.z = (unsigned)f2h(r4) | ((unsigned)f2h(r5) << 16);
        o.w = (unsigned)f2h(r6) | ((unsigned)f2h(r7) << 16);
        out[(size_t)gw * 16 + q] = o;
    }
}

// ---------------------------------------------------------------------------
// gather2: 6 groups x 10 lanes, uint2 = 4 fp16 classes/lane, packed adds.
// logits = dinv_i*(self + sum) + b2; fused log_softmax; float4 store.
// ---------------------------------------------------------------------------
__global__ __launch_bounds__(256) void gather2_kernel(const uint2* __restrict__ xw,
                                                      const float* __restrict__ dinv,
                                                      const int* __restrict__ rowoff,
                                                      const int* __restrict__ epay,
                                                      const float* __restrict__ b2,
                                                      float* __restrict__ out, int n) {
    int gw = (int)((blockIdx.x * 256u + threadIdx.x) >> 6);
    if (gw >= n) return;
    const int lane = threadIdx.x & 63;
    int g = lane / 10;                 // 0..6 (g=6: lanes 60-63, harmless)
    int q = lane - g * 10;             // 0..9 (g=6: 0..3, in-bounds)
    int rs = rowoff[gw], re = rowoff[gw + 1];

    h2 cA = (h2){0, 0}, cB = (h2){0, 0};
    if (g == 0) {
        uint2 v = xw[(size_t)gw * 10 + q];
        cA = u2h2(v.x); cB = u2h2(v.y);
    }

    for (int base = rs; base < re; base += 60) {
        int avail = re - base;
        int cnt = (avail < 60) ? avail : 60;
        int px = (lane < cnt) ? epay[base + lane] : n;  // OOB -> zero row
        for (int j = 0; j < cnt; j += 12) {
            int sA = __shfl(px, j + g, 64);
            int sB = __shfl(px, j + 6 + g, 64);
            uint2 vA = xw[(size_t)sA * 10 + q];
            uint2 vB = xw[(size_t)sB * 10 + q];
            cA += u2h2(vA.x); cB += u2h2(vA.y);
            cA += u2h2(vB.x); cB += u2h2(vB.y);
        }
    }
    // tree reduce 6 groups into lanes 0..9: +30, then +10 and +20
    cA += u2h2(__shfl(h22u(cA), (lane + 30) & 63, 64));
    cB += u2h2(__shfl(h22u(cB), (lane + 30) & 63, 64));
    {
        unsigned tA = __shfl(h22u(cA), (lane + 10) & 63, 64);
        unsigned uA = __shfl(h22u(cA), (lane + 20) & 63, 64);
        unsigned tB = __shfl(h22u(cB), (lane + 10) & 63, 64);
        unsigned uB = __shfl(h22u(cB), (lane + 20) & 63, 64);
        cA += u2h2(tA); cA += u2h2(uA);
        cB += u2h2(tB); cB += u2h2(uB);
    }
    bool fin = lane < 10;
    float v0 = -INFINITY, v1 = -INFINITY, v2 = -INFINITY, v3 = -INFINITY;
    if (fin) {
        float di = dinv[gw];
        float4 bb = *(const float4*)&b2[q * 4];
        v0 = fmaf((float)cA[0], di, bb.x);
        v1 = fmaf((float)cA[1], di, bb.y);
        v2 = fmaf((float)cB[0], di, bb.z);
        v3 = fmaf((float)cB[1], di, bb.w);
    }
    float m = fmaxf(fmaxf(v0, v1), fmaxf(v2, v3));
#pragma unroll
    for (int off = 8; off >= 1; off >>= 1) m = fmaxf(m, __shfl_xor(m, off, 64));
    float es = fin ? (expf(v0 - m) + expf(v1 - m) + expf(v2 - m) + expf(v3 - m)) : 0.f;
#pragma unroll
    for (int off = 8; off >= 1; off >>= 1) es += __shfl_xor(es, off, 64);
    if (fin) {
        float ls = m + logf(es);
        *(float4*)&out[(size_t)gw * NCLS + q * 4] =
            make_float4(v0 - ls, v1 - ls, v2 - ls, v3 - ls);
    }
}

extern "C" void kernel_launch(void* const* d_in, const int* in_sizes, int n_in,
                              void* d_out, int out_size, void* d_ws, size_t ws_size,
                              hipStream_t stream) {
    const float* x  = (const float*)d_in[0];
    const void*  ei = d_in[1];
    const float* W1 = (const float*)d_in[2];
    const float* b1 = (const float*)d_in[3];
    const float* W2 = (const float*)d_in[4];
    const float* b2 = (const float*)d_in[5];
    float* out = (float*)d_out;

    const int n = in_sizes[0] / FIN;  // 100000
    const int E = in_sizes[1] / 2;    // 640000
    const int nbk = (n + 255) >> 8;   // 391 coarse buckets (<=512)

    char* ws = (char*)d_ws;
    size_t off = 0;
    auto alloc = [&](size_t bytes) {
        size_t p = off;
        off += (bytes + 255) & ~(size_t)255;
        return p;
    };
    int*   flag    = (int*)(ws + alloc(256));
    float* dinv    = (float*)(ws + alloc((size_t)n * 4));
    int*   rowoff  = (int*)(ws + alloc((size_t)(n + 1) * 4));
    int*   blkhist = (int*)(ws + alloc((size_t)256 * 512 * 4));
    int*   blkbase = (int*)(ws + alloc((size_t)512 * 256 * 4));
    int*   btotal  = (int*)(ws + alloc(512 * 4));
    int*   bbase   = (int*)(ws + alloc(520 * 4));
    unsigned short* wt1 = (unsigned short*)(ws + alloc(128 * 128 * 2));
    unsigned short* wt2 = (unsigned short*)(ws + alloc(48 * 128 * 2));
    unsigned int* pairs = (unsigned int*)(ws + alloc((size_t)E * 4));
    int*   epay    = (int*)(ws + alloc((size_t)E * 4));
    unsigned short* xw1  = (unsigned short*)(ws + alloc((size_t)(n + 1) * HID * 2));
    unsigned short* out1 = (unsigned short*)(ws + alloc((size_t)n * HID * 2));
    unsigned short* xw2  = (unsigned short*)(ws + alloc((size_t)(n + 1) * NCLS * 2));

    const int npairs = (E < 2048) ? E : 2048;

    prep_kernel<<<90, 256, 0, stream>>>(
        (const unsigned int*)ei, npairs, flag, W1, wt1, W2, wt2,
        (unsigned int*)(xw1 + (size_t)n * HID), (unsigned int*)(xw2 + (size_t)n * NCLS));
    hist_kernel<<<256, 256, 0, stream>>>(ei, E, flag, blkhist, nbk);
    bscan_kernel<<<nbk, 256, 0, stream>>>(blkhist, blkbase, btotal, nbk);
    base_kernel<<<1, 512, 0, stream>>>(btotal, bbase, nbk);
    scatter_kernel<<<256, 256, 0, stream>>>(ei, E, flag, blkbase, bbase, pairs, nbk);
    fin_kernel<<<nbk, 256, 0, stream>>>(pairs, bbase, dinv, rowoff, epay, n);

    gemm1_kernel<<<(n + 63) / 64, 256, 0, stream>>>(x, wt1, dinv, xw1, n);
    gather1_kernel<<<(int)(((size_t)n * 64 + 255) / 256), 256, 0, stream>>>(
        (const uint4*)xw1, dinv, rowoff, epay, b1, (uint4*)out1, n);

    gemm2_kernel<<<(n + 63) / 64, 256, 0, stream>>>(out1, wt2, dinv, xw2, n);
    gather2_kernel<<<(int)(((size_t)n * 64 + 255) / 256), 256, 0, stream>>>(
        (const uint2*)xw2, dinv, rowoff, epay, b2, out, n);
}

// Round 9
// 203.553 us; speedup vs baseline: 4.4160x; 1.0925x over previous
//
#include <hip/hip_runtime.h>
#include <hip/hip_bf16.h>
#include <math.h>

#define FIN 128
#define HID 128
#define NCLS 40

typedef _Float16 h2 __attribute__((ext_vector_type(2)));
typedef _Float16 h8 __attribute__((ext_vector_type(8)));
typedef __attribute__((ext_vector_type(4))) float f32x4;

__device__ __forceinline__ unsigned short f2h(float f) {
    union { _Float16 h; unsigned short u; } c;
    c.h = (_Float16)f;
    return c.u;
}
__device__ __forceinline__ h2 u2h2(unsigned int u) {
    union { unsigned int u; h2 h; } c;
    c.u = u;
    return c.h;
}
__device__ __forceinline__ unsigned int h22u(h2 h) {
    union { unsigned int u; h2 h; } c;
    c.h = h;
    return c.u;
}

__device__ __forceinline__ void load_edge(const void* ei, int E, int e, int is32,
                                          int& src, int& dst) {
    if (is32) {
        const int* p = (const int*)ei;
        src = p[e];
        dst = p[E + e];
    } else {
        const long long* p = (const long long*)ei;
        src = (int)p[e];
        dst = (int)p[E + e];
    }
}

// ---------------------------------------------------------------------------
// prep: block 0 = edge-dtype detect; blocks 1..88 = weight transpose + f16
// cast; block 89 = zero rows xw1[n], xw2[n]
// ---------------------------------------------------------------------------
__global__ __launch_bounds__(256) void prep_kernel(const unsigned int* __restrict__ ei32,
                                                   int npairs, int* __restrict__ flag,
                                                   const float* __restrict__ W1,
                                                   unsigned short* __restrict__ Wt1,
                                                   const float* __restrict__ W2,
                                                   unsigned short* __restrict__ Wt2,
                                                   unsigned int* __restrict__ z1,
                                                   unsigned int* __restrict__ z2) {
    const int b = blockIdx.x, t = threadIdx.x;
    if (b == 0) {
        unsigned int any = 0;
        for (int k = t; k < npairs; k += 256) any |= ei32[2 * k + 1];
        __shared__ int sf[4];
        unsigned long long ball = __ballot(any != 0);
        if ((t & 63) == 0) sf[t >> 6] = (ball != 0ull) ? 1 : 0;
        __syncthreads();
        if (t == 0) flag[0] = sf[0] | sf[1] | sf[2] | sf[3];
    } else if (b <= 88) {
        int i = (b - 1) * 256 + t;
        if (i < 128 * 128) {
            int nidx = i >> 7, k = i & 127;
            Wt1[i] = f2h(W1[k * HID + nidx]);
        } else if (i < 128 * 128 + 48 * 128) {
            int j = i - 128 * 128;
            int nidx = j >> 7, k = j & 127;
            Wt2[j] = (nidx < NCLS) ? f2h(W2[k * NCLS + nidx]) : 0;
        }
    } else {
        if (t < 64) z1[t] = 0;            // xw1 zero row (64 dwords)
        else if (t < 84) z2[t - 64] = 0;  // xw2 zero row (20 dwords)
    }
}

// --------------------------- radix CSR build -------------------------------
__global__ __launch_bounds__(256) void hist_kernel(const void* __restrict__ ei, int E,
                                                   const int* __restrict__ flag,
                                                   int* __restrict__ blkhist, int nbk) {
    __shared__ int lh[512];
    const int t = threadIdx.x, blk = blockIdx.x;
    for (int i = t; i < nbk; i += 256) lh[i] = 0;
    __syncthreads();
    const int is32 = *flag;
    for (int e = blk * 256 + t; e < E; e += 256 * 256) {
        int dst;
        if (is32) dst = ((const int*)ei)[E + e];
        else      dst = (int)((const long long*)ei)[E + e];
        atomicAdd(&lh[dst >> 8], 1);
    }
    __syncthreads();
    for (int i = t; i < nbk; i += 256) blkhist[blk * nbk + i] = lh[i];
}

__global__ __launch_bounds__(256) void bscan_kernel(const int* __restrict__ blkhist,
                                                    int* __restrict__ blkbase,
                                                    int* __restrict__ btotal, int nbk) {
    __shared__ int s[256];
    const int t = threadIdx.x, b = blockIdx.x;
    int v = blkhist[t * nbk + b];
    s[t] = v;
    __syncthreads();
#pragma unroll
    for (int off = 1; off < 256; off <<= 1) {
        int u = (t >= off) ? s[t - off] : 0;
        __syncthreads();
        s[t] += u;
        __syncthreads();
    }
    blkbase[b * 256 + t] = s[t] - v;  // exclusive
    if (t == 255) btotal[b] = s[255];
}

__global__ __launch_bounds__(512) void base_kernel(const int* __restrict__ btotal,
                                                   int* __restrict__ bbase, int nbk) {
    __shared__ int s[512];
    const int t = threadIdx.x;
    int v = (t < nbk) ? btotal[t] : 0;
    s[t] = v;
    __syncthreads();
#pragma unroll
    for (int off = 1; off < 512; off <<= 1) {
        int u = (t >= off) ? s[t - off] : 0;
        __syncthreads();
        s[t] += u;
        __syncthreads();
    }
    if (t < nbk) bbase[t] = s[t] - v;
    if (t == nbk - 1) bbase[nbk] = s[t];
}

__global__ __launch_bounds__(256) void scatter_kernel(const void* __restrict__ ei, int E,
                                                      const int* __restrict__ flag,
                                                      const int* __restrict__ blkbase,
                                                      const int* __restrict__ bbase,
                                                      unsigned int* __restrict__ pairs,
                                                      int nbk) {
    __shared__ int lcur[512];
    const int t = threadIdx.x, blk = blockIdx.x;
    for (int i = t; i < nbk; i += 256) lcur[i] = bbase[i] + blkbase[i * 256 + blk];
    __syncthreads();
    const int is32 = *flag;
    for (int e = blk * 256 + t; e < E; e += 256 * 256) {
        int src, dst;
        load_edge(ei, E, e, is32, src, dst);
        int pos = atomicAdd(&lcur[dst >> 8], 1);
        pairs[pos] = (unsigned int)src | ((unsigned int)(dst & 255) << 17);
    }
}

__global__ __launch_bounds__(256) void fin_kernel(const unsigned int* __restrict__ pairs,
                                                  const int* __restrict__ bbase,
                                                  float* __restrict__ dinv,
                                                  int* __restrict__ rowoff,
                                                  int* __restrict__ epay, int n) {
    __shared__ int deg[256];
    __shared__ int s[256];
    __shared__ int cur[256];
    const int t = threadIdx.x, b = blockIdx.x;
    deg[t] = 0;
    __syncthreads();
    const int start = bbase[b], end = bbase[b + 1];
    for (int k = start + t; k < end; k += 256) atomicAdd(&deg[pairs[k] >> 17], 1);
    __syncthreads();
    int d = deg[t];
    s[t] = d;
    __syncthreads();
#pragma unroll
    for (int off = 1; off < 256; off <<= 1) {
        int u = (t >= off) ? s[t - off] : 0;
        __syncthreads();
        s[t] += u;
        __syncthreads();
    }
    int gi = b * 256 + t;
    if (gi < n) {
        dinv[gi] = rsqrtf((float)d + 1.0f);  // +1 self loop
        rowoff[gi + 1] = start + s[t];
    }
    if (gi == 0) rowoff[0] = 0;
    cur[t] = s[t] - d;
    __syncthreads();
    for (int k = start + t; k < end; k += 256) {
        unsigned int p = pairs[k];
        int dl = p >> 17;
        int pos = start + atomicAdd(&cur[dl], 1);
        epay[pos] = (int)(p & 0x1FFFFu);
    }
}

// ---------------------------------------------------------------------------
// MFMA GEMM1: xw1'[n x 128] (fp16) = dinv[row] * (f16(X) @ f16(W1))
// ---------------------------------------------------------------------------
__global__ __launch_bounds__(256) void gemm1_kernel(const float* __restrict__ X,
                                                    const unsigned short* __restrict__ Wt,
                                                    const float* __restrict__ dinv,
                                                    unsigned short* __restrict__ Y, int n) {
    __shared__ unsigned short Bs[128][136];
    const int t = threadIdx.x;
    for (int i = t; i < 128 * 16; i += 256) {
        int c = i >> 4, kc = (i & 15) << 3;
        *(int4*)&Bs[c][kc] = ((const int4*)Wt)[i];
    }
    __syncthreads();

    const int wv = t >> 6, lane = t & 63;
    const int lr = lane & 15, kg = lane >> 4;
    const int row0 = blockIdx.x * 64 + wv * 16;
    int arow = row0 + lr;
    if (arow >= n) arow = n - 1;
    const float* aptr = X + (size_t)arow * FIN + kg * 8;

    f32x4 acc[8];
#pragma unroll
    for (int nf = 0; nf < 8; ++nf) acc[nf] = (f32x4){0.f, 0.f, 0.f, 0.f};

#pragma unroll
    for (int kt = 0; kt < 4; ++kt) {
        float4 a0 = *(const float4*)(aptr + kt * 32);
        float4 a1 = *(const float4*)(aptr + kt * 32 + 4);
        h8 af;
        af[0] = (_Float16)a0.x; af[1] = (_Float16)a0.y;
        af[2] = (_Float16)a0.z; af[3] = (_Float16)a0.w;
        af[4] = (_Float16)a1.x; af[5] = (_Float16)a1.y;
        af[6] = (_Float16)a1.z; af[7] = (_Float16)a1.w;
#pragma unroll
        for (int nf = 0; nf < 8; ++nf) {
            h8 bf_ = *(const h8*)&Bs[nf * 16 + lr][kt * 32 + kg * 8];
            acc[nf] = __builtin_amdgcn_mfma_f32_16x16x32_f16(af, bf_, acc[nf], 0, 0, 0);
        }
    }
    float4 d4 = *(const float4*)&dinv[row0 + kg * 4];
    float dv[4] = {d4.x, d4.y, d4.z, d4.w};
#pragma unroll
    for (int nf = 0; nf < 8; ++nf) {
        int col = nf * 16 + lr;
#pragma unroll
        for (int r = 0; r < 4; ++r) {
            int row = row0 + kg * 4 + r;
            if (row < n) Y[(size_t)row * HID + col] = f2h(acc[nf][r] * dv[r]);
        }
    }
}

// ---------------------------------------------------------------------------
// MFMA GEMM2: xw2'[n x 40] (fp16, stride 40) = dinv[row]*(out1 @ f16(W2))
// ---------------------------------------------------------------------------
__global__ __launch_bounds__(256) void gemm2_kernel(const unsigned short* __restrict__ Xin,
                                                    const unsigned short* __restrict__ Wt,
                                                    const float* __restrict__ dinv,
                                                    unsigned short* __restrict__ Y, int n) {
    __shared__ unsigned short Bs[48][136];
    const int t = threadIdx.x;
    for (int i = t; i < 48 * 16; i += 256) {
        int c = i >> 4, kc = (i & 15) << 3;
        *(int4*)&Bs[c][kc] = ((const int4*)Wt)[i];
    }
    __syncthreads();

    const int wv = t >> 6, lane = t & 63;
    const int lr = lane & 15, kg = lane >> 4;
    const int row0 = blockIdx.x * 64 + wv * 16;
    int arow = row0 + lr;
    if (arow >= n) arow = n - 1;
    const unsigned short* aptr = Xin + (size_t)arow * HID + kg * 8;

    f32x4 acc[3];
#pragma unroll
    for (int nf = 0; nf < 3; ++nf) acc[nf] = (f32x4){0.f, 0.f, 0.f, 0.f};

#pragma unroll
    for (int kt = 0; kt < 4; ++kt) {
        h8 af = *(const h8*)(aptr + kt * 32);
#pragma unroll
        for (int nf = 0; nf < 3; ++nf) {
            h8 bf_ = *(const h8*)&Bs[nf * 16 + lr][kt * 32 + kg * 8];
            acc[nf] = __builtin_amdgcn_mfma_f32_16x16x32_f16(af, bf_, acc[nf], 0, 0, 0);
        }
    }
    float4 d4 = *(const float4*)&dinv[row0 + kg * 4];
    float dv[4] = {d4.x, d4.y, d4.z, d4.w};
#pragma unroll
    for (int nf = 0; nf < 3; ++nf) {
        int col = nf * 16 + lr;
        if (col < NCLS) {
#pragma unroll
            for (int r = 0; r < 4; ++r) {
                int row = row0 + kg * 4 + r;
                if (row < n) Y[(size_t)row * NCLS + col] = f2h(acc[nf][r] * dv[r]);
            }
        }
    }
}

// ---------------------------------------------------------------------------
// gather1 v3: 2 nodes/wave (one per 32-lane half). Per half: 2 subs x 16
// lanes, uint4 = 8 fp16 feats/lane; 2 edges per iter via one bpermute.
// out1 = f16(relu(dinv_i*(self + sum_src) + b1))
// ---------------------------------------------------------------------------
__global__ __launch_bounds__(256) void gather1_kernel(const uint4* __restrict__ xw,
                                                      const float* __restrict__ dinv,
                                                      const int* __restrict__ rowoff,
                                                      const int* __restrict__ epay,
                                                      const float* __restrict__ b1,
                                                      uint4* __restrict__ out, int n) {
    int w = (int)((blockIdx.x * 256u + threadIdx.x) >> 6);
    const int n2 = (n + 1) >> 1;
    if (w >= n2) return;
    const int lane = threadIdx.x & 63;
    const int half = lane >> 5;
    const int hl = lane & 31;
    const int sub = hl >> 4;   // 0/1
    const int q = hl & 15;     // feats q*8..q*8+7
    const int node = 2 * w + half;
    const int nd = (node < n) ? node : (n - 1);
    const int rs = rowoff[nd], re = rowoff[nd + 1];
    const float di = dinv[nd];

    h2 c0 = (h2){0, 0}, c1 = (h2){0, 0}, c2 = (h2){0, 0}, c3 = (h2){0, 0};
    if (sub == 0) {  // self row
        uint4 v = xw[(size_t)nd * 16 + q];
        c0 = u2h2(v.x); c1 = u2h2(v.y); c2 = u2h2(v.z); c3 = u2h2(v.w);
    }

    for (int base = rs; base < re; base += 32) {
        int avail = re - base;
        int cnt = (avail < 32) ? avail : 32;
        int px = (hl < cnt) ? epay[base + hl] : n;  // OOB -> zero row
        for (int j = 0; j < cnt; j += 2) {
            // slots j (sub0) and j+1 (sub1); slot==cnt (odd cnt) lands on px=n
            int s = __shfl(px, (half << 5) + j + sub, 64);
            uint4 v = xw[(size_t)s * 16 + q];
            c0 += u2h2(v.x); c1 += u2h2(v.y); c2 += u2h2(v.z); c3 += u2h2(v.w);
        }
    }
    // merge the two subs (xor16 stays within the half)
    c0 += u2h2(__shfl_xor(h22u(c0), 16, 64));
    c1 += u2h2(__shfl_xor(h22u(c1), 16, 64));
    c2 += u2h2(__shfl_xor(h22u(c2), 16, 64));
    c3 += u2h2(__shfl_xor(h22u(c3), 16, 64));
    if (sub == 0 && node < n) {
        float4 ba = *(const float4*)&b1[q * 8];
        float4 bb = *(const float4*)&b1[q * 8 + 4];
        float r0 = fmaxf(fmaf((float)c0[0], di, ba.x), 0.f);
        float r1 = fmaxf(fmaf((float)c0[1], di, ba.y), 0.f);
        float r2 = fmaxf(fmaf((float)c1[0], di, ba.z), 0.f);
        float r3 = fmaxf(fmaf((float)c1[1], di, ba.w), 0.f);
        float r4 = fmaxf(fmaf((float)c2[0], di, bb.x), 0.f);
        float r5 = fmaxf(fmaf((float)c2[1], di, bb.y), 0.f);
        float r6 = fmaxf(fmaf((float)c3[0], di, bb.z), 0.f);
        float r7 = fmaxf(fmaf((float)c3[1], di, bb.w), 0.f);
        uint4 o;
        o.x = (unsigned)f2h(r0) | ((unsigned)f2h(r1) << 16);
        o.y = (unsigned)f2h(r2) | ((unsigned)f2h(r3) << 16);
        o.z = (unsigned)f2h(r4) | ((unsigned)f2h(r5) << 16);
        o.w = (unsigned)f2h(r6) | ((unsigned)f2h(r7) << 16);
        out[(size_t)nd * 16 + q] = o;
    }
}

// ---------------------------------------------------------------------------
// gather2 v3: 2 nodes/wave. Per half: 3 subs x 10 lanes (uint2 = 4 classes),
// 6 edges/iter, slots <= 29 (no clamps). Softmax: fixed-shift (no max pass).
// ---------------------------------------------------------------------------
__global__ __launch_bounds__(256) void gather2_kernel(const uint2* __restrict__ xw,
                                                      const float* __restrict__ dinv,
                                                      const int* __restrict__ rowoff,
                                                      const int* __restrict__ epay,
                                                      const float* __restrict__ b2,
                                                      float* __restrict__ out, int n) {
    int w = (int)((blockIdx.x * 256u + threadIdx.x) >> 6);
    const int n2 = (n + 1) >> 1;
    if (w >= n2) return;
    const int lane = threadIdx.x & 63;
    const int half = lane >> 5;
    const int hl = lane & 31;
    const int sub = hl / 10;       // 0..3 (3 = lanes 30,31, discarded)
    const int q = hl - sub * 10;   // 0..9
    const int node = 2 * w + half;
    const int nd = (node < n) ? node : (n - 1);
    const int rs = rowoff[nd], re = rowoff[nd + 1];
    const float di = dinv[nd];

    h2 cA = (h2){0, 0}, cB = (h2){0, 0};
    if (sub == 0) {  // self row
        uint2 v = xw[(size_t)nd * 10 + q];
        cA = u2h2(v.x); cB = u2h2(v.y);
    }

    for (int base = rs; base < re; base += 30) {
        int avail = re - base;
        int cnt = (avail < 30) ? avail : 30;
        int px = (hl < cnt) ? epay[base + hl] : n;  // OOB -> zero row
        for (int j = 0; j < cnt; j += 6) {
            // j <= 24 -> slots <= 29, always within the half's px lanes
            int sA = __shfl(px, (half << 5) + j + sub, 64);
            int sB = __shfl(px, (half << 5) + j + 3 + sub, 64);
            uint2 vA = xw[(size_t)sA * 10 + q];
            uint2 vB = xw[(size_t)sB * 10 + q];
            cA += u2h2(vA.x); cB += u2h2(vA.y);
            cA += u2h2(vB.x); cB += u2h2(vB.y);
        }
    }
    // reduce 3 subs into lanes hl<10 (read both sources before adding)
    {
        unsigned tA = __shfl(h22u(cA), (lane + 10) & 63, 64);
        unsigned uA = __shfl(h22u(cA), (lane + 20) & 63, 64);
        unsigned tB = __shfl(h22u(cB), (lane + 10) & 63, 64);
        unsigned uB = __shfl(h22u(cB), (lane + 20) & 63, 64);
        cA += u2h2(tA); cA += u2h2(uA);
        cB += u2h2(tB); cB += u2h2(uB);
    }
    const bool fin = (hl < 10) && (node < n);
    float v0 = 0.f, v1 = 0.f, v2 = 0.f, v3 = 0.f;
    float es = 0.f;
    const float C = 12.0f;  // fixed shift: exact (shift-invariant), overflow at v>100
    if (fin) {
        float4 bb = *(const float4*)&b2[q * 4];
        v0 = fmaf((float)cA[0], di, bb.x);
        v1 = fmaf((float)cA[1], di, bb.y);
        v2 = fmaf((float)cB[0], di, bb.z);
        v3 = fmaf((float)cB[1], di, bb.w);
        es = expf(v0 - C) + expf(v1 - C) + expf(v2 - C) + expf(v3 - C);
    }
#pragma unroll
    for (int off = 16; off >= 1; off >>= 1) es += __shfl_xor(es, off, 64);
    if (fin) {
        float ls = C + logf(es);
        *(float4*)&out[(size_t)nd * NCLS + q * 4] =
            make_float4(v0 - ls, v1 - ls, v2 - ls, v3 - ls);
    }
}

extern "C" void kernel_launch(void* const* d_in, const int* in_sizes, int n_in,
                              void* d_out, int out_size, void* d_ws, size_t ws_size,
                              hipStream_t stream) {
    const float* x  = (const float*)d_in[0];
    const void*  ei = d_in[1];
    const float* W1 = (const float*)d_in[2];
    const float* b1 = (const float*)d_in[3];
    const float* W2 = (const float*)d_in[4];
    const float* b2 = (const float*)d_in[5];
    float* out = (float*)d_out;

    const int n = in_sizes[0] / FIN;  // 100000
    const int E = in_sizes[1] / 2;    // 640000
    const int nbk = (n + 255) >> 8;   // 391 coarse buckets (<=512)
    const int n2 = (n + 1) >> 1;      // nodes per gather wave = 2

    char* ws = (char*)d_ws;
    size_t off = 0;
    auto alloc = [&](size_t bytes) {
        size_t p = off;
        off += (bytes + 255) & ~(size_t)255;
        return p;
    };
    int*   flag    = (int*)(ws + alloc(256));
    float* dinv    = (float*)(ws + alloc((size_t)n * 4));
    int*   rowoff  = (int*)(ws + alloc((size_t)(n + 1) * 4));
    int*   blkhist = (int*)(ws + alloc((size_t)256 * 512 * 4));
    int*   blkbase = (int*)(ws + alloc((size_t)512 * 256 * 4));
    int*   btotal  = (int*)(ws + alloc(512 * 4));
    int*   bbase   = (int*)(ws + alloc(520 * 4));
    unsigned short* wt1 = (unsigned short*)(ws + alloc(128 * 128 * 2));
    unsigned short* wt2 = (unsigned short*)(ws + alloc(48 * 128 * 2));
    unsigned int* pairs = (unsigned int*)(ws + alloc((size_t)E * 4));
    int*   epay    = (int*)(ws + alloc((size_t)E * 4));
    unsigned short* xw1  = (unsigned short*)(ws + alloc((size_t)(n + 1) * HID * 2));
    unsigned short* out1 = (unsigned short*)(ws + alloc((size_t)n * HID * 2));
    unsigned short* xw2  = (unsigned short*)(ws + alloc((size_t)(n + 1) * NCLS * 2));

    const int npairs = (E < 2048) ? E : 2048;

    prep_kernel<<<90, 256, 0, stream>>>(
        (const unsigned int*)ei, npairs, flag, W1, wt1, W2, wt2,
        (unsigned int*)(xw1 + (size_t)n * HID), (unsigned int*)(xw2 + (size_t)n * NCLS));
    hist_kernel<<<256, 256, 0, stream>>>(ei, E, flag, blkhist, nbk);
    bscan_kernel<<<nbk, 256, 0, stream>>>(blkhist, blkbase, btotal, nbk);
    base_kernel<<<1, 512, 0, stream>>>(btotal, bbase, nbk);
    scatter_kernel<<<256, 256, 0, stream>>>(ei, E, flag, blkbase, bbase, pairs, nbk);
    fin_kernel<<<nbk, 256, 0, stream>>>(pairs, bbase, dinv, rowoff, epay, n);

    gemm1_kernel<<<(n + 63) / 64, 256, 0, stream>>>(x, wt1, dinv, xw1, n);
    gather1_kernel<<<(int)(((size_t)n2 * 64 + 255) / 256), 256, 0, stream>>>(
        (const uint4*)xw1, dinv, rowoff, epay, b1, (uint4*)out1, n);

    gemm2_kernel<<<(n + 63) / 64, 256, 0, stream>>>(out1, wt2, dinv, xw2, n);
    gather2_kernel<<<(int)(((size_t)n2 * 64 + 255) / 256), 256, 0, stream>>>(
        (const uint2*)xw2, dinv, rowoff, epay, b2, out, n);
}

// Round 11
// 199.825 us; speedup vs baseline: 4.4984x; 1.0187x over previous
//
#include <hip/hip_runtime.h>
#include <hip/hip_bf16.h>
#include <math.h>

#define FIN 128
#define HID 128
#define NCLS 40

typedef _Float16 h2 __attribute__((ext_vector_type(2)));
typedef _Float16 h8 __attribute__((ext_vector_type(8)));
typedef __attribute__((ext_vector_type(4))) float f32x4;

__device__ __forceinline__ unsigned short f2h(float f) {
    union { _Float16 h; unsigned short u; } c;
    c.h = (_Float16)f;
    return c.u;
}
__device__ __forceinline__ h2 u2h2(unsigned int u) {
    union { unsigned int u; h2 h; } c;
    c.u = u;
    return c.h;
}
__device__ __forceinline__ unsigned int h22u(h2 h) {
    union { unsigned int u; h2 h; } c;
    c.h = h;
    return c.u;
}

// wave-uniform edge dtype detect: sample 8 odd dwords; int64 data -> all zero
__device__ __forceinline__ int detect32(const unsigned int* ei32) {
    int k = (threadIdx.x & 63) & 7;
    return __any(ei32[2 * k + 1] != 0u);
}

__device__ __forceinline__ void load_edge(const void* ei, int E, int e, int is32,
                                          int& src, int& dst) {
    if (is32) {
        const int* p = (const int*)ei;
        src = p[e];
        dst = p[E + e];
    } else {
        const long long* p = (const long long*)ei;
        src = (int)p[e];
        dst = (int)p[E + e];
    }
}

// inclusive LDS scan of btotal[0..nbk) into sb[512]; call with 256 threads
__device__ __forceinline__ void scan_btotal(const int* __restrict__ btotal,
                                            int nbk, int* sb) {
    const int t = threadIdx.x;
    for (int i = t; i < 512; i += 256) sb[i] = (i < nbk) ? btotal[i] : 0;
    __syncthreads();
    for (int off = 1; off < 512; off <<= 1) {
        int i0 = t, i1 = t + 256;
        int v0 = (i0 >= off) ? sb[i0 - off] : 0;
        int v1 = (i1 >= off) ? sb[i1 - off] : 0;
        __syncthreads();
        sb[i0] += v0;
        sb[i1] += v1;
        __syncthreads();
    }
}

// ---------------------------------------------------------------------------
// build1: blocks 0..255 = per-block LDS histogram (dst>>8);
//         blocks 256..343 = weight transpose + f16 cast;
//         block 344 = zero rows xw1[n], xw2[n]
// ---------------------------------------------------------------------------
__global__ __launch_bounds__(256) void build1_kernel(const void* __restrict__ ei, int E,
                                                     int* __restrict__ blkhist, int nbk,
                                                     const float* __restrict__ W1,
                                                     unsigned short* __restrict__ Wt1,
                                                     const float* __restrict__ W2,
                                                     unsigned short* __restrict__ Wt2,
                                                     unsigned int* __restrict__ z1,
                                                     unsigned int* __restrict__ z2) {
    const int b = blockIdx.x, t = threadIdx.x;
    if (b < 256) {
        __shared__ int lh[512];
        for (int i = t; i < nbk; i += 256) lh[i] = 0;
        __syncthreads();
        const int is32 = detect32((const unsigned int*)ei);
        for (int e = b * 256 + t; e < E; e += 256 * 256) {
            int dst;
            if (is32) dst = ((const int*)ei)[E + e];
            else      dst = (int)((const long long*)ei)[E + e];
            atomicAdd(&lh[dst >> 8], 1);
        }
        __syncthreads();
        for (int i = t; i < nbk; i += 256) blkhist[b * nbk + i] = lh[i];
    } else if (b < 344) {
        int i = (b - 256) * 256 + t;
        if (i < 128 * 128) {
            int nidx = i >> 7, k = i & 127;
            Wt1[i] = f2h(W1[k * HID + nidx]);
        } else {
            int j = i - 128 * 128;  // < 48*128
            int nidx = j >> 7, k = j & 127;
            Wt2[j] = (nidx < NCLS) ? f2h(W2[k * NCLS + nidx]) : 0;
        }
    } else {
        if (t < 64) z1[t] = 0;            // xw1 zero row
        else if (t < 84) z2[t - 64] = 0;  // xw2 zero row
    }
}

__global__ __launch_bounds__(256) void bscan_kernel(const int* __restrict__ blkhist,
                                                    int* __restrict__ blkbase,
                                                    int* __restrict__ btotal, int nbk) {
    __shared__ int s[256];
    const int t = threadIdx.x, b = blockIdx.x;
    int v = blkhist[t * nbk + b];
    s[t] = v;
    __syncthreads();
#pragma unroll
    for (int off = 1; off < 256; off <<= 1) {
        int u = (t >= off) ? s[t - off] : 0;
        __syncthreads();
        s[t] += u;
        __syncthreads();
    }
    blkbase[b * 256 + t] = s[t] - v;  // exclusive
    if (t == 255) btotal[b] = s[255];
}

__global__ __launch_bounds__(256) void scatter_kernel(const void* __restrict__ ei, int E,
                                                      const int* __restrict__ blkbase,
                                                      const int* __restrict__ btotal,
                                                      unsigned int* __restrict__ pairs,
                                                      int nbk) {
    __shared__ int sb[512];
    __shared__ int lcur[512];
    const int t = threadIdx.x, blk = blockIdx.x;
    scan_btotal(btotal, nbk, sb);
    for (int i = t; i < nbk; i += 256) {
        int base = (i > 0) ? sb[i - 1] : 0;
        lcur[i] = base + blkbase[i * 256 + blk];
    }
    __syncthreads();
    const int is32 = detect32((const unsigned int*)ei);
    for (int e = blk * 256 + t; e < E; e += 256 * 256) {
        int src, dst;
        load_edge(ei, E, e, is32, src, dst);
        int pos = atomicAdd(&lcur[dst >> 8], 1);
        pairs[pos] = (unsigned int)src | ((unsigned int)(dst & 255) << 17);
    }
}

__global__ __launch_bounds__(256) void fin_kernel(const unsigned int* __restrict__ pairs,
                                                  const int* __restrict__ btotal,
                                                  float* __restrict__ dinv,
                                                  int* __restrict__ rowoff,
                                                  int* __restrict__ epay, int n, int nbk) {
    __shared__ int sb[512];
    __shared__ int deg[256];
    __shared__ int s[256];
    __shared__ int cur[256];
    const int t = threadIdx.x, b = blockIdx.x;
    scan_btotal(btotal, nbk, sb);
    deg[t] = 0;
    __syncthreads();
    const int start = (b > 0) ? sb[b - 1] : 0;
    const int end = sb[b];
    for (int k = start + t; k < end; k += 256) atomicAdd(&deg[pairs[k] >> 17], 1);
    __syncthreads();
    int d = deg[t];
    s[t] = d;
    __syncthreads();
#pragma unroll
    for (int off = 1; off < 256; off <<= 1) {
        int u = (t >= off) ? s[t - off] : 0;
        __syncthreads();
        s[t] += u;
        __syncthreads();
    }
    int gi = b * 256 + t;
    if (gi < n) {
        dinv[gi] = rsqrtf((float)d + 1.0f);  // +1 self loop
        rowoff[gi + 1] = start + s[t];
    }
    if (gi == 0) rowoff[0] = 0;
    cur[t] = s[t] - d;
    __syncthreads();
    for (int k = start + t; k < end; k += 256) {
        unsigned int p = pairs[k];
        int dl = p >> 17;
        int pos = start + atomicAdd(&cur[dl], 1);
        epay[pos] = (int)(p & 0x1FFFFu);
    }
}

// ---------------------------------------------------------------------------
// MFMA GEMM1: xw1'[n x 128] (fp16) = dinv[row] * (f16(X) @ f16(W1))
// ---------------------------------------------------------------------------
__global__ __launch_bounds__(256) void gemm1_kernel(const float* __restrict__ X,
                                                    const unsigned short* __restrict__ Wt,
                                                    const float* __restrict__ dinv,
                                                    unsigned short* __restrict__ Y, int n) {
    __shared__ unsigned short Bs[128][136];
    const int t = threadIdx.x;
    for (int i = t; i < 128 * 16; i += 256) {
        int c = i >> 4, kc = (i & 15) << 3;
        *(int4*)&Bs[c][kc] = ((const int4*)Wt)[i];
    }
    __syncthreads();

    const int wv = t >> 6, lane = t & 63;
    const int lr = lane & 15, kg = lane >> 4;
    const int row0 = blockIdx.x * 64 + wv * 16;
    int arow = row0 + lr;
    if (arow >= n) arow = n - 1;
    const float* aptr = X + (size_t)arow * FIN + kg * 8;

    f32x4 acc[8];
#pragma unroll
    for (int nf = 0; nf < 8; ++nf) acc[nf] = (f32x4){0.f, 0.f, 0.f, 0.f};

#pragma unroll
    for (int kt = 0; kt < 4; ++kt) {
        float4 a0 = *(const float4*)(aptr + kt * 32);
        float4 a1 = *(const float4*)(aptr + kt * 32 + 4);
        h8 af;
        af[0] = (_Float16)a0.x; af[1] = (_Float16)a0.y;
        af[2] = (_Float16)a0.z; af[3] = (_Float16)a0.w;
        af[4] = (_Float16)a1.x; af[5] = (_Float16)a1.y;
        af[6] = (_Float16)a1.z; af[7] = (_Float16)a1.w;
#pragma unroll
        for (int nf = 0; nf < 8; ++nf) {
            h8 bf_ = *(const h8*)&Bs[nf * 16 + lr][kt * 32 + kg * 8];
            acc[nf] = __builtin_amdgcn_mfma_f32_16x16x32_f16(af, bf_, acc[nf], 0, 0, 0);
        }
    }
    float4 d4 = *(const float4*)&dinv[row0 + kg * 4];
    float dv[4] = {d4.x, d4.y, d4.z, d4.w};
#pragma unroll
    for (int nf = 0; nf < 8; ++nf) {
        int col = nf * 16 + lr;
#pragma unroll
        for (int r = 0; r < 4; ++r) {
            int row = row0 + kg * 4 + r;
            if (row < n) Y[(size_t)row * HID + col] = f2h(acc[nf][r] * dv[r]);
        }
    }
}

// ---------------------------------------------------------------------------
// MFMA GEMM2: xw2'[n x 40] (fp16, stride 40) = dinv[row]*(out1 @ f16(W2))
// ---------------------------------------------------------------------------
__global__ __launch_bounds__(256) void gemm2_kernel(const unsigned short* __restrict__ Xin,
                                                    const unsigned short* __restrict__ Wt,
                                                    const float* __restrict__ dinv,
                                                    unsigned short* __restrict__ Y, int n) {
    __shared__ unsigned short Bs[48][136];
    const int t = threadIdx.x;
    for (int i = t; i < 48 * 16; i += 256) {
        int c = i >> 4, kc = (i & 15) << 3;
        *(int4*)&Bs[c][kc] = ((const int4*)Wt)[i];
    }
    __syncthreads();

    const int wv = t >> 6, lane = t & 63;
    const int lr = lane & 15, kg = lane >> 4;
    const int row0 = blockIdx.x * 64 + wv * 16;
    int arow = row0 + lr;
    if (arow >= n) arow = n - 1;
    const unsigned short* aptr = Xin + (size_t)arow * HID + kg * 8;

    f32x4 acc[3];
#pragma unroll
    for (int nf = 0; nf < 3; ++nf) acc[nf] = (f32x4){0.f, 0.f, 0.f, 0.f};

#pragma unroll
    for (int kt = 0; kt < 4; ++kt) {
        h8 af = *(const h8*)(aptr + kt * 32);
#pragma unroll
        for (int nf = 0; nf < 3; ++nf) {
            h8 bf_ = *(const h8*)&Bs[nf * 16 + lr][kt * 32 + kg * 8];
            acc[nf] = __builtin_amdgcn_mfma_f32_16x16x32_f16(af, bf_, acc[nf], 0, 0, 0);
        }
    }
    float4 d4 = *(const float4*)&dinv[row0 + kg * 4];
    float dv[4] = {d4.x, d4.y, d4.z, d4.w};
#pragma unroll
    for (int nf = 0; nf < 3; ++nf) {
        int col = nf * 16 + lr;
        if (col < NCLS) {
#pragma unroll
            for (int r = 0; r < 4; ++r) {
                int row = row0 + kg * 4 + r;
                if (row < n) Y[(size_t)row * NCLS + col] = f2h(acc[nf][r] * dv[r]);
            }
        }
    }
}

// ---------------------------------------------------------------------------
// gather1 v4: 4 nodes/wave; quarter = 16 lanes = one 128-feat row (uint4/lane).
// Per edge: 1 shfl + 1 uint4 load + 4 pk_adds. No cross-lane tail.
// out1 = f16(relu(dinv_i*(self + sum_src) + b1))
// ---------------------------------------------------------------------------
__global__ __launch_bounds__(256) void gather1_kernel(const uint4* __restrict__ xw,
                                                      const float* __restrict__ dinv,
                                                      const int* __restrict__ rowoff,
                                                      const int* __restrict__ epay,
                                                      const float* __restrict__ b1,
                                                      uint4* __restrict__ out, int n) {
    int w = (int)((blockIdx.x * 256u + threadIdx.x) >> 6);
    const int n4 = (n + 3) >> 2;
    if (w >= n4) return;
    const int lane = threadIdx.x & 63;
    const int qb = lane & 48;  // quarter base
    const int hl = lane & 15;  // lane in quarter = feat chunk
    const int node = 4 * w + (lane >> 4);
    const int nd = (node < n) ? node : (n - 1);
    const int rs = rowoff[nd], re = rowoff[nd + 1];
    const float di = dinv[nd];

    h2 c0, c1, c2, c3;
    {
        uint4 v = xw[(size_t)nd * 16 + hl];  // self row
        c0 = u2h2(v.x); c1 = u2h2(v.y); c2 = u2h2(v.z); c3 = u2h2(v.w);
    }

    for (int base = rs; base < re; base += 16) {
        int avail = re - base;
        int cnt = (avail < 16) ? avail : 16;
        int px = (hl < cnt) ? epay[base + hl] : n;  // OOB -> zero row
        int j = 0;
        for (; j + 1 < cnt; j += 2) {
            int sA = __shfl(px, qb | j, 64);
            int sB = __shfl(px, qb | (j + 1), 64);
            uint4 vA = xw[(size_t)sA * 16 + hl];
            uint4 vB = xw[(size_t)sB * 16 + hl];
            c0 += u2h2(vA.x); c1 += u2h2(vA.y); c2 += u2h2(vA.z); c3 += u2h2(vA.w);
            c0 += u2h2(vB.x); c1 += u2h2(vB.y); c2 += u2h2(vB.z); c3 += u2h2(vB.w);
        }
        if (j < cnt) {
            int sA = __shfl(px, qb | j, 64);
            uint4 vA = xw[(size_t)sA * 16 + hl];
            c0 += u2h2(vA.x); c1 += u2h2(vA.y); c2 += u2h2(vA.z); c3 += u2h2(vA.w);
        }
    }
    if (node < n) {
        float4 ba = *(const float4*)&b1[hl * 8];
        float4 bb = *(const float4*)&b1[hl * 8 + 4];
        float r0 = fmaxf(fmaf((float)c0[0], di, ba.x), 0.f);
        float r1 = fmaxf(fmaf((float)c0[1], di, ba.y), 0.f);
        float r2 = fmaxf(fmaf((float)c1[0], di, ba.z), 0.f);
        float r3 = fmaxf(fmaf((float)c1[1], di, ba.w), 0.f);
        float r4 = fmaxf(fmaf((float)c2[0], di, bb.x), 0.f);
        float r5 = fmaxf(fmaf((float)c2[1], di, bb.y), 0.f);
        float r6 = fmaxf(fmaf((float)c3[0], di, bb.z), 0.f);
        float r7 = fmaxf(fmaf((float)c3[1], di, bb.w), 0.f);
        uint4 o;
        o.x = (unsigned)f2h(r0) | ((unsigned)f2h(r1) << 16);
        o.y = (unsigned)f2h(r2) | ((unsigned)f2h(r3) << 16);
        o.z = (unsigned)f2h(r4) | ((unsigned)f2h(r5) << 16);
        o.w = (unsigned)f2h(r6) | ((unsigned)f2h(r7) << 16);
        out[(size_t)nd * 16 + hl] = o;
    }
}

// ---------------------------------------------------------------------------
// gather2 v4: 4 nodes/wave; quarter = 16 lanes, 10 active (uint2 = 4 classes).
// Fixed-shift log_softmax (no max pass), es butterfly = 4 rounds in-quarter.
// ---------------------------------------------------------------------------
__global__ __launch_bounds__(256) void gather2_kernel(const uint2* __restrict__ xw,
                                                      const float* __restrict__ dinv,
                                                      const int* __restrict__ rowoff,
                                                      const int* __restrict__ epay,
                                                      const float* __restrict__ b2,
                                                      float* __restrict__ out, int n) {
    int w = (int)((blockIdx.x * 256u + threadIdx.x) >> 6);
    const int n4 = (n + 3) >> 2;
    if (w >= n4) return;
    const int lane = threadIdx.x & 63;
    const int qb = lane & 48;
    const int hl = lane & 15;
    const int q = (hl < 10) ? hl : 0;  // class-pair; lanes 10-15 clamp (dead)
    const int node = 4 * w + (lane >> 4);
    const int nd = (node < n) ? node : (n - 1);
    const int rs = rowoff[nd], re = rowoff[nd + 1];
    const float di = dinv[nd];

    h2 cA, cB;
    {
        uint2 v = xw[(size_t)nd * 10 + q];  // self row
        cA = u2h2(v.x); cB = u2h2(v.y);
    }

    for (int base = rs; base < re; base += 16) {
        int avail = re - base;
        int cnt = (avail < 16) ? avail : 16;
        int px = (hl < cnt) ? epay[base + hl] : n;  // OOB -> zero row
        int j = 0;
        for (; j + 1 < cnt; j += 2) {
            int sA = __shfl(px, qb | j, 64);
            int sB = __shfl(px, qb | (j + 1), 64);
            uint2 vA = xw[(size_t)sA * 10 + q];
            uint2 vB = xw[(size_t)sB * 10 + q];
            cA += u2h2(vA.x); cB += u2h2(vA.y);
            cA += u2h2(vB.x); cB += u2h2(vB.y);
        }
        if (j < cnt) {
            int sA = __shfl(px, qb | j, 64);
            uint2 vA = xw[(size_t)sA * 10 + q];
            cA += u2h2(vA.x); cB += u2h2(vA.y);
        }
    }
    const bool fin = (hl < 10) && (node < n);
    float v0 = 0.f, v1 = 0.f, v2 = 0.f, v3 = 0.f;
    float es = 0.f;
    const float C = 12.0f;  // fixed shift: exact (shift-invariant); logits |v|<~30
    if (fin) {
        float4 bb = *(const float4*)&b2[q * 4];
        v0 = fmaf((float)cA[0], di, bb.x);
        v1 = fmaf((float)cA[1], di, bb.y);
        v2 = fmaf((float)cB[0], di, bb.z);
        v3 = fmaf((float)cB[1], di, bb.w);
        es = expf(v0 - C) + expf(v1 - C) + expf(v2 - C) + expf(v3 - C);
    }
#pragma unroll
    for (int off = 8; off >= 1; off >>= 1) es += __shfl_xor(es, off, 64);
    if (fin) {
        float ls = C + logf(es);
        *(float4*)&out[(size_t)nd * NCLS + q * 4] =
            make_float4(v0 - ls, v1 - ls, v2 - ls, v3 - ls);
    }
}

extern "C" void kernel_launch(void* const* d_in, const int* in_sizes, int n_in,
                              void* d_out, int out_size, void* d_ws, size_t ws_size,
                              hipStream_t stream) {
    const float* x  = (const float*)d_in[0];
    const void*  ei = d_in[1];
    const float* W1 = (const float*)d_in[2];
    const float* b1 = (const float*)d_in[3];
    const float* W2 = (const float*)d_in[4];
    const float* b2 = (const float*)d_in[5];
    float* out = (float*)d_out;

    const int n = in_sizes[0] / FIN;  // 100000
    const int E = in_sizes[1] / 2;    // 640000
    const int nbk = (n + 255) >> 8;   // 391 coarse buckets (<=512)
    const int n4 = (n + 3) >> 2;      // 4 nodes per gather wave

    char* ws = (char*)d_ws;
    size_t off = 0;
    auto alloc = [&](size_t bytes) {
        size_t p = off;
        off += (bytes + 255) & ~(size_t)255;
        return p;
    };
    float* dinv    = (float*)(ws + alloc((size_t)n * 4));
    int*   rowoff  = (int*)(ws + alloc((size_t)(n + 1) * 4));
    int*   blkhist = (int*)(ws + alloc((size_t)256 * 512 * 4));
    int*   blkbase = (int*)(ws + alloc((size_t)512 * 256 * 4));
    int*   btotal  = (int*)(ws + alloc(512 * 4));
    unsigned short* wt1 = (unsigned short*)(ws + alloc(128 * 128 * 2));
    unsigned short* wt2 = (unsigned short*)(ws + alloc(48 * 128 * 2));
    unsigned int* pairs = (unsigned int*)(ws + alloc((size_t)E * 4));
    int*   epay    = (int*)(ws + alloc((size_t)E * 4));
    unsigned short* xw1  = (unsigned short*)(ws + alloc((size_t)(n + 1) * HID * 2));
    unsigned short* out1 = (unsigned short*)(ws + alloc((size_t)n * HID * 2));
    unsigned short* xw2  = (unsigned short*)(ws + alloc((size_t)(n + 1) * NCLS * 2));

    build1_kernel<<<345, 256, 0, stream>>>(
        ei, E, blkhist, nbk, W1, wt1, W2, wt2,
        (unsigned int*)(xw1 + (size_t)n * HID), (unsigned int*)(xw2 + (size_t)n * NCLS));
    bscan_kernel<<<nbk, 256, 0, stream>>>(blkhist, blkbase, btotal, nbk);
    scatter_kernel<<<256, 256, 0, stream>>>(ei, E, blkbase, btotal, pairs, nbk);
    fin_kernel<<<nbk, 256, 0, stream>>>(pairs, btotal, dinv, rowoff, epay, n, nbk);

    gemm1_kernel<<<(n + 63) / 64, 256, 0, stream>>>(x, wt1, dinv, xw1, n);
    gather1_kernel<<<(n4 + 3) / 4, 256, 0, stream>>>(
        (const uint4*)xw1, dinv, rowoff, epay, b1, (uint4*)out1, n);

    gemm2_kernel<<<(n + 63) / 64, 256, 0, stream>>>(out1, wt2, dinv, xw2, n);
    gather2_kernel<<<(n4 + 3) / 4, 256, 0, stream>>>(
        (const uint2*)xw2, dinv, rowoff, epay, b2, out, n);
}